// Round 2
// baseline (10765.747 us; speedup 1.0000x reference)
//
#include <hip/hip_runtime.h>

// GraphRec forward on MI355X. Round 2: dtype-robust (runtime-sniffed f32 vs bf16
// device buffers) correctness-first vector implementation.
// Internal compute f32. Weights materialized as f32 in d_ws.

typedef unsigned int   u32;
typedef unsigned short u16;

#define U_N   100000
#define I_N   50000
#define EUI_N 1000000
#define EUU_N 500000

// ---------- bf16 helpers (manual, RNE) ----------
__device__ __forceinline__ float bflo(u32 u){ return __uint_as_float(u << 16); }
__device__ __forceinline__ float bfhi(u32 u){ return __uint_as_float(u & 0xffff0000u); }
__device__ __forceinline__ u16 f2bf(float f){
  u32 x = __float_as_uint(f);
  x += 0x7fffu + ((x >> 16) & 1u);       // round-to-nearest-even
  return (u16)(x >> 16);
}
__device__ __forceinline__ u32 pk2(float a, float b){
  return (u32)f2bf(a) | ((u32)f2bf(b) << 16);
}
// leaky relu, slope s in [0,1): max(x, s*x). s=0 -> relu.
__device__ __forceinline__ float actf(float x, float s){ return fmaxf(x, x * s); }

// ---------- dtype-generic row access ----------
template<int F32>
__device__ __forceinline__ const void* rowptr(const void* emb, int idx){
  if (F32) return (const void*)((const float*)emb + (size_t)idx * 64);
  else     return (const void*)((const u16*)emb + (size_t)idx * 64);
}
template<int F32>
__device__ __forceinline__ void load8(const void* p, int k, float f[8]){
  if (F32){
    const float* fp = (const float*)p + k;
    float4 a = *(const float4*)fp;
    float4 b = *(const float4*)(fp + 4);
    f[0]=a.x; f[1]=a.y; f[2]=a.z; f[3]=a.w;
    f[4]=b.x; f[5]=b.y; f[6]=b.z; f[7]=b.w;
  } else {
    uint4 q = *(const uint4*)((const u16*)p + k);
    f[0]=bflo(q.x); f[1]=bfhi(q.x); f[2]=bflo(q.y); f[3]=bfhi(q.y);
    f[4]=bflo(q.z); f[5]=bfhi(q.z); f[6]=bflo(q.w); f[7]=bfhi(q.w);
  }
}

// ---------- dense-layer inner chunks (acc[64] statically indexed) ----------
__device__ __forceinline__ void fma8(float acc[64], const float f[8],
                                     const float* __restrict__ W, int r0){
  #pragma unroll
  for (int u = 0; u < 8; ++u){
    const float* __restrict__ Wp = W + (size_t)(r0 + u) * 64;
    float c = f[u];
    #pragma unroll
    for (int j = 0; j < 64; ++j) acc[j] = fmaf(c, Wp[j], acc[j]);
  }
}
__device__ __forceinline__ void fma4_f32(float acc[64], float4 q,
                                         const float* __restrict__ W, int k0){
  #pragma unroll
  for (int u = 0; u < 4; ++u){
    float c = (&q.x)[u];
    const float* __restrict__ Wp = W + (size_t)(k0 + u) * 64;
    #pragma unroll
    for (int j = 0; j < 64; ++j) acc[j] = fmaf(c, Wp[j], acc[j]);
  }
}

// ---------- attention score: x = cat(srow f32[64], rowD[64]); relu MLP 128->64->64->1 ----------
template<int DF32>
__device__ __forceinline__ float att_score(float* srow, const void* rowD,
    const float* __restrict__ Wa1, const float* __restrict__ ba1,
    const float* __restrict__ Wa2, const float* __restrict__ ba2,
    const float* __restrict__ wa3, const float* __restrict__ ba3)
{
  float acc[64];
  #pragma unroll
  for (int j = 0; j < 64; ++j) acc[j] = ba1[j];
  #pragma unroll 1
  for (int c = 0; c < 64; c += 4){ float4 q = *(const float4*)(srow + c); fma4_f32(acc, q, Wa1, c); }
  #pragma unroll 1
  for (int k = 0; k < 64; k += 8){ float f[8]; load8<DF32>(rowD, k, f); fma8(acc, f, Wa1, 64 + k); }
  #pragma unroll
  for (int j = 0; j < 64; j += 4){
    *(float4*)(srow + j) = make_float4(fmaxf(acc[j],0.f), fmaxf(acc[j+1],0.f),
                                       fmaxf(acc[j+2],0.f), fmaxf(acc[j+3],0.f));
  }
  #pragma unroll
  for (int j = 0; j < 64; ++j) acc[j] = ba2[j];
  #pragma unroll 1
  for (int c = 0; c < 64; c += 4){ float4 q = *(const float4*)(srow + c); fma4_f32(acc, q, Wa2, c); }
  float s0=0.f, s1=0.f, s2=0.f, s3=0.f;
  #pragma unroll
  for (int j = 0; j < 64; j += 4){
    s0 = fmaf(fmaxf(acc[j  ],0.f), wa3[j  ], s0);
    s1 = fmaf(fmaxf(acc[j+1],0.f), wa3[j+1], s1);
    s2 = fmaf(fmaxf(acc[j+2],0.f), wa3[j+2], s2);
    s3 = fmaf(fmaxf(acc[j+3],0.f), wa3[j+3], s3);
  }
  return ba3[0] + ((s0 + s1) + (s2 + s3));
}

// ---------- value MLP: x = cat(rowA[64], rowR[64]); leaky MLP 128->64->64 ----------
template<int F32>
__device__ __forceinline__ void gv_mlp(float acc[64], float* srow,
    const void* rowA, const void* rowR,
    const float* __restrict__ Wg1, const float* __restrict__ bg1,
    const float* __restrict__ Wg2, const float* __restrict__ bg2, float slope)
{
  #pragma unroll
  for (int j = 0; j < 64; ++j) acc[j] = bg1[j];
  #pragma unroll 1
  for (int k = 0; k < 64; k += 8){ float f[8]; load8<F32>(rowA, k, f); fma8(acc, f, Wg1, k); }
  #pragma unroll 1
  for (int k = 0; k < 64; k += 8){ float f[8]; load8<F32>(rowR, k, f); fma8(acc, f, Wg1, 64 + k); }
  #pragma unroll
  for (int j = 0; j < 64; j += 4){
    *(float4*)(srow + j) = make_float4(actf(acc[j],slope), actf(acc[j+1],slope),
                                       actf(acc[j+2],slope), actf(acc[j+3],slope));
  }
  #pragma unroll
  for (int j = 0; j < 64; ++j) acc[j] = bg2[j];
  #pragma unroll 1
  for (int c = 0; c < 64; c += 4){ float4 q = *(const float4*)(srow + c); fma4_f32(acc, q, Wg2, c); }
  #pragma unroll
  for (int j = 0; j < 64; ++j) acc[j] = actf(acc[j], slope);
}

#define SROW_STRIDE 68   // floats; 272B: 16B-aligned, benign bank pattern

// ---------- dtype sniff: f32 data is sane under f32 read; bf16 pairs are ~2^100 ----------
__global__ void sniff_kernel(const float* __restrict__ x, int* __restrict__ flag){
  float v = x[threadIdx.x];
  float a = fabsf(v);
  int sane = (v == 0.0f) || (a > 1e-30f && a < 1e6f);
  unsigned long long m = __ballot(sane);
  if (threadIdx.x == 0) flag[0] = (__popcll(m) >= 32) ? 1 : 0;
}

// ---------- pass A: per-edge value-MLP + attention score; esc=exp(sc); sum[dst]+=esc ----------
template<int F32>
__global__ void __launch_bounds__(192) edge_score_kernel(
    const int* __restrict__ flag,
    const void* __restrict__ embA, const int* __restrict__ idxA,
    const void* __restrict__ embR, const int* __restrict__ idxR,
    const void* __restrict__ embD, const int* __restrict__ idxD,
    const float* __restrict__ Wg1, const float* __restrict__ bg1,
    const float* __restrict__ Wg2, const float* __restrict__ bg2,
    const float* __restrict__ Wa1, const float* __restrict__ ba1,
    const float* __restrict__ Wa2, const float* __restrict__ ba2,
    const float* __restrict__ wa3, const float* __restrict__ ba3,
    float slope, float* __restrict__ esc, float* __restrict__ sum, int E)
{
  if (flag[0] != F32) return;
  __shared__ float sh[192 * SROW_STRIDE];
  int e = blockIdx.x * 192 + threadIdx.x;
  if (e >= E) return;
  float* srow = sh + threadIdx.x * SROW_STRIDE;
  int ia = idxA[e], ir = idxR[e], id = idxD[e];
  float acc[64];
  gv_mlp<F32>(acc, srow, rowptr<F32>(embA, ia), rowptr<F32>(embR, ir),
              Wg1, bg1, Wg2, bg2, slope);
  #pragma unroll
  for (int j = 0; j < 64; j += 4)
    *(float4*)(srow + j) = make_float4(acc[j], acc[j+1], acc[j+2], acc[j+3]);
  float sc = att_score<F32>(srow, rowptr<F32>(embD, id), Wa1, ba1, Wa2, ba2, wa3, ba3);
  float ev = expf(sc);          // |sc| <~ 1: identical math to max-subtracted softmax
  esc[e] = ev;
  atomicAdd(&sum[id], ev);
}

// ---------- pass B: recompute value-MLP; h[dst] += x * esc/sum ----------
template<int F32>
__global__ void __launch_bounds__(192) edge_agg_kernel(
    const int* __restrict__ flag,
    const void* __restrict__ embA, const int* __restrict__ idxA,
    const void* __restrict__ embR, const int* __restrict__ idxR,
    const int* __restrict__ idxD,
    const float* __restrict__ Wg1, const float* __restrict__ bg1,
    const float* __restrict__ Wg2, const float* __restrict__ bg2,
    float slope, const float* __restrict__ esc, const float* __restrict__ sum,
    float* __restrict__ hacc, int E)
{
  if (flag[0] != F32) return;
  __shared__ float sh[192 * SROW_STRIDE];
  int e = blockIdx.x * 192 + threadIdx.x;
  if (e >= E) return;
  float* srow = sh + threadIdx.x * SROW_STRIDE;
  int ia = idxA[e], ir = idxR[e], id = idxD[e];
  float acc[64];
  gv_mlp<F32>(acc, srow, rowptr<F32>(embA, ia), rowptr<F32>(embR, ir),
              Wg1, bg1, Wg2, bg2, slope);
  float val = esc[e] / sum[id];
  float* dst = hacc + (size_t)id * 64;
  #pragma unroll
  for (int j = 0; j < 64; ++j) atomicAdd(dst + j, acc[j] * val);
}

// ---------- social pass A: att(user_emb[trust], hI[trustee]) ----------
template<int F32>
__global__ void __launch_bounds__(192) social_score_kernel(
    const int* __restrict__ flag,
    const void* __restrict__ uemb, const int* __restrict__ tr_idx,
    const u16* __restrict__ hIbf, const int* __restrict__ te_idx,
    const float* __restrict__ Wa1, const float* __restrict__ ba1,
    const float* __restrict__ Wa2, const float* __restrict__ ba2,
    const float* __restrict__ wa3, const float* __restrict__ ba3,
    float* __restrict__ esc, float* __restrict__ sum, int E)
{
  if (flag[0] != F32) return;
  __shared__ float sh[192 * SROW_STRIDE];
  int e = blockIdx.x * 192 + threadIdx.x;
  if (e >= E) return;
  float* srow = sh + threadIdx.x * SROW_STRIDE;
  int tr = tr_idx[e], te = te_idx[e];
  const void* rowT = rowptr<F32>(uemb, tr);
  #pragma unroll 1
  for (int k = 0; k < 64; k += 8){
    float f[8]; load8<F32>(rowT, k, f);
    #pragma unroll
    for (int u = 0; u < 8; ++u) srow[k + u] = f[u];
  }
  const void* rowD = (const void*)(hIbf + (size_t)te * 64);  // internal: always bf16
  float sc = att_score<0>(srow, rowD, Wa1, ba1, Wa2, ba2, wa3, ba3);
  float ev = expf(sc);
  esc[e] = ev;
  atomicAdd(&sum[te], ev);
}

// ---------- social pass B: hS[trustee] += hI[trust] * esc/sum ----------
__global__ void __launch_bounds__(256) social_agg_kernel(
    const int* __restrict__ tr_idx, const int* __restrict__ te_idx,
    const u16* __restrict__ hIbf, const float* __restrict__ esc,
    const float* __restrict__ sum, float* __restrict__ hSacc, int E)
{
  int e = blockIdx.x * 256 + threadIdx.x;
  if (e >= E) return;
  int tr = tr_idx[e], te = te_idx[e];
  float val = esc[e] / sum[te];
  const u32* rowT = (const u32*)(hIbf + (size_t)tr * 64);
  float* dst = hSacc + (size_t)te * 64;
  #pragma unroll 1
  for (int w = 0; w < 32; w += 4){
    uint4 q = *(const uint4*)(rowT + w);
    atomicAdd(dst + 2*w + 0, bflo(q.x)*val); atomicAdd(dst + 2*w + 1, bfhi(q.x)*val);
    atomicAdd(dst + 2*w + 2, bflo(q.y)*val); atomicAdd(dst + 2*w + 3, bfhi(q.y)*val);
    atomicAdd(dst + 2*w + 4, bflo(q.z)*val); atomicAdd(dst + 2*w + 5, bfhi(q.z)*val);
    atomicAdd(dst + 2*w + 6, bflo(q.w)*val); atomicAdd(dst + 2*w + 7, bfhi(q.w)*val);
  }
}

// ---------- row transform: out = leaky0.2(in_f32 @ W + b); out dtype per outf32 ----------
__global__ void __launch_bounds__(256) rt_kernel(
    const int* __restrict__ flag, int want, int outf32,
    const float* __restrict__ in, const float* __restrict__ W, const float* __restrict__ b,
    void* __restrict__ out, size_t row0, int N)
{
  if (want >= 0 && flag[0] != want) return;
  int r = blockIdx.x * 256 + threadIdx.x;
  if (r >= N) return;
  const float* row = in + (size_t)r * 64;
  float acc[64];
  #pragma unroll
  for (int j = 0; j < 64; ++j) acc[j] = b[j];
  #pragma unroll 1
  for (int c = 0; c < 64; c += 4){ float4 q = *(const float4*)(row + c); fma4_f32(acc, q, W, c); }
  if (outf32){
    float* o = (float*)out + (row0 + (size_t)r) * 64;
    #pragma unroll
    for (int j = 0; j < 64; j += 4)
      *(float4*)(o + j) = make_float4(actf(acc[j],0.2f), actf(acc[j+1],0.2f),
                                      actf(acc[j+2],0.2f), actf(acc[j+3],0.2f));
  } else {
    u32* o = (u32*)((u16*)out + (row0 + (size_t)r) * 64);
    #pragma unroll
    for (int j = 0; j < 64; j += 8){
      uint4 w;
      w.x = pk2(actf(acc[j  ],0.2f), actf(acc[j+1],0.2f));
      w.y = pk2(actf(acc[j+2],0.2f), actf(acc[j+3],0.2f));
      w.z = pk2(actf(acc[j+4],0.2f), actf(acc[j+5],0.2f));
      w.w = pk2(actf(acc[j+6],0.2f), actf(acc[j+7],0.2f));
      *(uint4*)(o + j/2) = w;
    }
  }
}

// ---------- h_out: hS = leaky0.2(hSacc@wS+b); out = leaky0.2(cat(hI,hS)@W2+b2) ----------
__global__ void __launch_bounds__(192) hout_kernel(
    const int* __restrict__ flag, int want, int outf32,
    const float* __restrict__ hSacc, const float* __restrict__ WS, const float* __restrict__ bS,
    const u16* __restrict__ hIbf, const float* __restrict__ W2, const float* __restrict__ b2,
    void* __restrict__ out, int N)
{
  if (flag[0] != want) return;
  __shared__ float sh[192 * SROW_STRIDE];
  int r = blockIdx.x * 192 + threadIdx.x;
  if (r >= N) return;
  float* srow = sh + threadIdx.x * SROW_STRIDE;
  const float* rowS = hSacc + (size_t)r * 64;
  float acc[64];
  #pragma unroll
  for (int j = 0; j < 64; ++j) acc[j] = bS[j];
  #pragma unroll 1
  for (int c = 0; c < 64; c += 4){ float4 q = *(const float4*)(rowS + c); fma4_f32(acc, q, WS, c); }
  #pragma unroll
  for (int j = 0; j < 64; j += 4)
    *(float4*)(srow + j) = make_float4(actf(acc[j],0.2f), actf(acc[j+1],0.2f),
                                       actf(acc[j+2],0.2f), actf(acc[j+3],0.2f));
  #pragma unroll
  for (int j = 0; j < 64; ++j) acc[j] = b2[j];
  const void* rowH = (const void*)(hIbf + (size_t)r * 64);
  #pragma unroll 1
  for (int k = 0; k < 64; k += 8){ float f[8]; load8<0>(rowH, k, f); fma8(acc, f, W2, k); }
  #pragma unroll 1
  for (int c = 0; c < 64; c += 4){ float4 q = *(const float4*)(srow + c); fma4_f32(acc, q, W2 + 64*64, c); }
  if (outf32){
    float* o = (float*)out + (size_t)r * 64;
    #pragma unroll
    for (int j = 0; j < 64; j += 4)
      *(float4*)(o + j) = make_float4(actf(acc[j],0.2f), actf(acc[j+1],0.2f),
                                      actf(acc[j+2],0.2f), actf(acc[j+3],0.2f));
  } else {
    u32* o = (u32*)((u16*)out + (size_t)r * 64);
    #pragma unroll
    for (int j = 0; j < 64; j += 8){
      uint4 w;
      w.x = pk2(actf(acc[j  ],0.2f), actf(acc[j+1],0.2f));
      w.y = pk2(actf(acc[j+2],0.2f), actf(acc[j+3],0.2f));
      w.z = pk2(actf(acc[j+4],0.2f), actf(acc[j+5],0.2f));
      w.w = pk2(actf(acc[j+6],0.2f), actf(acc[j+7],0.2f));
      *(uint4*)(o + j/2) = w;
    }
  }
}

// ---------- weight -> f32 materialization (dtype per flag) ----------
struct WCvt {
  const void* src[34];
  int n[34];
  int dst[34];
};
__global__ void cvt_weights(const int* __restrict__ flag, WCvt c, float* __restrict__ base){
  int i = blockIdx.y;
  int t = blockIdx.x * 256 + threadIdx.x;
  if (t >= c.n[i]) return;
  float v = flag[0] ? ((const float*)c.src[i])[t]
                    : bflo((u32)((const u16*)c.src[i])[t]);
  base[c.dst[i] + t] = v;
}

extern "C" void kernel_launch(void* const* d_in, const int* in_sizes, int n_in,
                              void* d_out, int out_size, void* d_ws, size_t ws_size,
                              hipStream_t stream) {
  (void)n_in; (void)out_size;
  // input order: 0 user_emb, 1 item_emb, 2 rating_emb, 3..36 weights (34),
  // 37 user_e, 38 item_e, 39 rating_e, 40 trust_e, 41 trustee_e
  const void* user_emb   = d_in[0];
  const void* item_emb   = d_in[1];
  const void* rating_emb = d_in[2];
  const int* user_e     = (const int*)d_in[37];
  const int* item_e     = (const int*)d_in[38];
  const int* rating_e   = (const int*)d_in[39];
  const int* trust_e    = (const int*)d_in[40];
  const int* trustee_e  = (const int*)d_in[41];

  float* W = (float*)d_ws;
  int woff[34]; int tot = 0;
  for (int i = 0; i < 34; ++i){ woff[i] = tot; tot += in_sizes[3 + i]; }

  size_t off = 84000;                  // f32 weight region (83,011 used)
  float* sumI  = W + off; off += U_N;
  float* sumS  = W + off; off += U_N;
  float* sumU  = W + off; off += I_N;
  float* hIacc = W + off; off += (size_t)U_N * 64;
  float* hSacc = W + off; off += (size_t)U_N * 64;
  float* zacc  = W + off; off += (size_t)I_N * 64;
  size_t zero_floats = off - 84000;    // 16,250,000
  float* escI  = W + off; off += EUI_N;
  float* escU  = W + off; off += EUI_N;
  float* escS  = W + off; off += EUU_N;
  u16*   hIbf  = (u16*)(W + off); off += (size_t)U_N * 64 / 2;
  int*   dflag = (int*)(W + off); off += 16;
  if (ws_size < off * 4) return;       // workspace too small: bail without OOB

  // zero accumulators / softmax denominators (replays must be identical)
  hipMemsetAsync(sumI, 0, zero_floats * 4, stream);

  // dtype sniff (one wave) -> dflag
  sniff_kernel<<<1, 64, 0, stream>>>((const float*)user_emb, dflag);

  // weights -> f32
  WCvt c;
  for (int i = 0; i < 34; ++i){
    c.src[i] = d_in[3 + i];
    c.n[i]   = in_sizes[3 + i];
    c.dst[i] = woff[i];
  }
  cvt_weights<<<dim3(33, 34), 256, 0, stream>>>(dflag, c, W);

  auto wf = [&](int idx){ return (const float*)(W + woff[idx - 3]); };
  const float *gv_w1=wf(3), *gv_b1=wf(4), *gv_w2=wf(5), *gv_b2=wf(6);
  const float *aI_w1=wf(7), *aI_b1=wf(8), *aI_w2=wf(9), *aI_b2=wf(10), *aI_w3=wf(11), *aI_b3=wf(12);
  const float *wI_w=wf(13), *wI_b=wf(14);
  const float *aS_w1=wf(15), *aS_b1=wf(16), *aS_w2=wf(17), *aS_b2=wf(18), *aS_w3=wf(19), *aS_b3=wf(20);
  const float *wS_w=wf(21), *wS_b=wf(22);
  const float *W2_w=wf(23), *W2_b=wf(24);
  const float *gu_w1=wf(25), *gu_b1=wf(26), *gu_w2=wf(27), *gu_b2=wf(28);
  const float *aU_w1=wf(29), *aU_b1=wf(30), *aU_w2=wf(31), *aU_b2=wf(32), *aU_w3=wf(33), *aU_b3=wf(34);
  const float *wU_w=wf(35), *wU_b=wf(36);

  const int gEUI = (EUI_N + 191) / 192;
  const int gEUU = (EUU_N + 191) / 192;

  // ---- ItemAgg ----
  edge_score_kernel<0><<<gEUI, 192, 0, stream>>>(dflag,
      item_emb, item_e, rating_emb, rating_e, user_emb, user_e,
      gv_w1, gv_b1, gv_w2, gv_b2, aI_w1, aI_b1, aI_w2, aI_b2, aI_w3, aI_b3,
      0.01f, escI, sumI, EUI_N);
  edge_score_kernel<1><<<gEUI, 192, 0, stream>>>(dflag,
      item_emb, item_e, rating_emb, rating_e, user_emb, user_e,
      gv_w1, gv_b1, gv_w2, gv_b2, aI_w1, aI_b1, aI_w2, aI_b2, aI_w3, aI_b3,
      0.01f, escI, sumI, EUI_N);
  edge_agg_kernel<0><<<gEUI, 192, 0, stream>>>(dflag,
      item_emb, item_e, rating_emb, rating_e, user_e,
      gv_w1, gv_b1, gv_w2, gv_b2, 0.01f, escI, sumI, hIacc, EUI_N);
  edge_agg_kernel<1><<<gEUI, 192, 0, stream>>>(dflag,
      item_emb, item_e, rating_emb, rating_e, user_e,
      gv_w1, gv_b1, gv_w2, gv_b2, 0.01f, escI, sumI, hIacc, EUI_N);
  rt_kernel<<<(U_N + 255) / 256, 256, 0, stream>>>(dflag, -1, 0,
      hIacc, wI_w, wI_b, hIbf, 0, U_N);            // internal hI (bf16)

  // ---- SocialAgg ----
  social_score_kernel<0><<<gEUU, 192, 0, stream>>>(dflag,
      user_emb, trust_e, hIbf, trustee_e,
      aS_w1, aS_b1, aS_w2, aS_b2, aS_w3, aS_b3, escS, sumS, EUU_N);
  social_score_kernel<1><<<gEUU, 192, 0, stream>>>(dflag,
      user_emb, trust_e, hIbf, trustee_e,
      aS_w1, aS_b1, aS_w2, aS_b2, aS_w3, aS_b3, escS, sumS, EUU_N);
  social_agg_kernel<<<(EUU_N + 255) / 256, 256, 0, stream>>>(
      trust_e, trustee_e, hIbf, escS, sumS, hSacc, EUU_N);
  hout_kernel<<<(U_N + 191) / 192, 192, 0, stream>>>(dflag, 0, 0,
      hSacc, wS_w, wS_b, hIbf, W2_w, W2_b, d_out, U_N);
  hout_kernel<<<(U_N + 191) / 192, 192, 0, stream>>>(dflag, 1, 1,
      hSacc, wS_w, wS_b, hIbf, W2_w, W2_b, d_out, U_N);

  // ---- UserAgg ----
  edge_score_kernel<0><<<gEUI, 192, 0, stream>>>(dflag,
      user_emb, user_e, rating_emb, rating_e, item_emb, item_e,
      gu_w1, gu_b1, gu_w2, gu_b2, aU_w1, aU_b1, aU_w2, aU_b2, aU_w3, aU_b3,
      0.0f, escU, sumU, EUI_N);
  edge_score_kernel<1><<<gEUI, 192, 0, stream>>>(dflag,
      user_emb, user_e, rating_emb, rating_e, item_emb, item_e,
      gu_w1, gu_b1, gu_w2, gu_b2, aU_w1, aU_b1, aU_w2, aU_b2, aU_w3, aU_b3,
      0.0f, escU, sumU, EUI_N);
  edge_agg_kernel<0><<<gEUI, 192, 0, stream>>>(dflag,
      user_emb, user_e, rating_emb, rating_e, item_e,
      gu_w1, gu_b1, gu_w2, gu_b2, 0.0f, escU, sumU, zacc, EUI_N);
  edge_agg_kernel<1><<<gEUI, 192, 0, stream>>>(dflag,
      user_emb, user_e, rating_emb, rating_e, item_e,
      gu_w1, gu_b1, gu_w2, gu_b2, 0.0f, escU, sumU, zacc, EUI_N);
  rt_kernel<<<(I_N + 255) / 256, 256, 0, stream>>>(dflag, 0, 0,
      zacc, wU_w, wU_b, d_out, U_N, I_N);          // z rows at offset U_N (bf16 out)
  rt_kernel<<<(I_N + 255) / 256, 256, 0, stream>>>(dflag, 1, 1,
      zacc, wU_w, wU_b, d_out, U_N, I_N);          // z rows at offset U_N (f32 out)
}

// Round 3
// 1786.679 us; speedup vs baseline: 6.0256x; 6.0256x over previous
//
#include <hip/hip_runtime.h>

// GraphRec forward, MI355X. Round 3: CSR aggregation (no f32 atomics) +
// (pair,rating)-keyed bf16 tables (X = value-MLP out, Y = att-layer1 src half,
// D = att-layer1 dst half) + LDS-staged weights + fused finalize transforms.
// Inputs f32, output f32 (confirmed by round-2 pass). Internal tables bf16.

typedef unsigned int   u32;
typedef unsigned short u16;

#define U_N   100000
#define I_N   50000
#define EUI_E 1000000
#define EUU_E 500000

// ---------- helpers ----------
__device__ __forceinline__ float bflo(u32 u){ return __uint_as_float(u << 16); }
__device__ __forceinline__ float bfhi(u32 u){ return __uint_as_float(u & 0xffff0000u); }
__device__ __forceinline__ u16 f2bf(float f){
  u32 x = __float_as_uint(f);
  x += 0x7fffu + ((x >> 16) & 1u);
  return (u16)(x >> 16);
}
__device__ __forceinline__ u32 pk2(float a, float b){
  return (u32)f2bf(a) | ((u32)f2bf(b) << 16);
}
__device__ __forceinline__ float actf(float x, float s){ return fmaxf(x, x * s); }
__device__ __forceinline__ void cvt8(uint4 q, float f[8]){
  f[0]=bflo(q.x); f[1]=bfhi(q.x); f[2]=bflo(q.y); f[3]=bfhi(q.y);
  f[4]=bflo(q.z); f[5]=bfhi(q.z); f[6]=bflo(q.w); f[7]=bfhi(q.w);
}

// ---------- CSR build ----------
__global__ void hist_k(const int* __restrict__ idx, int* __restrict__ deg, int E){
  int e = blockIdx.x*256 + threadIdx.x;
  if (e < E) atomicAdd(&deg[idx[e]], 1);
}
__global__ void scan1_k(const int* __restrict__ deg, int* __restrict__ part,
                        int* __restrict__ blk, int N){
  __shared__ int sh[256];
  int i = blockIdx.x*256 + threadIdx.x;
  sh[threadIdx.x] = (i < N) ? deg[i] : 0;
  __syncthreads();
  for (int o = 1; o < 256; o <<= 1){
    int t = (threadIdx.x >= o) ? sh[threadIdx.x - o] : 0;
    __syncthreads();
    sh[threadIdx.x] += t;
    __syncthreads();
  }
  if (i < N) part[i] = sh[threadIdx.x];
  if (threadIdx.x == 255) blk[blockIdx.x] = sh[255];
}
__global__ void scan2_k(int* __restrict__ blk, int nb){  // 1 block, 512 threads, nb<=512
  __shared__ int sh[512];
  sh[threadIdx.x] = (threadIdx.x < nb) ? blk[threadIdx.x] : 0;
  __syncthreads();
  for (int o = 1; o < 512; o <<= 1){
    int t = (threadIdx.x >= o) ? sh[threadIdx.x - o] : 0;
    __syncthreads();
    sh[threadIdx.x] += t;
    __syncthreads();
  }
  if (threadIdx.x < nb) blk[threadIdx.x] = sh[threadIdx.x];
}
__global__ void scan3_k(const int* __restrict__ part, const int* __restrict__ blk,
                        int* __restrict__ rowptr, int N){
  int i = blockIdx.x*256 + threadIdx.x;
  if (i >= N) return;
  int add = blockIdx.x ? blk[blockIdx.x - 1] : 0;
  rowptr[i + 1] = part[i] + add;
  if (i == 0) rowptr[0] = 0;
}
__global__ void scatter_k(const int* __restrict__ idx, const int* __restrict__ rowptr,
                          int* __restrict__ cur, int* __restrict__ eids, int E){
  int e = blockIdx.x*256 + threadIdx.x;
  if (e >= E) return;
  int d = idx[e];
  int pos = rowptr[d] + atomicAdd(&cur[d], 1);
  eids[pos] = e;
}

// ---------- pair-table value MLP: X[p] = mlp(cat(embA[p/5], embR[p%5])) ----------
__global__ void __launch_bounds__(256) pair_mlp_k(
    const float* __restrict__ embA, const float* __restrict__ embR,
    const float* __restrict__ W1, const float* __restrict__ b1,
    const float* __restrict__ W2, const float* __restrict__ b2,
    float slope, int plo, int phi, u16* __restrict__ X)
{
  __shared__ __align__(16) float w1s[128*64];
  __shared__ __align__(16) float w2s[64*64];
  __shared__ float b1s[64], b2s[64], rrs[5*64];
  for (int t = threadIdx.x; t < 128*64; t += 256) w1s[t] = W1[t];
  for (int t = threadIdx.x; t < 64*64;  t += 256) w2s[t] = W2[t];
  if (threadIdx.x < 64){ b1s[threadIdx.x] = b1[threadIdx.x]; b2s[threadIdx.x] = b2[threadIdx.x]; }
  for (int t = threadIdx.x; t < 320; t += 256) rrs[t] = embR[t];
  __syncthreads();
  int p = plo + blockIdx.x*256 + threadIdx.x;
  if (p >= phi) return;
  int i = p / 5, r = p - 5*i;
  const float* ea = embA + (size_t)i * 64;
  float acc[64];
  #pragma unroll
  for (int j = 0; j < 64; ++j) acc[j] = b1s[j];
  #pragma unroll 2
  for (int k = 0; k < 64; k += 4){
    float4 q = *(const float4*)(ea + k);
    #pragma unroll
    for (int u = 0; u < 4; ++u){
      float v = (&q.x)[u];
      const float4* wr = (const float4*)&w1s[(k + u)*64];
      #pragma unroll
      for (int j = 0; j < 16; ++j){
        float4 w = wr[j];
        acc[4*j  ] = fmaf(v, w.x, acc[4*j  ]);
        acc[4*j+1] = fmaf(v, w.y, acc[4*j+1]);
        acc[4*j+2] = fmaf(v, w.z, acc[4*j+2]);
        acc[4*j+3] = fmaf(v, w.w, acc[4*j+3]);
      }
    }
  }
  const float* rrow = &rrs[r*64];
  #pragma unroll 2
  for (int k = 0; k < 64; k += 4){
    #pragma unroll
    for (int u = 0; u < 4; ++u){
      float v = rrow[k + u];
      const float4* wr = (const float4*)&w1s[(64 + k + u)*64];
      #pragma unroll
      for (int j = 0; j < 16; ++j){
        float4 w = wr[j];
        acc[4*j  ] = fmaf(v, w.x, acc[4*j  ]);
        acc[4*j+1] = fmaf(v, w.y, acc[4*j+1]);
        acc[4*j+2] = fmaf(v, w.z, acc[4*j+2]);
        acc[4*j+3] = fmaf(v, w.w, acc[4*j+3]);
      }
    }
  }
  float x2[64];
  #pragma unroll
  for (int j = 0; j < 64; ++j) x2[j] = actf(acc[j], slope);
  #pragma unroll
  for (int j = 0; j < 64; ++j) acc[j] = b2s[j];
  #pragma unroll
  for (int c = 0; c < 64; ++c){            // full unroll: x2[c] stays in VGPRs
    float v = x2[c];
    const float4* wr = (const float4*)&w2s[c*64];
    #pragma unroll
    for (int j = 0; j < 16; ++j){
      float4 w = wr[j];
      acc[4*j  ] = fmaf(v, w.x, acc[4*j  ]);
      acc[4*j+1] = fmaf(v, w.y, acc[4*j+1]);
      acc[4*j+2] = fmaf(v, w.z, acc[4*j+2]);
      acc[4*j+3] = fmaf(v, w.w, acc[4*j+3]);
    }
  }
  u32* o = (u32*)(X + (size_t)(p - plo) * 64);
  #pragma unroll
  for (int j = 0; j < 64; j += 8){
    uint4 w;
    w.x = pk2(actf(acc[j  ],slope), actf(acc[j+1],slope));
    w.y = pk2(actf(acc[j+2],slope), actf(acc[j+3],slope));
    w.z = pk2(actf(acc[j+4],slope), actf(acc[j+5],slope));
    w.w = pk2(actf(acc[j+6],slope), actf(acc[j+7],slope));
    *(uint4*)(o + j/2) = w;
  }
}

// ---------- generic linear: out_bf16[r] = in[r] @ W (+ b) ----------
template<int INF32, int BIAS>
__global__ void __launch_bounds__(256) linear_k(
    const void* __restrict__ in, const float* __restrict__ W, const float* __restrict__ b,
    u16* __restrict__ out, int N)
{
  __shared__ __align__(16) float ws[64*64];
  __shared__ float bs[64];
  for (int t = threadIdx.x; t < 4096; t += 256) ws[t] = W[t];
  if (threadIdx.x < 64) bs[threadIdx.x] = BIAS ? b[threadIdx.x] : 0.0f;
  __syncthreads();
  int r = blockIdx.x*256 + threadIdx.x;
  if (r >= N) return;
  float acc[64];
  #pragma unroll
  for (int j = 0; j < 64; ++j) acc[j] = bs[j];
  if (INF32){
    const float* row = (const float*)in + (size_t)r * 64;
    #pragma unroll 2
    for (int k = 0; k < 64; k += 4){
      float4 q = *(const float4*)(row + k);
      #pragma unroll
      for (int u = 0; u < 4; ++u){
        float v = (&q.x)[u];
        const float4* wr = (const float4*)&ws[(k + u)*64];
        #pragma unroll
        for (int j = 0; j < 16; ++j){
          float4 w = wr[j];
          acc[4*j  ] = fmaf(v, w.x, acc[4*j  ]);
          acc[4*j+1] = fmaf(v, w.y, acc[4*j+1]);
          acc[4*j+2] = fmaf(v, w.z, acc[4*j+2]);
          acc[4*j+3] = fmaf(v, w.w, acc[4*j+3]);
        }
      }
    }
  } else {
    const u16* row = (const u16*)in + (size_t)r * 64;
    #pragma unroll 1
    for (int k = 0; k < 64; k += 8){
      uint4 q = *(const uint4*)(row + k);
      float f[8]; cvt8(q, f);
      #pragma unroll
      for (int u = 0; u < 8; ++u){
        float v = f[u];
        const float4* wr = (const float4*)&ws[(k + u)*64];
        #pragma unroll
        for (int j = 0; j < 16; ++j){
          float4 w = wr[j];
          acc[4*j  ] = fmaf(v, w.x, acc[4*j  ]);
          acc[4*j+1] = fmaf(v, w.y, acc[4*j+1]);
          acc[4*j+2] = fmaf(v, w.z, acc[4*j+2]);
          acc[4*j+3] = fmaf(v, w.w, acc[4*j+3]);
        }
      }
    }
  }
  u32* o = (u32*)(out + (size_t)r * 64);
  #pragma unroll
  for (int j = 0; j < 64; j += 8){
    uint4 w;
    w.x = pk2(acc[j  ], acc[j+1]);
    w.y = pk2(acc[j+2], acc[j+3]);
    w.z = pk2(acc[j+4], acc[j+5]);
    w.w = pk2(acc[j+6], acc[j+7]);
    *(uint4*)(o + j/2) = w;
  }
}

// ---------- per-edge attention score: esc[e]=exp(w3 . relu(W2 . relu(Y[key]+D[dst]) + b2) + b3) ----------
__global__ void __launch_bounds__(256) score_k(
    const int* __restrict__ keyI, const int* __restrict__ ratI, int kmul,
    const int* __restrict__ dstI,
    const u16* __restrict__ Ytab, int klo, int khi,
    const u16* __restrict__ Dtab,
    const float* __restrict__ W2, const float* __restrict__ b2,
    const float* __restrict__ w3, const float* __restrict__ b3,
    float* __restrict__ esc, int E)
{
  __shared__ __align__(16) float w2s[64*64];
  __shared__ float b2s[64], w3s[64];
  for (int t = threadIdx.x; t < 4096; t += 256) w2s[t] = W2[t];
  if (threadIdx.x < 64){ b2s[threadIdx.x] = b2[threadIdx.x]; w3s[threadIdx.x] = w3[threadIdx.x]; }
  __syncthreads();
  int e = blockIdx.x*256 + threadIdx.x;
  if (e >= E) return;
  int key = keyI[e]*kmul + (ratI ? ratI[e] : 0);
  if (key < klo || key >= khi) return;
  const u16* Y = Ytab + (size_t)(key - klo) * 64;
  const u16* D = Dtab + (size_t)dstI[e] * 64;
  float pre[64];
  #pragma unroll
  for (int k = 0; k < 64; k += 8){
    uint4 qy = *(const uint4*)(Y + k);
    uint4 qd = *(const uint4*)(D + k);
    float fy[8], fd[8]; cvt8(qy, fy); cvt8(qd, fd);
    #pragma unroll
    for (int u = 0; u < 8; ++u) pre[k + u] = fmaxf(fy[u] + fd[u], 0.0f);
  }
  float acc[64];
  #pragma unroll
  for (int j = 0; j < 64; ++j) acc[j] = b2s[j];
  #pragma unroll
  for (int c = 0; c < 64; ++c){            // full unroll keeps pre[c] static
    float v = pre[c];
    const float4* wr = (const float4*)&w2s[c*64];
    #pragma unroll
    for (int j = 0; j < 16; ++j){
      float4 w = wr[j];
      acc[4*j  ] = fmaf(v, w.x, acc[4*j  ]);
      acc[4*j+1] = fmaf(v, w.y, acc[4*j+1]);
      acc[4*j+2] = fmaf(v, w.z, acc[4*j+2]);
      acc[4*j+3] = fmaf(v, w.w, acc[4*j+3]);
    }
  }
  float s0 = 0.f, s1 = 0.f, s2 = 0.f, s3 = 0.f;
  #pragma unroll
  for (int j = 0; j < 64; j += 4){
    s0 = fmaf(fmaxf(acc[j  ],0.f), w3s[j  ], s0);
    s1 = fmaf(fmaxf(acc[j+1],0.f), w3s[j+1], s1);
    s2 = fmaf(fmaxf(acc[j+2],0.f), w3s[j+2], s2);
    s3 = fmaf(fmaxf(acc[j+3],0.f), w3s[j+3], s3);
  }
  float sc = b3[0] + ((s0 + s1) + (s2 + s3));
  esc[e] = __expf(sc);   // |sc| <~ 2: identical math to max-subtracted softmax
}

// ---------- per-dst softmax denominator ----------
__global__ void sdst_k(const int* __restrict__ rowptr, const int* __restrict__ eids,
                       const float* __restrict__ esc, float* __restrict__ sdst, int N){
  int d = blockIdx.x*256 + threadIdx.x;
  if (d >= N) return;
  int a = rowptr[d], b = rowptr[d+1];
  float s = 0.f;
  for (int k = a; k < b; ++k) s += esc[eids[k]];
  sdst[d] = s;
}

// ---------- segmented accumulate: acc[d] += sum_e esc[e] * X[key(e)] ----------
template<int XF32>
__global__ void __launch_bounds__(256) agg_k(
    const int* __restrict__ rowptr, const int* __restrict__ eids,
    const int* __restrict__ keyI, const int* __restrict__ ratI, int kmul,
    const float* __restrict__ esc, const void* __restrict__ Xtab,
    int klo, int khi, float* __restrict__ acc, int N)
{
  int d = blockIdx.x*256 + threadIdx.x;
  if (d >= N) return;
  float a[64];
  float* ar = acc + (size_t)d * 64;
  #pragma unroll
  for (int j = 0; j < 64; j += 4){
    float4 q = *(const float4*)(ar + j);
    a[j]=q.x; a[j+1]=q.y; a[j+2]=q.z; a[j+3]=q.w;
  }
  int s0 = rowptr[d], s1 = rowptr[d+1];
  for (int k = s0; k < s1; ++k){
    int e = eids[k];
    int key = keyI[e]*kmul + (ratI ? ratI[e] : 0);
    if (key < klo || key >= khi) continue;
    float w = esc[e];
    if (XF32){
      const float* xr = (const float*)Xtab + (size_t)key * 64;   // full-key (hI)
      #pragma unroll
      for (int j = 0; j < 64; j += 4){
        float4 q = *(const float4*)(xr + j);
        a[j]   = fmaf(w, q.x, a[j]);
        a[j+1] = fmaf(w, q.y, a[j+1]);
        a[j+2] = fmaf(w, q.z, a[j+2]);
        a[j+3] = fmaf(w, q.w, a[j+3]);
      }
    } else {
      const u16* xr = (const u16*)Xtab + (size_t)(key - klo) * 64;
      #pragma unroll
      for (int kk = 0; kk < 64; kk += 8){
        uint4 q = *(const uint4*)(xr + kk);
        float f[8]; cvt8(q, f);
        #pragma unroll
        for (int u = 0; u < 8; ++u) a[kk+u] = fmaf(w, f[u], a[kk+u]);
      }
    }
  }
  #pragma unroll
  for (int j = 0; j < 64; j += 4)
    *(float4*)(ar + j) = make_float4(a[j], a[j+1], a[j+2], a[j+3]);
}

// ---------- finalize: out[r] = leaky0.2((acc[r]/s) @ W + b), f32 out ----------
__global__ void __launch_bounds__(256) fin_gemv_k(
    const float* __restrict__ acc, const float* __restrict__ sdst,
    const float* __restrict__ W, const float* __restrict__ b,
    float* __restrict__ out, int N)
{
  __shared__ __align__(16) float ws[64*64];
  __shared__ float bs[64];
  for (int t = threadIdx.x; t < 4096; t += 256) ws[t] = W[t];
  if (threadIdx.x < 64) bs[threadIdx.x] = b[threadIdx.x];
  __syncthreads();
  int d = blockIdx.x*256 + threadIdx.x;
  if (d >= N) return;
  float s = sdst[d];
  float inv = (s > 0.f) ? 1.0f / s : 0.0f;
  const float* ar = acc + (size_t)d * 64;
  float h[64];
  #pragma unroll
  for (int j = 0; j < 64; j += 4){
    float4 q = *(const float4*)(ar + j);
    h[j]=q.x*inv; h[j+1]=q.y*inv; h[j+2]=q.z*inv; h[j+3]=q.w*inv;
  }
  float o[64];
  #pragma unroll
  for (int j = 0; j < 64; ++j) o[j] = bs[j];
  #pragma unroll
  for (int c = 0; c < 64; ++c){
    float v = h[c];
    const float4* wr = (const float4*)&ws[c*64];
    #pragma unroll
    for (int j = 0; j < 16; ++j){
      float4 w = wr[j];
      o[4*j  ] = fmaf(v, w.x, o[4*j  ]);
      o[4*j+1] = fmaf(v, w.y, o[4*j+1]);
      o[4*j+2] = fmaf(v, w.z, o[4*j+2]);
      o[4*j+3] = fmaf(v, w.w, o[4*j+3]);
    }
  }
  float* orow = out + (size_t)d * 64;
  #pragma unroll
  for (int j = 0; j < 64; j += 4)
    *(float4*)(orow + j) = make_float4(actf(o[j],0.2f), actf(o[j+1],0.2f),
                                       actf(o[j+2],0.2f), actf(o[j+3],0.2f));
}

// ---------- social finalize: hS = leaky0.2((accS/s)@wS+bS); out = leaky0.2(cat(hI,hS)@W2+b2) ----------
__global__ void __launch_bounds__(256) fin_social_k(
    const float* __restrict__ accS, const float* __restrict__ sdst,
    const float* __restrict__ hI,
    const float* __restrict__ wS, const float* __restrict__ bS,
    const float* __restrict__ W2, const float* __restrict__ b2,
    float* __restrict__ out, int N)
{
  __shared__ __align__(16) float wsT[64*64];   // transposed wS: wsT[c*64+j] = wS[j*64+c]
  __shared__ __align__(16) float w2s[128*64];
  __shared__ float bSs[64], b2s[64];
  for (int t = threadIdx.x; t < 4096; t += 256){
    int rrow = t >> 6, col = t & 63;
    wsT[col*64 + rrow] = wS[t];
  }
  for (int t = threadIdx.x; t < 128*64; t += 256) w2s[t] = W2[t];
  if (threadIdx.x < 64){ bSs[threadIdx.x] = bS[threadIdx.x]; b2s[threadIdx.x] = b2[threadIdx.x]; }
  __syncthreads();
  int d = blockIdx.x*256 + threadIdx.x;
  if (d >= N) return;
  float s = sdst[d];
  float inv = (s > 0.f) ? 1.0f / s : 0.0f;
  const float* ar = accS + (size_t)d * 64;
  float hin[64];
  #pragma unroll
  for (int j = 0; j < 64; j += 4){
    float4 q = *(const float4*)(ar + j);
    hin[j]=q.x*inv; hin[j+1]=q.y*inv; hin[j+2]=q.z*inv; hin[j+3]=q.w*inv;
  }
  float o[64];
  #pragma unroll
  for (int j = 0; j < 64; ++j) o[j] = b2s[j];
  // cat part 1: hI row (streamed)
  const float* hrow = hI + (size_t)d * 64;
  #pragma unroll 2
  for (int k = 0; k < 64; k += 4){
    float4 q = *(const float4*)(hrow + k);
    #pragma unroll
    for (int u = 0; u < 4; ++u){
      float v = (&q.x)[u];
      const float4* wr = (const float4*)&w2s[(k + u)*64];
      #pragma unroll
      for (int j = 0; j < 16; ++j){
        float4 w = wr[j];
        o[4*j  ] = fmaf(v, w.x, o[4*j  ]);
        o[4*j+1] = fmaf(v, w.y, o[4*j+1]);
        o[4*j+2] = fmaf(v, w.z, o[4*j+2]);
        o[4*j+3] = fmaf(v, w.w, o[4*j+3]);
      }
    }
  }
  // cat part 2: hS computed per-channel then consumed
  #pragma unroll 1
  for (int c = 0; c < 64; ++c){
    float t0=0.f, t1=0.f, t2=0.f, t3=0.f;
    const float4* wc = (const float4*)&wsT[c*64];
    #pragma unroll
    for (int j = 0; j < 16; ++j){
      float4 w = wc[j];
      t0 = fmaf(hin[4*j  ], w.x, t0);
      t1 = fmaf(hin[4*j+1], w.y, t1);
      t2 = fmaf(hin[4*j+2], w.z, t2);
      t3 = fmaf(hin[4*j+3], w.w, t3);
    }
    float hSc = actf(((t0+t1)+(t2+t3)) + bSs[c], 0.2f);
    const float4* wr = (const float4*)&w2s[(64 + c)*64];
    #pragma unroll
    for (int j = 0; j < 16; ++j){
      float4 w = wr[j];
      o[4*j  ] = fmaf(hSc, w.x, o[4*j  ]);
      o[4*j+1] = fmaf(hSc, w.y, o[4*j+1]);
      o[4*j+2] = fmaf(hSc, w.z, o[4*j+2]);
      o[4*j+3] = fmaf(hSc, w.w, o[4*j+3]);
    }
  }
  float* orow = out + (size_t)d * 64;
  #pragma unroll
  for (int j = 0; j < 64; j += 4)
    *(float4*)(orow + j) = make_float4(actf(o[j],0.2f), actf(o[j+1],0.2f),
                                       actf(o[j+2],0.2f), actf(o[j+3],0.2f));
}

extern "C" void kernel_launch(void* const* d_in, const int* in_sizes, int n_in,
                              void* d_out, int out_size, void* d_ws, size_t ws_size,
                              hipStream_t stream) {
  (void)in_sizes; (void)n_in; (void)out_size;
  const float* user_emb   = (const float*)d_in[0];
  const float* item_emb   = (const float*)d_in[1];
  const float* rating_emb = (const float*)d_in[2];
  const float *gv_w1=(const float*)d_in[3],  *gv_b1=(const float*)d_in[4];
  const float *gv_w2=(const float*)d_in[5],  *gv_b2=(const float*)d_in[6];
  const float *aI_w1=(const float*)d_in[7],  *aI_b1=(const float*)d_in[8];
  const float *aI_w2=(const float*)d_in[9],  *aI_b2=(const float*)d_in[10];
  const float *aI_w3=(const float*)d_in[11], *aI_b3=(const float*)d_in[12];
  const float *wI_w =(const float*)d_in[13], *wI_b =(const float*)d_in[14];
  const float *aS_w1=(const float*)d_in[15], *aS_b1=(const float*)d_in[16];
  const float *aS_w2=(const float*)d_in[17], *aS_b2=(const float*)d_in[18];
  const float *aS_w3=(const float*)d_in[19], *aS_b3=(const float*)d_in[20];
  const float *wS_w =(const float*)d_in[21], *wS_b =(const float*)d_in[22];
  const float *W2_w =(const float*)d_in[23], *W2_b =(const float*)d_in[24];
  const float *gu_w1=(const float*)d_in[25], *gu_b1=(const float*)d_in[26];
  const float *gu_w2=(const float*)d_in[27], *gu_b2=(const float*)d_in[28];
  const float *aU_w1=(const float*)d_in[29], *aU_b1=(const float*)d_in[30];
  const float *aU_w2=(const float*)d_in[31], *aU_b2=(const float*)d_in[32];
  const float *aU_w3=(const float*)d_in[33], *aU_b3=(const float*)d_in[34];
  const float *wU_w =(const float*)d_in[35], *wU_b =(const float*)d_in[36];
  const int* user_e    = (const int*)d_in[37];
  const int* item_e    = (const int*)d_in[38];
  const int* rating_e  = (const int*)d_in[39];
  const int* trust_e   = (const int*)d_in[40];
  const int* trustee_e = (const int*)d_in[41];
  float* dout = (float*)d_out;

  // ---- workspace layout ----
  char* base = (char*)d_ws;
  size_t cur = 0;
  auto alloc = [&](size_t bytes)->char*{
    char* p = base + cur; cur += (bytes + 255) & ~(size_t)255; return p;
  };
  float* hI     = (float*)alloc((size_t)U_N * 64 * 4);   // 25.6 MB
  float* esc    = (float*)alloc((size_t)EUI_E * 4);      // 4 MB
  float* sdst   = (float*)alloc((size_t)U_N * 4);
  int*   rowptr = (int*)  alloc((size_t)(U_N + 1) * 4);
  int*   part   = (int*)  alloc((size_t)U_N * 4);
  int*   deg    = (int*)  alloc((size_t)U_N * 4);
  int*   eids   = (int*)  alloc((size_t)EUI_E * 4);      // 4 MB
  int*   blk    = (int*)  alloc(512 * 4);
  float* acc    = (float*)alloc((size_t)U_N * 64 * 4);   // 25.6 MB
  size_t fixed_end = cur;
  if (ws_size < fixed_end + 26000000) return;            // need >=26MB arena (known ws >= 88MB)
  char* tab = base + fixed_end;
  size_t arena = ws_size - fixed_end;

  auto cdiv = [](int a, int b){ return (a + b - 1) / b; };
  auto buildCSR = [&](const int* dstIdx, int E, int N){
    hipMemsetAsync(deg, 0, (size_t)N * 4, stream);
    hist_k<<<cdiv(E,256), 256, 0, stream>>>(dstIdx, deg, E);
    int nb = cdiv(N, 256);
    scan1_k<<<nb, 256, 0, stream>>>(deg, part, blk, N);
    scan2_k<<<1, 512, 0, stream>>>(blk, nb);
    scan3_k<<<nb, 256, 0, stream>>>(part, blk, rowptr, N);
    hipMemsetAsync(deg, 0, (size_t)N * 4, stream);
    scatter_k<<<cdiv(E,256), 256, 0, stream>>>(dstIdx, rowptr, deg, eids, E);
  };

  // ============ Phase 1: ItemAgg (dst = user) ============
  {
    buildCSR(user_e, EUI_E, U_N);
    const size_t DU_BYTES = (size_t)U_N * 64 * 2;                  // 12.8 MB
    u16* DU = (u16*)tab;
    u16* XI = (u16*)(tab + DU_BYTES);
    long long rem = (long long)arena - (long long)DU_BYTES;
    int cp = (int)(rem / 256);                                     // pairs per chunk (X+Y rows)
    if (cp < 1) return;
    if (cp > 250000) cp = 250000;
    u16* YI = XI + (size_t)cp * 64;
    linear_k<1,1><<<cdiv(U_N,256), 256, 0, stream>>>(user_emb, aI_w1 + 64*64, aI_b1, DU, U_N);
    hipMemsetAsync(acc, 0, (size_t)U_N * 64 * 4, stream);
    for (int plo = 0; plo < 250000; plo += cp){
      int phi = plo + cp; if (phi > 250000) phi = 250000;
      int n = phi - plo;
      pair_mlp_k<<<cdiv(n,256), 256, 0, stream>>>(item_emb, rating_emb,
          gv_w1, gv_b1, gv_w2, gv_b2, 0.01f, plo, phi, XI);
      linear_k<0,0><<<cdiv(n,256), 256, 0, stream>>>(XI, aI_w1, aI_b1 /*unused*/, YI, n);
      score_k<<<cdiv(EUI_E,256), 256, 0, stream>>>(item_e, rating_e, 5, user_e,
          YI, plo, phi, DU, aI_w2, aI_b2, aI_w3, aI_b3, esc, EUI_E);
      agg_k<0><<<cdiv(U_N,256), 256, 0, stream>>>(rowptr, eids, item_e, rating_e, 5,
          esc, XI, plo, phi, acc, U_N);
    }
    sdst_k<<<cdiv(U_N,256), 256, 0, stream>>>(rowptr, eids, esc, sdst, U_N);
    fin_gemv_k<<<cdiv(U_N,256), 256, 0, stream>>>(acc, sdst, wI_w, wI_b, hI, U_N);
  }

  // ============ Phase 2: SocialAgg (dst = trustee) ============
  {
    buildCSR(trustee_e, EUU_E, U_N);
    u16* SS = (u16*)tab;
    u16* SD = (u16*)(tab + (size_t)U_N * 64 * 2);
    if (arena < (size_t)U_N * 64 * 4) return;   // 25.6 MB
    linear_k<1,0><<<cdiv(U_N,256), 256, 0, stream>>>(user_emb, aS_w1, aS_b1, SS, U_N);
    linear_k<1,1><<<cdiv(U_N,256), 256, 0, stream>>>(hI, aS_w1 + 64*64, aS_b1, SD, U_N);
    score_k<<<cdiv(EUU_E,256), 256, 0, stream>>>(trust_e, (const int*)nullptr, 1, trustee_e,
        SS, 0, U_N, SD, aS_w2, aS_b2, aS_w3, aS_b3, esc, EUU_E);
    hipMemsetAsync(acc, 0, (size_t)U_N * 64 * 4, stream);
    agg_k<1><<<cdiv(U_N,256), 256, 0, stream>>>(rowptr, eids, trust_e, (const int*)nullptr, 1,
        esc, hI, 0, U_N, acc, U_N);
    sdst_k<<<cdiv(U_N,256), 256, 0, stream>>>(rowptr, eids, esc, sdst, U_N);
    fin_social_k<<<cdiv(U_N,256), 256, 0, stream>>>(acc, sdst, hI,
        wS_w, wS_b, W2_w, W2_b, dout, U_N);
  }

  // ============ Phase 3: UserAgg (dst = item) ============
  {
    buildCSR(item_e, EUI_E, I_N);
    const size_t DI_BYTES = (size_t)I_N * 64 * 2;                  // 6.4 MB
    u16* DI = (u16*)tab;
    u16* XU = (u16*)(tab + DI_BYTES);
    long long rem = (long long)arena - (long long)DI_BYTES;
    int cp = (int)(rem / 256);
    if (cp < 1) return;
    if (cp > 500000) cp = 500000;
    u16* YU = XU + (size_t)cp * 64;
    linear_k<1,1><<<cdiv(I_N,256), 256, 0, stream>>>(item_emb, aU_w1 + 64*64, aU_b1, DI, I_N);
    hipMemsetAsync(acc, 0, (size_t)I_N * 64 * 4, stream);
    for (int plo = 0; plo < 500000; plo += cp){
      int phi = plo + cp; if (phi > 500000) phi = 500000;
      int n = phi - plo;
      pair_mlp_k<<<cdiv(n,256), 256, 0, stream>>>(user_emb, rating_emb,
          gu_w1, gu_b1, gu_w2, gu_b2, 0.0f, plo, phi, XU);
      linear_k<0,0><<<cdiv(n,256), 256, 0, stream>>>(XU, aU_w1, aU_b1 /*unused*/, YU, n);
      score_k<<<cdiv(EUI_E,256), 256, 0, stream>>>(user_e, rating_e, 5, item_e,
          YU, plo, phi, DI, aU_w2, aU_b2, aU_w3, aU_b3, esc, EUI_E);
      agg_k<0><<<cdiv(I_N,256), 256, 0, stream>>>(rowptr, eids, user_e, rating_e, 5,
          esc, XU, plo, phi, acc, I_N);
    }
    sdst_k<<<cdiv(I_N,256), 256, 0, stream>>>(rowptr, eids, esc, sdst, I_N);
    fin_gemv_k<<<cdiv(I_N,256), 256, 0, stream>>>(acc, sdst, wU_w, wU_b,
        dout + (size_t)U_N * 64, I_N);
  }
}

// Round 4
// 1284.264 us; speedup vs baseline: 8.3828x; 1.3912x over previous
//
#include <hip/hip_runtime.h>

// GraphRec forward, MI355X. Round 4: MFMA table builders (pair MLP + linears),
// CSR aggregation, VALU score kernel (MFMA next round). In f32, out f32.

typedef unsigned int   u32;
typedef unsigned short u16;
typedef short bf16x8 __attribute__((ext_vector_type(8)));
typedef float f32x4  __attribute__((ext_vector_type(4)));

#define U_N   100000
#define I_N   50000
#define EUI_E 1000000
#define EUU_E 500000

// ---------- helpers ----------
__device__ __forceinline__ float bflo(u32 u){ return __uint_as_float(u << 16); }
__device__ __forceinline__ float bfhi(u32 u){ return __uint_as_float(u & 0xffff0000u); }
__device__ __forceinline__ u16 f2bf(float f){
  u32 x = __float_as_uint(f);
  x += 0x7fffu + ((x >> 16) & 1u);
  return (u16)(x >> 16);
}
__device__ __forceinline__ u32 pk2(float a, float b){
  return (u32)f2bf(a) | ((u32)f2bf(b) << 16);
}
__device__ __forceinline__ float actf(float x, float s){ return fmaxf(x, x * s); }
__device__ __forceinline__ void cvt8(uint4 q, float f[8]){
  f[0]=bflo(q.x); f[1]=bfhi(q.x); f[2]=bflo(q.y); f[3]=bfhi(q.y);
  f[4]=bflo(q.z); f[5]=bfhi(q.z); f[6]=bflo(q.w); f[7]=bfhi(q.w);
}

// ---------- MFMA fragment helpers (16x16x32 bf16) ----------
// A: lane l holds row (l&15), k = 8*(l>>4)+j. B: col (l&15), k = 8*(l>>4)+j.
// D: col (l&15), row = 4*(l>>4)+reg  [m89-verified].
__device__ __forceinline__ bf16x8 bfrag(const float* __restrict__ W, int kt, int nt, int l){
  int c = l & 15, g = l >> 4;
  const float* p = W + (size_t)(kt*32 + g*8) * 64 + nt*16 + c;
  bf16x8 r;
  #pragma unroll
  for (int j = 0; j < 8; ++j) r[j] = (short)f2bf(p[(size_t)j * 64]);
  return r;
}
__device__ __forceinline__ bf16x8 afrag_f32(const float* p){
  float4 a = *(const float4*)p, b = *(const float4*)(p + 4);
  bf16x8 r;
  r[0]=(short)f2bf(a.x); r[1]=(short)f2bf(a.y); r[2]=(short)f2bf(a.z); r[3]=(short)f2bf(a.w);
  r[4]=(short)f2bf(b.x); r[5]=(short)f2bf(b.y); r[6]=(short)f2bf(b.z); r[7]=(short)f2bf(b.w);
  return r;
}
#define LDT 68   // LDS row stride (floats): 2-way bank aliasing only (free)
__device__ __forceinline__ void dwrite(float* lb, const f32x4* acc, float slope, int l){
  int c = l & 15, g = l >> 4;
  #pragma unroll
  for (int nt = 0; nt < 4; ++nt){
    #pragma unroll
    for (int rg = 0; rg < 4; ++rg)
      lb[(4*g + rg)*LDT + nt*16 + c] = actf(acc[nt][rg], slope);
  }
}
__device__ __forceinline__ bf16x8 afrag_lds(const float* lb, int kt, int l){
  int r = l & 15, g = l >> 4;
  return afrag_f32(lb + r*LDT + kt*32 + g*8);
}
__device__ __forceinline__ void store_rows(const float* lb, u16* out, int base, int nrows, int l){
  int r = l >> 2, q = l & 3;
  if (r >= nrows) return;
  const float* src = lb + r*LDT + q*16;
  float4 a = *(const float4*)src, b = *(const float4*)(src+4);
  float4 c = *(const float4*)(src+8), d = *(const float4*)(src+12);
  uint4 w0, w1;
  w0.x = pk2(a.x,a.y); w0.y = pk2(a.z,a.w); w0.z = pk2(b.x,b.y); w0.w = pk2(b.z,b.w);
  w1.x = pk2(c.x,c.y); w1.y = pk2(c.z,c.w); w1.z = pk2(d.x,d.y); w1.w = pk2(d.z,d.w);
  u32* dst = (u32*)(out + ((size_t)(base + r))*64 + q*16);
  *(uint4*)dst = w0;
  *(uint4*)(dst + 4) = w1;
}
#define MFMA(a,b,c) __builtin_amdgcn_mfma_f32_16x16x32_bf16((a),(b),(c),0,0,0)

// ---------- fused pair-table builder: X = act2(act1(cat(embA[p/5],embR[p%5])@W1+b1)@W2+b2); Y = X@Wy ----------
__global__ void __launch_bounds__(256) mfma_pair_k(
    const float* __restrict__ embA, const float* __restrict__ embR,
    const float* __restrict__ W1, const float* __restrict__ b1,
    const float* __restrict__ W2, const float* __restrict__ b2,
    const float* __restrict__ Wy,
    float slope, int plo, int phi, u16* __restrict__ X, u16* __restrict__ Y)
{
  __shared__ float lbuf[4][2][16*LDT];
  int l   = threadIdx.x & 63;
  int wid = threadIdx.x >> 6;
  float* lb0 = lbuf[wid][0];
  float* lb1 = lbuf[wid][1];
  int c = l & 15, g = l >> 4; (void)g;
  bf16x8 w1f[4][4], w2f[2][4], wyf[2][4];
  #pragma unroll
  for (int kt = 0; kt < 4; ++kt)
    #pragma unroll
    for (int nt = 0; nt < 4; ++nt) w1f[kt][nt] = bfrag(W1, kt, nt, l);
  #pragma unroll
  for (int kt = 0; kt < 2; ++kt)
    #pragma unroll
    for (int nt = 0; nt < 4; ++nt){ w2f[kt][nt] = bfrag(W2, kt, nt, l); wyf[kt][nt] = bfrag(Wy, kt, nt, l); }
  float bias1[4], bias2[4];
  #pragma unroll
  for (int nt = 0; nt < 4; ++nt){ bias1[nt] = b1[nt*16 + c]; bias2[nt] = b2[nt*16 + c]; }

  int n = phi - plo;
  int ngrp = (n + 15) >> 4;
  for (int grp = blockIdx.x*4 + wid; grp < ngrp; grp += gridDim.x*4){
    int base = grp * 16;
    int p = plo + base + (l & 15);
    if (p >= phi) p = phi - 1;
    int i = p / 5, r = p - 5*i;
    const float* ra = embA + (size_t)i * 64;
    const float* rr = embR + (size_t)r * 64;
    bf16x8 a0 = afrag_f32(ra + (l>>4)*8);
    bf16x8 a1 = afrag_f32(ra + 32 + (l>>4)*8);
    bf16x8 a2 = afrag_f32(rr + (l>>4)*8);
    bf16x8 a3 = afrag_f32(rr + 32 + (l>>4)*8);
    f32x4 acc[4];
    #pragma unroll
    for (int nt = 0; nt < 4; ++nt){
      f32x4 v; v[0]=bias1[nt]; v[1]=bias1[nt]; v[2]=bias1[nt]; v[3]=bias1[nt];
      v = MFMA(a0, w1f[0][nt], v);
      v = MFMA(a1, w1f[1][nt], v);
      v = MFMA(a2, w1f[2][nt], v);
      v = MFMA(a3, w1f[3][nt], v);
      acc[nt] = v;
    }
    dwrite(lb0, acc, slope, l);
    bf16x8 x0 = afrag_lds(lb0, 0, l);
    bf16x8 x1 = afrag_lds(lb0, 1, l);
    #pragma unroll
    for (int nt = 0; nt < 4; ++nt){
      f32x4 v; v[0]=bias2[nt]; v[1]=bias2[nt]; v[2]=bias2[nt]; v[3]=bias2[nt];
      v = MFMA(x0, w2f[0][nt], v);
      v = MFMA(x1, w2f[1][nt], v);
      acc[nt] = v;
    }
    dwrite(lb1, acc, slope, l);
    int nrows = n - base; if (nrows > 16) nrows = 16;
    store_rows(lb1, X, base, nrows, l);
    bf16x8 y0 = afrag_lds(lb1, 0, l);
    bf16x8 y1 = afrag_lds(lb1, 1, l);
    #pragma unroll
    for (int nt = 0; nt < 4; ++nt){
      f32x4 v; v[0]=0.f; v[1]=0.f; v[2]=0.f; v[3]=0.f;
      v = MFMA(y0, wyf[0][nt], v);
      v = MFMA(y1, wyf[1][nt], v);
      acc[nt] = v;
    }
    dwrite(lb0, acc, 1.0f, l);   // identity
    store_rows(lb0, Y, base, nrows, l);
  }
}

// ---------- single linear: out_bf16 = A[N x 64] @ W[64 x 64] (+ b) ----------
__global__ void __launch_bounds__(256) mfma_lin_k(
    const float* __restrict__ A, const float* __restrict__ W, const float* __restrict__ b,
    int has_bias, u16* __restrict__ out, int N)
{
  __shared__ float lbuf[4][16*LDT];
  int l   = threadIdx.x & 63;
  int wid = threadIdx.x >> 6;
  float* lb = lbuf[wid];
  int c = l & 15;
  bf16x8 wf[2][4];
  #pragma unroll
  for (int kt = 0; kt < 2; ++kt)
    #pragma unroll
    for (int nt = 0; nt < 4; ++nt) wf[kt][nt] = bfrag(W, kt, nt, l);
  float bias[4];
  #pragma unroll
  for (int nt = 0; nt < 4; ++nt) bias[nt] = has_bias ? b[nt*16 + c] : 0.0f;

  int ngrp = (N + 15) >> 4;
  for (int grp = blockIdx.x*4 + wid; grp < ngrp; grp += gridDim.x*4){
    int base = grp * 16;
    int ar = base + (l & 15);
    if (ar >= N) ar = N - 1;
    const float* row = A + (size_t)ar * 64;
    bf16x8 a0 = afrag_f32(row + (l>>4)*8);
    bf16x8 a1 = afrag_f32(row + 32 + (l>>4)*8);
    f32x4 acc[4];
    #pragma unroll
    for (int nt = 0; nt < 4; ++nt){
      f32x4 v; v[0]=bias[nt]; v[1]=bias[nt]; v[2]=bias[nt]; v[3]=bias[nt];
      v = MFMA(a0, wf[0][nt], v);
      v = MFMA(a1, wf[1][nt], v);
      acc[nt] = v;
    }
    dwrite(lb, acc, 1.0f, l);
    int nrows = N - base; if (nrows > 16) nrows = 16;
    store_rows(lb, out, base, nrows, l);
  }
}

// ---------- CSR build ----------
__global__ void hist_k(const int* __restrict__ idx, int* __restrict__ deg, int E){
  int e = blockIdx.x*256 + threadIdx.x;
  if (e < E) atomicAdd(&deg[idx[e]], 1);
}
__global__ void scan1_k(const int* __restrict__ deg, int* __restrict__ part,
                        int* __restrict__ blk, int N){
  __shared__ int sh[256];
  int i = blockIdx.x*256 + threadIdx.x;
  sh[threadIdx.x] = (i < N) ? deg[i] : 0;
  __syncthreads();
  for (int o = 1; o < 256; o <<= 1){
    int t = (threadIdx.x >= o) ? sh[threadIdx.x - o] : 0;
    __syncthreads();
    sh[threadIdx.x] += t;
    __syncthreads();
  }
  if (i < N) part[i] = sh[threadIdx.x];
  if (threadIdx.x == 255) blk[blockIdx.x] = sh[255];
}
__global__ void scan2_k(int* __restrict__ blk, int nb){
  __shared__ int sh[512];
  sh[threadIdx.x] = (threadIdx.x < nb) ? blk[threadIdx.x] : 0;
  __syncthreads();
  for (int o = 1; o < 512; o <<= 1){
    int t = (threadIdx.x >= o) ? sh[threadIdx.x - o] : 0;
    __syncthreads();
    sh[threadIdx.x] += t;
    __syncthreads();
  }
  if (threadIdx.x < nb) blk[threadIdx.x] = sh[threadIdx.x];
}
__global__ void scan3_k(const int* __restrict__ part, const int* __restrict__ blk,
                        int* __restrict__ rowptr, int N){
  int i = blockIdx.x*256 + threadIdx.x;
  if (i >= N) return;
  int add = blockIdx.x ? blk[blockIdx.x - 1] : 0;
  rowptr[i + 1] = part[i] + add;
  if (i == 0) rowptr[0] = 0;
}
__global__ void scatter_k(const int* __restrict__ idx, const int* __restrict__ rowptr,
                          int* __restrict__ cur, int* __restrict__ eids, int E){
  int e = blockIdx.x*256 + threadIdx.x;
  if (e >= E) return;
  int d = idx[e];
  int pos = rowptr[d] + atomicAdd(&cur[d], 1);
  eids[pos] = e;
}

// ---------- per-edge attention score ----------
__global__ void __launch_bounds__(256) score_k(
    const int* __restrict__ keyI, const int* __restrict__ ratI, int kmul,
    const int* __restrict__ dstI,
    const u16* __restrict__ Ytab, int klo, int khi,
    const u16* __restrict__ Dtab,
    const float* __restrict__ W2, const float* __restrict__ b2,
    const float* __restrict__ w3, const float* __restrict__ b3,
    float* __restrict__ esc, int E)
{
  __shared__ __align__(16) float w2s[64*64];
  __shared__ float b2s[64], w3s[64];
  for (int t = threadIdx.x; t < 4096; t += 256) w2s[t] = W2[t];
  if (threadIdx.x < 64){ b2s[threadIdx.x] = b2[threadIdx.x]; w3s[threadIdx.x] = w3[threadIdx.x]; }
  __syncthreads();
  int e = blockIdx.x*256 + threadIdx.x;
  if (e >= E) return;
  int key = keyI[e]*kmul + (ratI ? ratI[e] : 0);
  if (key < klo || key >= khi) return;
  const u16* Y = Ytab + (size_t)(key - klo) * 64;
  const u16* D = Dtab + (size_t)dstI[e] * 64;
  float pre[64];
  #pragma unroll
  for (int k = 0; k < 64; k += 8){
    uint4 qy = *(const uint4*)(Y + k);
    uint4 qd = *(const uint4*)(D + k);
    float fy[8], fd[8]; cvt8(qy, fy); cvt8(qd, fd);
    #pragma unroll
    for (int u = 0; u < 8; ++u) pre[k + u] = fmaxf(fy[u] + fd[u], 0.0f);
  }
  float acc[64];
  #pragma unroll
  for (int j = 0; j < 64; ++j) acc[j] = b2s[j];
  #pragma unroll
  for (int c = 0; c < 64; ++c){
    float v = pre[c];
    const float4* wr = (const float4*)&w2s[c*64];
    #pragma unroll
    for (int j = 0; j < 16; ++j){
      float4 w = wr[j];
      acc[4*j  ] = fmaf(v, w.x, acc[4*j  ]);
      acc[4*j+1] = fmaf(v, w.y, acc[4*j+1]);
      acc[4*j+2] = fmaf(v, w.z, acc[4*j+2]);
      acc[4*j+3] = fmaf(v, w.w, acc[4*j+3]);
    }
  }
  float s0 = 0.f, s1 = 0.f, s2 = 0.f, s3 = 0.f;
  #pragma unroll
  for (int j = 0; j < 64; j += 4){
    s0 = fmaf(fmaxf(acc[j  ],0.f), w3s[j  ], s0);
    s1 = fmaf(fmaxf(acc[j+1],0.f), w3s[j+1], s1);
    s2 = fmaf(fmaxf(acc[j+2],0.f), w3s[j+2], s2);
    s3 = fmaf(fmaxf(acc[j+3],0.f), w3s[j+3], s3);
  }
  float sc = b3[0] + ((s0 + s1) + (s2 + s3));
  esc[e] = __expf(sc);
}

// ---------- per-dst softmax denominator ----------
__global__ void sdst_k(const int* __restrict__ rowptr, const int* __restrict__ eids,
                       const float* __restrict__ esc, float* __restrict__ sdst, int N){
  int d = blockIdx.x*256 + threadIdx.x;
  if (d >= N) return;
  int a = rowptr[d], b = rowptr[d+1];
  float s = 0.f;
  for (int k = a; k < b; ++k) s += esc[eids[k]];
  sdst[d] = s;
}

// ---------- segmented accumulate ----------
template<int XF32>
__global__ void __launch_bounds__(256) agg_k(
    const int* __restrict__ rowptr, const int* __restrict__ eids,
    const int* __restrict__ keyI, const int* __restrict__ ratI, int kmul,
    const float* __restrict__ esc, const void* __restrict__ Xtab,
    int klo, int khi, float* __restrict__ acc, int N)
{
  int d = blockIdx.x*256 + threadIdx.x;
  if (d >= N) return;
  float a[64];
  float* ar = acc + (size_t)d * 64;
  #pragma unroll
  for (int j = 0; j < 64; j += 4){
    float4 q = *(const float4*)(ar + j);
    a[j]=q.x; a[j+1]=q.y; a[j+2]=q.z; a[j+3]=q.w;
  }
  int s0 = rowptr[d], s1 = rowptr[d+1];
  for (int k = s0; k < s1; ++k){
    int e = eids[k];
    int key = keyI[e]*kmul + (ratI ? ratI[e] : 0);
    if (key < klo || key >= khi) continue;
    float w = esc[e];
    if (XF32){
      const float* xr = (const float*)Xtab + (size_t)key * 64;
      #pragma unroll
      for (int j = 0; j < 64; j += 4){
        float4 q = *(const float4*)(xr + j);
        a[j]   = fmaf(w, q.x, a[j]);
        a[j+1] = fmaf(w, q.y, a[j+1]);
        a[j+2] = fmaf(w, q.z, a[j+2]);
        a[j+3] = fmaf(w, q.w, a[j+3]);
      }
    } else {
      const u16* xr = (const u16*)Xtab + (size_t)(key - klo) * 64;
      #pragma unroll
      for (int kk = 0; kk < 64; kk += 8){
        uint4 q = *(const uint4*)(xr + kk);
        float f[8]; cvt8(q, f);
        #pragma unroll
        for (int u = 0; u < 8; ++u) a[kk+u] = fmaf(w, f[u], a[kk+u]);
      }
    }
  }
  #pragma unroll
  for (int j = 0; j < 64; j += 4)
    *(float4*)(ar + j) = make_float4(a[j], a[j+1], a[j+2], a[j+3]);
}

// ---------- finalize kernels ----------
__global__ void __launch_bounds__(256) fin_gemv_k(
    const float* __restrict__ acc, const float* __restrict__ sdst,
    const float* __restrict__ W, const float* __restrict__ b,
    float* __restrict__ out, int N)
{
  __shared__ __align__(16) float ws[64*64];
  __shared__ float bs[64];
  for (int t = threadIdx.x; t < 4096; t += 256) ws[t] = W[t];
  if (threadIdx.x < 64) bs[threadIdx.x] = b[threadIdx.x];
  __syncthreads();
  int d = blockIdx.x*256 + threadIdx.x;
  if (d >= N) return;
  float s = sdst[d];
  float inv = (s > 0.f) ? 1.0f / s : 0.0f;
  const float* ar = acc + (size_t)d * 64;
  float h[64];
  #pragma unroll
  for (int j = 0; j < 64; j += 4){
    float4 q = *(const float4*)(ar + j);
    h[j]=q.x*inv; h[j+1]=q.y*inv; h[j+2]=q.z*inv; h[j+3]=q.w*inv;
  }
  float o[64];
  #pragma unroll
  for (int j = 0; j < 64; ++j) o[j] = bs[j];
  #pragma unroll
  for (int c = 0; c < 64; ++c){
    float v = h[c];
    const float4* wr = (const float4*)&ws[c*64];
    #pragma unroll
    for (int j = 0; j < 16; ++j){
      float4 w = wr[j];
      o[4*j  ] = fmaf(v, w.x, o[4*j  ]);
      o[4*j+1] = fmaf(v, w.y, o[4*j+1]);
      o[4*j+2] = fmaf(v, w.z, o[4*j+2]);
      o[4*j+3] = fmaf(v, w.w, o[4*j+3]);
    }
  }
  float* orow = out + (size_t)d * 64;
  #pragma unroll
  for (int j = 0; j < 64; j += 4)
    *(float4*)(orow + j) = make_float4(actf(o[j],0.2f), actf(o[j+1],0.2f),
                                       actf(o[j+2],0.2f), actf(o[j+3],0.2f));
}

__global__ void __launch_bounds__(256) fin_social_k(
    const float* __restrict__ accS, const float* __restrict__ sdst,
    const float* __restrict__ hI,
    const float* __restrict__ wS, const float* __restrict__ bS,
    const float* __restrict__ W2, const float* __restrict__ b2,
    float* __restrict__ out, int N)
{
  __shared__ __align__(16) float wsT[64*64];
  __shared__ __align__(16) float w2s[128*64];
  __shared__ float bSs[64], b2s[64];
  for (int t = threadIdx.x; t < 4096; t += 256){
    int rrow = t >> 6, col = t & 63;
    wsT[col*64 + rrow] = wS[t];
  }
  for (int t = threadIdx.x; t < 128*64; t += 256) w2s[t] = W2[t];
  if (threadIdx.x < 64){ bSs[threadIdx.x] = bS[threadIdx.x]; b2s[threadIdx.x] = b2[threadIdx.x]; }
  __syncthreads();
  int d = blockIdx.x*256 + threadIdx.x;
  if (d >= N) return;
  float s = sdst[d];
  float inv = (s > 0.f) ? 1.0f / s : 0.0f;
  const float* ar = accS + (size_t)d * 64;
  float hin[64];
  #pragma unroll
  for (int j = 0; j < 64; j += 4){
    float4 q = *(const float4*)(ar + j);
    hin[j]=q.x*inv; hin[j+1]=q.y*inv; hin[j+2]=q.z*inv; hin[j+3]=q.w*inv;
  }
  float o[64];
  #pragma unroll
  for (int j = 0; j < 64; ++j) o[j] = b2s[j];
  const float* hrow = hI + (size_t)d * 64;
  #pragma unroll 2
  for (int k = 0; k < 64; k += 4){
    float4 q = *(const float4*)(hrow + k);
    #pragma unroll
    for (int u = 0; u < 4; ++u){
      float v = (&q.x)[u];
      const float4* wr = (const float4*)&w2s[(k + u)*64];
      #pragma unroll
      for (int j = 0; j < 16; ++j){
        float4 w = wr[j];
        o[4*j  ] = fmaf(v, w.x, o[4*j  ]);
        o[4*j+1] = fmaf(v, w.y, o[4*j+1]);
        o[4*j+2] = fmaf(v, w.z, o[4*j+2]);
        o[4*j+3] = fmaf(v, w.w, o[4*j+3]);
      }
    }
  }
  #pragma unroll 1
  for (int c = 0; c < 64; ++c){
    float t0=0.f, t1=0.f, t2=0.f, t3=0.f;
    const float4* wc = (const float4*)&wsT[c*64];
    #pragma unroll
    for (int j = 0; j < 16; ++j){
      float4 w = wc[j];
      t0 = fmaf(hin[4*j  ], w.x, t0);
      t1 = fmaf(hin[4*j+1], w.y, t1);
      t2 = fmaf(hin[4*j+2], w.z, t2);
      t3 = fmaf(hin[4*j+3], w.w, t3);
    }
    float hSc = actf(((t0+t1)+(t2+t3)) + bSs[c], 0.2f);
    const float4* wr = (const float4*)&w2s[(64 + c)*64];
    #pragma unroll
    for (int j = 0; j < 16; ++j){
      float4 w = wr[j];
      o[4*j  ] = fmaf(hSc, w.x, o[4*j  ]);
      o[4*j+1] = fmaf(hSc, w.y, o[4*j+1]);
      o[4*j+2] = fmaf(hSc, w.z, o[4*j+2]);
      o[4*j+3] = fmaf(hSc, w.w, o[4*j+3]);
    }
  }
  float* orow = out + (size_t)d * 64;
  #pragma unroll
  for (int j = 0; j < 64; j += 4)
    *(float4*)(orow + j) = make_float4(actf(o[j],0.2f), actf(o[j+1],0.2f),
                                       actf(o[j+2],0.2f), actf(o[j+3],0.2f));
}

extern "C" void kernel_launch(void* const* d_in, const int* in_sizes, int n_in,
                              void* d_out, int out_size, void* d_ws, size_t ws_size,
                              hipStream_t stream) {
  (void)in_sizes; (void)n_in; (void)out_size;
  const float* user_emb   = (const float*)d_in[0];
  const float* item_emb   = (const float*)d_in[1];
  const float* rating_emb = (const float*)d_in[2];
  const float *gv_w1=(const float*)d_in[3],  *gv_b1=(const float*)d_in[4];
  const float *gv_w2=(const float*)d_in[5],  *gv_b2=(const float*)d_in[6];
  const float *aI_w1=(const float*)d_in[7],  *aI_b1=(const float*)d_in[8];
  const float *aI_w2=(const float*)d_in[9],  *aI_b2=(const float*)d_in[10];
  const float *aI_w3=(const float*)d_in[11], *aI_b3=(const float*)d_in[12];
  const float *wI_w =(const float*)d_in[13], *wI_b =(const float*)d_in[14];
  const float *aS_w1=(const float*)d_in[15], *aS_b1=(const float*)d_in[16];
  const float *aS_w2=(const float*)d_in[17], *aS_b2=(const float*)d_in[18];
  const float *aS_w3=(const float*)d_in[19], *aS_b3=(const float*)d_in[20];
  const float *wS_w =(const float*)d_in[21], *wS_b =(const float*)d_in[22];
  const float *W2_w =(const float*)d_in[23], *W2_b =(const float*)d_in[24];
  const float *gu_w1=(const float*)d_in[25], *gu_b1=(const float*)d_in[26];
  const float *gu_w2=(const float*)d_in[27], *gu_b2=(const float*)d_in[28];
  const float *aU_w1=(const float*)d_in[29], *aU_b1=(const float*)d_in[30];
  const float *aU_w2=(const float*)d_in[31], *aU_b2=(const float*)d_in[32];
  const float *aU_w3=(const float*)d_in[33], *aU_b3=(const float*)d_in[34];
  const float *wU_w =(const float*)d_in[35], *wU_b =(const float*)d_in[36];
  const int* user_e    = (const int*)d_in[37];
  const int* item_e    = (const int*)d_in[38];
  const int* rating_e  = (const int*)d_in[39];
  const int* trust_e   = (const int*)d_in[40];
  const int* trustee_e = (const int*)d_in[41];
  float* dout = (float*)d_out;

  char* base = (char*)d_ws;
  size_t cur = 0;
  auto alloc = [&](size_t bytes)->char*{
    char* p = base + cur; cur += (bytes + 255) & ~(size_t)255; return p;
  };
  float* hI     = (float*)alloc((size_t)U_N * 64 * 4);
  float* esc    = (float*)alloc((size_t)EUI_E * 4);
  float* sdst   = (float*)alloc((size_t)U_N * 4);
  int*   rowptr = (int*)  alloc((size_t)(U_N + 1) * 4);
  int*   part   = (int*)  alloc((size_t)U_N * 4);
  int*   deg    = (int*)  alloc((size_t)U_N * 4);
  int*   eids   = (int*)  alloc((size_t)EUI_E * 4);
  int*   blk    = (int*)  alloc(512 * 4);
  float* acc    = (float*)alloc((size_t)U_N * 64 * 4);
  size_t fixed_end = cur;
  if (ws_size < fixed_end + 26000000) return;
  char* tab = base + fixed_end;
  size_t arena = ws_size - fixed_end;

  auto cdiv = [](int a, int b){ return (a + b - 1) / b; };
  auto buildCSR = [&](const int* dstIdx, int E, int N){
    hipMemsetAsync(deg, 0, (size_t)N * 4, stream);
    hist_k<<<cdiv(E,256), 256, 0, stream>>>(dstIdx, deg, E);
    int nb = cdiv(N, 256);
    scan1_k<<<nb, 256, 0, stream>>>(deg, part, blk, N);
    scan2_k<<<1, 512, 0, stream>>>(blk, nb);
    scan3_k<<<nb, 256, 0, stream>>>(part, blk, rowptr, N);
    hipMemsetAsync(deg, 0, (size_t)N * 4, stream);
    scatter_k<<<cdiv(E,256), 256, 0, stream>>>(dstIdx, rowptr, deg, eids, E);
  };
  auto linGrid = [&](int N){ int g = cdiv(cdiv(N,16),4); return g > 512 ? 512 : g; };

  // ============ Phase 1: ItemAgg (dst = user) ============
  {
    buildCSR(user_e, EUI_E, U_N);
    const size_t DU_BYTES = (size_t)U_N * 64 * 2;
    u16* DU = (u16*)tab;
    u16* XI = (u16*)(tab + DU_BYTES);
    long long rem = (long long)arena - (long long)DU_BYTES;
    int cp = (int)(rem / 256);
    if (cp < 1) return;
    if (cp > 250000) cp = 250000;
    u16* YI = XI + (size_t)cp * 64;
    mfma_lin_k<<<linGrid(U_N), 256, 0, stream>>>(user_emb, aI_w1 + 64*64, aI_b1, 1, DU, U_N);
    hipMemsetAsync(acc, 0, (size_t)U_N * 64 * 4, stream);
    for (int plo = 0; plo < 250000; plo += cp){
      int phi = plo + cp; if (phi > 250000) phi = 250000;
      int n = phi - plo;
      int g = cdiv(cdiv(n,16),4); if (g > 1024) g = 1024;
      mfma_pair_k<<<g, 256, 0, stream>>>(item_emb, rating_emb,
          gv_w1, gv_b1, gv_w2, gv_b2, aI_w1, 0.01f, plo, phi, XI, YI);
      score_k<<<cdiv(EUI_E,256), 256, 0, stream>>>(item_e, rating_e, 5, user_e,
          YI, plo, phi, DU, aI_w2, aI_b2, aI_w3, aI_b3, esc, EUI_E);
      agg_k<0><<<cdiv(U_N,256), 256, 0, stream>>>(rowptr, eids, item_e, rating_e, 5,
          esc, XI, plo, phi, acc, U_N);
    }
    sdst_k<<<cdiv(U_N,256), 256, 0, stream>>>(rowptr, eids, esc, sdst, U_N);
    fin_gemv_k<<<cdiv(U_N,256), 256, 0, stream>>>(acc, sdst, wI_w, wI_b, hI, U_N);
  }

  // ============ Phase 2: SocialAgg (dst = trustee) ============
  {
    buildCSR(trustee_e, EUU_E, U_N);
    u16* SS = (u16*)tab;
    u16* SD = (u16*)(tab + (size_t)U_N * 64 * 2);
    if (arena < (size_t)U_N * 64 * 4) return;
    mfma_lin_k<<<linGrid(U_N), 256, 0, stream>>>(user_emb, aS_w1, aS_b1, 0, SS, U_N);
    mfma_lin_k<<<linGrid(U_N), 256, 0, stream>>>(hI, aS_w1 + 64*64, aS_b1, 1, SD, U_N);
    score_k<<<cdiv(EUU_E,256), 256, 0, stream>>>(trust_e, (const int*)nullptr, 1, trustee_e,
        SS, 0, U_N, SD, aS_w2, aS_b2, aS_w3, aS_b3, esc, EUU_E);
    hipMemsetAsync(acc, 0, (size_t)U_N * 64 * 4, stream);
    agg_k<1><<<cdiv(U_N,256), 256, 0, stream>>>(rowptr, eids, trust_e, (const int*)nullptr, 1,
        esc, hI, 0, U_N, acc, U_N);
    sdst_k<<<cdiv(U_N,256), 256, 0, stream>>>(rowptr, eids, esc, sdst, U_N);
    fin_social_k<<<cdiv(U_N,256), 256, 0, stream>>>(acc, sdst, hI,
        wS_w, wS_b, W2_w, W2_b, dout, U_N);
  }

  // ============ Phase 3: UserAgg (dst = item) ============
  {
    buildCSR(item_e, EUI_E, I_N);
    const size_t DI_BYTES = (size_t)I_N * 64 * 2;
    u16* DI = (u16*)tab;
    u16* XU = (u16*)(tab + DI_BYTES);
    long long rem = (long long)arena - (long long)DI_BYTES;
    int cp = (int)(rem / 256);
    if (cp < 1) return;
    if (cp > 500000) cp = 500000;
    u16* YU = XU + (size_t)cp * 64;
    mfma_lin_k<<<linGrid(I_N), 256, 0, stream>>>(item_emb, aU_w1 + 64*64, aU_b1, 1, DI, I_N);
    hipMemsetAsync(acc, 0, (size_t)I_N * 64 * 4, stream);
    for (int plo = 0; plo < 500000; plo += cp){
      int phi = plo + cp; if (phi > 500000) phi = 500000;
      int n = phi - plo;
      int g = cdiv(cdiv(n,16),4); if (g > 1024) g = 1024;
      mfma_pair_k<<<g, 256, 0, stream>>>(user_emb, rating_emb,
          gu_w1, gu_b1, gu_w2, gu_b2, aU_w1, 0.0f, plo, phi, XU, YU);
      score_k<<<cdiv(EUI_E,256), 256, 0, stream>>>(user_e, rating_e, 5, item_e,
          YU, plo, phi, DI, aU_w2, aU_b2, aU_w3, aU_b3, esc, EUI_E);
      agg_k<0><<<cdiv(I_N,256), 256, 0, stream>>>(rowptr, eids, user_e, rating_e, 5,
          esc, XU, plo, phi, acc, I_N);
    }
    sdst_k<<<cdiv(I_N,256), 256, 0, stream>>>(rowptr, eids, esc, sdst, I_N);
    fin_gemv_k<<<cdiv(I_N,256), 256, 0, stream>>>(acc, sdst, wU_w, wU_b,
        dout + (size_t)U_N * 64, I_N);
  }
}

// Round 5
// 1034.413 us; speedup vs baseline: 10.4076x; 1.2415x over previous
//
#include <hip/hip_runtime.h>

// GraphRec forward, MI355X. Round 5: fused MFMA score (Y computed on the fly,
// no Y table), CSR-position esc + fused denominator, bf16 hI, d_out-as-scratch
// X tables. Inputs f32, output f32.

typedef unsigned int   u32;
typedef unsigned short u16;
typedef short bf16x8 __attribute__((ext_vector_type(8)));
typedef float f32x4  __attribute__((ext_vector_type(4)));

#define U_N   100000
#define I_N   50000
#define EUI_E 1000000
#define EUU_E 500000
#define NDOUT 200000   // X rows that fit in d_out[0 .. U_N*64*4) used as scratch

// ---------- helpers ----------
__device__ __forceinline__ float bflo(u32 u){ return __uint_as_float(u << 16); }
__device__ __forceinline__ float bfhi(u32 u){ return __uint_as_float(u & 0xffff0000u); }
__device__ __forceinline__ u16 f2bf(float f){
  u32 x = __float_as_uint(f);
  x += 0x7fffu + ((x >> 16) & 1u);
  return (u16)(x >> 16);
}
__device__ __forceinline__ u32 pk2(float a, float b){
  return (u32)f2bf(a) | ((u32)f2bf(b) << 16);
}
__device__ __forceinline__ float actf(float x, float s){ return fmaxf(x, x * s); }
__device__ __forceinline__ void cvt8(uint4 q, float f[8]){
  f[0]=bflo(q.x); f[1]=bfhi(q.x); f[2]=bflo(q.y); f[3]=bfhi(q.y);
  f[4]=bflo(q.z); f[5]=bfhi(q.z); f[6]=bflo(q.w); f[7]=bfhi(q.w);
}

// ---------- MFMA fragment helpers (16x16x32 bf16) ----------
// A: lane l holds row (l&15), k = 8*(l>>4)+j. B: col (l&15), k = 8*(l>>4)+j.
// D: col (l&15), row = 4*(l>>4)+reg  [m89-verified, validated on-HW round 4].
__device__ __forceinline__ bf16x8 bfrag(const float* __restrict__ W, int kt, int nt, int l){
  int c = l & 15, g = l >> 4;
  const float* p = W + (size_t)(kt*32 + g*8) * 64 + nt*16 + c;
  bf16x8 r;
  #pragma unroll
  for (int j = 0; j < 8; ++j) r[j] = (short)f2bf(p[(size_t)j * 64]);
  return r;
}
__device__ __forceinline__ bf16x8 afrag_f32(const float* p){
  float4 a = *(const float4*)p, b = *(const float4*)(p + 4);
  bf16x8 r;
  r[0]=(short)f2bf(a.x); r[1]=(short)f2bf(a.y); r[2]=(short)f2bf(a.z); r[3]=(short)f2bf(a.w);
  r[4]=(short)f2bf(b.x); r[5]=(short)f2bf(b.y); r[6]=(short)f2bf(b.z); r[7]=(short)f2bf(b.w);
  return r;
}
#define LDT 68   // LDS row stride (floats)
__device__ __forceinline__ void dwrite(float* lb, const f32x4* acc, float slope, int l){
  int c = l & 15, g = l >> 4;
  #pragma unroll
  for (int nt = 0; nt < 4; ++nt){
    #pragma unroll
    for (int rg = 0; rg < 4; ++rg)
      lb[(4*g + rg)*LDT + nt*16 + c] = actf(acc[nt][rg], slope);
  }
}
__device__ __forceinline__ bf16x8 afrag_lds(const float* lb, int kt, int l){
  int r = l & 15, g = l >> 4;
  return afrag_f32(lb + r*LDT + kt*32 + g*8);
}
// store 16 rows of 64 f32 from LDS to bf16 table split across two regions
__device__ __forceinline__ void store_rows2(const float* lb, u16* lo, u16* hi, int ndout,
                                            int base, int nrows, int l){
  int r = l >> 2, q = l & 3;
  if (r >= nrows) return;
  int row = base + r;
  u16* out = (row < ndout) ? lo + (size_t)row * 64 : hi + (size_t)(row - ndout) * 64;
  const float* src = lb + r*LDT + q*16;
  float4 a = *(const float4*)src, b = *(const float4*)(src+4);
  float4 c = *(const float4*)(src+8), d = *(const float4*)(src+12);
  uint4 w0, w1;
  w0.x = pk2(a.x,a.y); w0.y = pk2(a.z,a.w); w0.z = pk2(b.x,b.y); w0.w = pk2(b.z,b.w);
  w1.x = pk2(c.x,c.y); w1.y = pk2(c.z,c.w); w1.z = pk2(d.x,d.y); w1.w = pk2(d.z,d.w);
  u32* dst = (u32*)(out + (size_t)q*16);
  *(uint4*)dst = w0;
  *(uint4*)(dst + 4) = w1;
}
#define MFMA(a,b,c) __builtin_amdgcn_mfma_f32_16x16x32_bf16((a),(b),(c),0,0,0)

// ---------- pair-table value MLP: X[p] = act2(act1(cat(embA[p/5],embR[p%5])@W1+b1)@W2+b2) ----------
__global__ void __launch_bounds__(256) mfma_pair_k(
    const float* __restrict__ embA, const float* __restrict__ embR,
    const float* __restrict__ W1, const float* __restrict__ b1,
    const float* __restrict__ W2, const float* __restrict__ b2,
    float slope, int plo, int phi, u16* __restrict__ Xlo, u16* __restrict__ Xhi, int ndout)
{
  __shared__ float lbuf[4][16*LDT];
  int l   = threadIdx.x & 63;
  int wid = threadIdx.x >> 6;
  float* lb = lbuf[wid];
  int c = l & 15;
  bf16x8 w1f[4][4], w2f[2][4];
  #pragma unroll
  for (int kt = 0; kt < 4; ++kt)
    #pragma unroll
    for (int nt = 0; nt < 4; ++nt) w1f[kt][nt] = bfrag(W1, kt, nt, l);
  #pragma unroll
  for (int kt = 0; kt < 2; ++kt)
    #pragma unroll
    for (int nt = 0; nt < 4; ++nt) w2f[kt][nt] = bfrag(W2, kt, nt, l);
  float bias1[4], bias2[4];
  #pragma unroll
  for (int nt = 0; nt < 4; ++nt){ bias1[nt] = b1[nt*16 + c]; bias2[nt] = b2[nt*16 + c]; }

  int n = phi - plo;
  int ngrp = (n + 15) >> 4;
  for (int grp = blockIdx.x*4 + wid; grp < ngrp; grp += gridDim.x*4){
    int base = grp * 16;
    int p = plo + base + (l & 15);
    if (p >= phi) p = phi - 1;
    int i = p / 5, r = p - 5*i;
    const float* ra = embA + (size_t)i * 64;
    const float* rr = embR + (size_t)r * 64;
    bf16x8 a0 = afrag_f32(ra + (l>>4)*8);
    bf16x8 a1 = afrag_f32(ra + 32 + (l>>4)*8);
    bf16x8 a2 = afrag_f32(rr + (l>>4)*8);
    bf16x8 a3 = afrag_f32(rr + 32 + (l>>4)*8);
    f32x4 acc[4];
    #pragma unroll
    for (int nt = 0; nt < 4; ++nt){
      f32x4 v; v[0]=bias1[nt]; v[1]=bias1[nt]; v[2]=bias1[nt]; v[3]=bias1[nt];
      v = MFMA(a0, w1f[0][nt], v);
      v = MFMA(a1, w1f[1][nt], v);
      v = MFMA(a2, w1f[2][nt], v);
      v = MFMA(a3, w1f[3][nt], v);
      acc[nt] = v;
    }
    dwrite(lb, acc, slope, l);
    bf16x8 x0 = afrag_lds(lb, 0, l);
    bf16x8 x1 = afrag_lds(lb, 1, l);
    #pragma unroll
    for (int nt = 0; nt < 4; ++nt){
      f32x4 v; v[0]=bias2[nt]; v[1]=bias2[nt]; v[2]=bias2[nt]; v[3]=bias2[nt];
      v = MFMA(x0, w2f[0][nt], v);
      v = MFMA(x1, w2f[1][nt], v);
      acc[nt] = v;
    }
    dwrite(lb, acc, slope, l);
    int nrows = n - base; if (nrows > 16) nrows = 16;
    store_rows2(lb, Xlo, Xhi, ndout, base, nrows, l);
  }
}

// ---------- single linear: out_bf16 = A[N x 64] @ W[64 x 64] (+ b) ----------
template<int AF32>
__global__ void __launch_bounds__(256) mfma_lin_k(
    const void* __restrict__ A, const float* __restrict__ W, const float* __restrict__ b,
    int has_bias, u16* __restrict__ out, int N)
{
  __shared__ float lbuf[4][16*LDT];
  int l   = threadIdx.x & 63;
  int wid = threadIdx.x >> 6;
  float* lb = lbuf[wid];
  int c = l & 15;
  bf16x8 wf[2][4];
  #pragma unroll
  for (int kt = 0; kt < 2; ++kt)
    #pragma unroll
    for (int nt = 0; nt < 4; ++nt) wf[kt][nt] = bfrag(W, kt, nt, l);
  float bias[4];
  #pragma unroll
  for (int nt = 0; nt < 4; ++nt) bias[nt] = has_bias ? b[nt*16 + c] : 0.0f;

  int ngrp = (N + 15) >> 4;
  for (int grp = blockIdx.x*4 + wid; grp < ngrp; grp += gridDim.x*4){
    int base = grp * 16;
    int ar = base + (l & 15);
    if (ar >= N) ar = N - 1;
    bf16x8 a0, a1;
    if (AF32){
      const float* row = (const float*)A + (size_t)ar * 64;
      a0 = afrag_f32(row + (l>>4)*8);
      a1 = afrag_f32(row + 32 + (l>>4)*8);
    } else {
      const u16* row = (const u16*)A + (size_t)ar * 64;
      a0 = *(const bf16x8*)(row + (l>>4)*8);
      a1 = *(const bf16x8*)(row + 32 + (l>>4)*8);
    }
    f32x4 acc[4];
    #pragma unroll
    for (int nt = 0; nt < 4; ++nt){
      f32x4 v; v[0]=bias[nt]; v[1]=bias[nt]; v[2]=bias[nt]; v[3]=bias[nt];
      v = MFMA(a0, wf[0][nt], v);
      v = MFMA(a1, wf[1][nt], v);
      acc[nt] = v;
    }
    dwrite(lb, acc, 1.0f, l);
    int nrows = N - base; if (nrows > 16) nrows = 16;
    store_rows2(lb, out, out, 1<<30, base, nrows, l);
  }
}

// ---------- CSR build ----------
__global__ void hist_k(const int* __restrict__ idx, int* __restrict__ deg, int E){
  int e = blockIdx.x*256 + threadIdx.x;
  if (e < E) atomicAdd(&deg[idx[e]], 1);
}
__global__ void scan1_k(const int* __restrict__ deg, int* __restrict__ part,
                        int* __restrict__ blk, int N){
  __shared__ int sh[256];
  int i = blockIdx.x*256 + threadIdx.x;
  sh[threadIdx.x] = (i < N) ? deg[i] : 0;
  __syncthreads();
  for (int o = 1; o < 256; o <<= 1){
    int t = (threadIdx.x >= o) ? sh[threadIdx.x - o] : 0;
    __syncthreads();
    sh[threadIdx.x] += t;
    __syncthreads();
  }
  if (i < N) part[i] = sh[threadIdx.x];
  if (threadIdx.x == 255) blk[blockIdx.x] = sh[255];
}
__global__ void scan2_k(int* __restrict__ blk, int nb){
  __shared__ int sh[512];
  sh[threadIdx.x] = (threadIdx.x < nb) ? blk[threadIdx.x] : 0;
  __syncthreads();
  for (int o = 1; o < 512; o <<= 1){
    int t = (threadIdx.x >= o) ? sh[threadIdx.x - o] : 0;
    __syncthreads();
    sh[threadIdx.x] += t;
    __syncthreads();
  }
  if (threadIdx.x < nb) blk[threadIdx.x] = sh[threadIdx.x];
}
__global__ void scan3_k(const int* __restrict__ part, const int* __restrict__ blk,
                        int* __restrict__ rowptr, int N){
  int i = blockIdx.x*256 + threadIdx.x;
  if (i >= N) return;
  int add = blockIdx.x ? blk[blockIdx.x - 1] : 0;
  rowptr[i + 1] = part[i] + add;
  if (i == 0) rowptr[0] = 0;
}
__global__ void scatter_k(const int* __restrict__ idx, const int* __restrict__ rowptr,
                          int* __restrict__ cur, int* __restrict__ eids, int E){
  int e = blockIdx.x*256 + threadIdx.x;
  if (e >= E) return;
  int d = idx[e];
  int pos = rowptr[d] + atomicAdd(&cur[d], 1);
  eids[pos] = e;
}

// ---------- fused MFMA score: esc[pos] = exp(w3 . relu(W2 . relu(Y + D[dst]) + b2) + b3) ----------
// CY=1: Y computed as X[key]@Wy (X gathered); CY=0: Y rows gathered directly (social SS).
template<int CY>
__global__ void __launch_bounds__(256) fscore_k(
    const int* __restrict__ eids, const int* __restrict__ keyI,
    const int* __restrict__ ratI, int kmul, const int* __restrict__ dstI,
    const u16* __restrict__ Xlo, const u16* __restrict__ Xhi, int ndout,
    int klo, int nk,
    const u16* __restrict__ Dtab,
    const float* __restrict__ Wy,
    const float* __restrict__ W2, const float* __restrict__ b2,
    const float* __restrict__ w3, const float* __restrict__ b3,
    float* __restrict__ esc, int E)
{
  __shared__ float lbuf[4][16*LDT];
  int l   = threadIdx.x & 63;
  int wid = threadIdx.x >> 6;
  int r16 = l & 15, g = l >> 4;
  float* lb = lbuf[wid];
  bf16x8 wyf[2][4], w2f[2][4];
  if (CY){
    #pragma unroll
    for (int kt = 0; kt < 2; ++kt)
      #pragma unroll
      for (int nt = 0; nt < 4; ++nt) wyf[kt][nt] = bfrag(Wy, kt, nt, l);
  }
  #pragma unroll
  for (int kt = 0; kt < 2; ++kt)
    #pragma unroll
    for (int nt = 0; nt < 4; ++nt) w2f[kt][nt] = bfrag(W2, kt, nt, l);
  f32x4 b2v[4]; float w3v[4];
  #pragma unroll
  for (int nt = 0; nt < 4; ++nt){
    float bv = b2[nt*16 + r16];
    f32x4 t; t[0]=bv; t[1]=bv; t[2]=bv; t[3]=bv;
    b2v[nt] = t;
    w3v[nt] = w3[nt*16 + r16];
  }
  float b3v = b3[0];

  int ngrp = (E + 15) >> 4;
  for (int grp = blockIdx.x*4 + wid; grp < ngrp; grp += gridDim.x*4){
    int pos = grp*16 + r16;
    int pc  = pos < E ? pos : E - 1;
    int e   = eids[pc];
    int key = keyI[e]*kmul + (ratI ? ratI[e] : 0);
    int j   = key - klo;
    bool inr = (pos < E) && ((unsigned)j < (unsigned)nk);
    unsigned long long bal = __ballot(inr ? 1 : 0);
    uint4 xa = {0,0,0,0}, xb = xa, da = xa, db = xa;
    if (inr){
      const u16* xr = (j < ndout) ? Xlo + (size_t)j * 64 : Xhi + (size_t)(j - ndout) * 64;
      xa = *(const uint4*)(xr + g*8);
      xb = *(const uint4*)(xr + 32 + g*8);
      const u16* dr = Dtab + (size_t)dstI[e] * 64;
      da = *(const uint4*)(dr + g*8);
      db = *(const uint4*)(dr + 32 + g*8);
    }
    bf16x8 p0, p1;
    float dfa[8], dfb[8];
    cvt8(da, dfa); cvt8(db, dfb);
    if (CY){
      bf16x8 a0 = *reinterpret_cast<const bf16x8*>(&xa);
      bf16x8 a1 = *reinterpret_cast<const bf16x8*>(&xb);
      f32x4 y[4];
      #pragma unroll
      for (int nt = 0; nt < 4; ++nt){
        f32x4 z; z[0]=0.f; z[1]=0.f; z[2]=0.f; z[3]=0.f;
        z = MFMA(a0, wyf[0][nt], z);
        z = MFMA(a1, wyf[1][nt], z);
        y[nt] = z;
      }
      // transpose D-layout -> A-layout through wave-private LDS
      #pragma unroll
      for (int nt = 0; nt < 4; ++nt)
        #pragma unroll
        for (int rg = 0; rg < 4; ++rg)
          lb[(4*g + rg)*LDT + nt*16 + r16] = y[nt][rg];
      const float* pr = lb + r16*LDT;
      float4 f0 = *(const float4*)(pr + g*8);
      float4 f1 = *(const float4*)(pr + g*8 + 4);
      float4 f2 = *(const float4*)(pr + 32 + g*8);
      float4 f3 = *(const float4*)(pr + 36 + g*8);
      float q0[8] = {f0.x,f0.y,f0.z,f0.w,f1.x,f1.y,f1.z,f1.w};
      float q1[8] = {f2.x,f2.y,f2.z,f2.w,f3.x,f3.y,f3.z,f3.w};
      #pragma unroll
      for (int u = 0; u < 8; ++u){
        p0[u] = (short)f2bf(fmaxf(q0[u] + dfa[u], 0.0f));
        p1[u] = (short)f2bf(fmaxf(q1[u] + dfb[u], 0.0f));
      }
    } else {
      float xfa[8], xfb[8];
      cvt8(xa, xfa); cvt8(xb, xfb);
      #pragma unroll
      for (int u = 0; u < 8; ++u){
        p0[u] = (short)f2bf(fmaxf(xfa[u] + dfa[u], 0.0f));
        p1[u] = (short)f2bf(fmaxf(xfb[u] + dfb[u], 0.0f));
      }
    }
    f32x4 o[4];
    #pragma unroll
    for (int nt = 0; nt < 4; ++nt){
      f32x4 v = b2v[nt];
      v = MFMA(p0, w2f[0][nt], v);
      v = MFMA(p1, w2f[1][nt], v);
      o[nt] = v;
    }
    float part[4] = {0.f, 0.f, 0.f, 0.f};
    #pragma unroll
    for (int nt = 0; nt < 4; ++nt)
      #pragma unroll
      for (int rg = 0; rg < 4; ++rg)
        part[rg] += fmaxf(o[nt][rg], 0.0f) * w3v[nt];
    #pragma unroll
    for (int m = 1; m < 16; m <<= 1){
      #pragma unroll
      for (int rg = 0; rg < 4; ++rg) part[rg] += __shfl_xor(part[rg], m);
    }
    if (r16 < 4){
      int eidx = 4*g + r16;                  // edge slot within group
      int p2 = grp*16 + eidx;
      if (p2 < E && ((bal >> eidx) & 1))
        esc[p2] = __expf(part[r16] + b3v);
    }
  }
}

// ---------- segmented accumulate + denominator (esc indexed by CSR position) ----------
__global__ void __launch_bounds__(256) agg2_k(
    const int* __restrict__ rowptr, const int* __restrict__ eids,
    const int* __restrict__ keyI, const int* __restrict__ ratI, int kmul,
    const float* __restrict__ esc,
    const u16* __restrict__ Xlo, const u16* __restrict__ Xhi, int ndout,
    int klo, int nk,
    float* __restrict__ acc, float* __restrict__ sdst, int N)
{
  int d = blockIdx.x*256 + threadIdx.x;
  if (d >= N) return;
  float a[64];
  float* ar = acc + (size_t)d * 64;
  #pragma unroll
  for (int t = 0; t < 64; t += 4){
    float4 q = *(const float4*)(ar + t);
    a[t]=q.x; a[t+1]=q.y; a[t+2]=q.z; a[t+3]=q.w;
  }
  float s = sdst[d];
  int k0 = rowptr[d], k1 = rowptr[d+1];
  for (int k = k0; k < k1; ++k){
    int e = eids[k];
    int j = keyI[e]*kmul + (ratI ? ratI[e] : 0) - klo;
    if ((unsigned)j >= (unsigned)nk) continue;
    float w = esc[k];
    s += w;
    const u16* xr = (j < ndout) ? Xlo + (size_t)j * 64 : Xhi + (size_t)(j - ndout) * 64;
    #pragma unroll
    for (int kk = 0; kk < 64; kk += 8){
      uint4 q = *(const uint4*)(xr + kk);
      float f[8]; cvt8(q, f);
      #pragma unroll
      for (int u = 0; u < 8; ++u) a[kk+u] = fmaf(w, f[u], a[kk+u]);
    }
  }
  #pragma unroll
  for (int t = 0; t < 64; t += 4)
    *(float4*)(ar + t) = make_float4(a[t], a[t+1], a[t+2], a[t+3]);
  sdst[d] = s;
}

// ---------- finalize: out = leaky0.2((acc/s)@W + b); OUTBF: bf16 (hI) else f32 ----------
template<int OUTBF>
__global__ void __launch_bounds__(256) fin_gemv_k(
    const float* __restrict__ acc, const float* __restrict__ sdst,
    const float* __restrict__ W, const float* __restrict__ b,
    void* __restrict__ out, int N)
{
  __shared__ __align__(16) float ws[64*64];
  __shared__ float bs[64];
  for (int t = threadIdx.x; t < 4096; t += 256) ws[t] = W[t];
  if (threadIdx.x < 64) bs[threadIdx.x] = b[threadIdx.x];
  __syncthreads();
  int d = blockIdx.x*256 + threadIdx.x;
  if (d >= N) return;
  float s = sdst[d];
  float inv = (s > 0.f) ? 1.0f / s : 0.0f;
  const float* ar = acc + (size_t)d * 64;
  float h[64];
  #pragma unroll
  for (int t = 0; t < 64; t += 4){
    float4 q = *(const float4*)(ar + t);
    h[t]=q.x*inv; h[t+1]=q.y*inv; h[t+2]=q.z*inv; h[t+3]=q.w*inv;
  }
  float o[64];
  #pragma unroll
  for (int t = 0; t < 64; ++t) o[t] = bs[t];
  #pragma unroll
  for (int c = 0; c < 64; ++c){
    float v = h[c];
    const float4* wr = (const float4*)&ws[c*64];
    #pragma unroll
    for (int t = 0; t < 16; ++t){
      float4 w = wr[t];
      o[4*t  ] = fmaf(v, w.x, o[4*t  ]);
      o[4*t+1] = fmaf(v, w.y, o[4*t+1]);
      o[4*t+2] = fmaf(v, w.z, o[4*t+2]);
      o[4*t+3] = fmaf(v, w.w, o[4*t+3]);
    }
  }
  if (OUTBF){
    u32* orow = (u32*)((u16*)out + (size_t)d * 64);
    #pragma unroll
    for (int t = 0; t < 64; t += 8){
      uint4 w;
      w.x = pk2(actf(o[t  ],0.2f), actf(o[t+1],0.2f));
      w.y = pk2(actf(o[t+2],0.2f), actf(o[t+3],0.2f));
      w.z = pk2(actf(o[t+4],0.2f), actf(o[t+5],0.2f));
      w.w = pk2(actf(o[t+6],0.2f), actf(o[t+7],0.2f));
      *(uint4*)(orow + t/2) = w;
    }
  } else {
    float* orow = (float*)out + (size_t)d * 64;
    #pragma unroll
    for (int t = 0; t < 64; t += 4)
      *(float4*)(orow + t) = make_float4(actf(o[t],0.2f), actf(o[t+1],0.2f),
                                         actf(o[t+2],0.2f), actf(o[t+3],0.2f));
  }
}

// ---------- social finalize: hS = leaky0.2((accS/s)@wS+bS); out = leaky0.2(cat(hI,hS)@W2+b2) ----------
__global__ void __launch_bounds__(256) fin_social_k(
    const float* __restrict__ accS, const float* __restrict__ sdst,
    const u16* __restrict__ hI,
    const float* __restrict__ wS, const float* __restrict__ bS,
    const float* __restrict__ W2, const float* __restrict__ b2,
    float* __restrict__ out, int N)
{
  __shared__ __align__(16) float wsT[64*64];   // transposed wS
  __shared__ __align__(16) float w2s[128*64];
  __shared__ float bSs[64], b2s[64];
  for (int t = threadIdx.x; t < 4096; t += 256){
    int rrow = t >> 6, col = t & 63;
    wsT[col*64 + rrow] = wS[t];
  }
  for (int t = threadIdx.x; t < 128*64; t += 256) w2s[t] = W2[t];
  if (threadIdx.x < 64){ bSs[threadIdx.x] = bS[threadIdx.x]; b2s[threadIdx.x] = b2[threadIdx.x]; }
  __syncthreads();
  int d = blockIdx.x*256 + threadIdx.x;
  if (d >= N) return;
  float s = sdst[d];
  float inv = (s > 0.f) ? 1.0f / s : 0.0f;
  const float* ar = accS + (size_t)d * 64;
  float hin[64];
  #pragma unroll
  for (int t = 0; t < 64; t += 4){
    float4 q = *(const float4*)(ar + t);
    hin[t]=q.x*inv; hin[t+1]=q.y*inv; hin[t+2]=q.z*inv; hin[t+3]=q.w*inv;
  }
  float o[64];
  #pragma unroll
  for (int t = 0; t < 64; ++t) o[t] = b2s[t];
  const u16* hrow = hI + (size_t)d * 64;
  #pragma unroll 1
  for (int k = 0; k < 64; k += 8){
    uint4 q = *(const uint4*)(hrow + k);
    float f[8]; cvt8(q, f);
    #pragma unroll
    for (int u = 0; u < 8; ++u){
      float v = f[u];
      const float4* wr = (const float4*)&w2s[(k + u)*64];
      #pragma unroll
      for (int t = 0; t < 16; ++t){
        float4 w = wr[t];
        o[4*t  ] = fmaf(v, w.x, o[4*t  ]);
        o[4*t+1] = fmaf(v, w.y, o[4*t+1]);
        o[4*t+2] = fmaf(v, w.z, o[4*t+2]);
        o[4*t+3] = fmaf(v, w.w, o[4*t+3]);
      }
    }
  }
  #pragma unroll 1
  for (int c = 0; c < 64; ++c){
    float t0=0.f, t1=0.f, t2=0.f, t3=0.f;
    const float4* wc = (const float4*)&wsT[c*64];
    #pragma unroll
    for (int t = 0; t < 16; ++t){
      float4 w = wc[t];
      t0 = fmaf(hin[4*t  ], w.x, t0);
      t1 = fmaf(hin[4*t+1], w.y, t1);
      t2 = fmaf(hin[4*t+2], w.z, t2);
      t3 = fmaf(hin[4*t+3], w.w, t3);
    }
    float hSc = actf(((t0+t1)+(t2+t3)) + bSs[c], 0.2f);
    const float4* wr = (const float4*)&w2s[(64 + c)*64];
    #pragma unroll
    for (int t = 0; t < 16; ++t){
      float4 w = wr[t];
      o[4*t  ] = fmaf(hSc, w.x, o[4*t  ]);
      o[4*t+1] = fmaf(hSc, w.y, o[4*t+1]);
      o[4*t+2] = fmaf(hSc, w.z, o[4*t+2]);
      o[4*t+3] = fmaf(hSc, w.w, o[4*t+3]);
    }
  }
  float* orow = out + (size_t)d * 64;
  #pragma unroll
  for (int t = 0; t < 64; t += 4)
    *(float4*)(orow + t) = make_float4(actf(o[t],0.2f), actf(o[t+1],0.2f),
                                       actf(o[t+2],0.2f), actf(o[t+3],0.2f));
}

extern "C" void kernel_launch(void* const* d_in, const int* in_sizes, int n_in,
                              void* d_out, int out_size, void* d_ws, size_t ws_size,
                              hipStream_t stream) {
  (void)in_sizes; (void)n_in; (void)out_size;
  const float* user_emb   = (const float*)d_in[0];
  const float* item_emb   = (const float*)d_in[1];
  const float* rating_emb = (const float*)d_in[2];
  const float *gv_w1=(const float*)d_in[3],  *gv_b1=(const float*)d_in[4];
  const float *gv_w2=(const float*)d_in[5],  *gv_b2=(const float*)d_in[6];
  const float *aI_w1=(const float*)d_in[7],  *aI_b1=(const float*)d_in[8];
  const float *aI_w2=(const float*)d_in[9],  *aI_b2=(const float*)d_in[10];
  const float *aI_w3=(const float*)d_in[11], *aI_b3=(const float*)d_in[12];
  const float *wI_w =(const float*)d_in[13], *wI_b =(const float*)d_in[14];
  const float *aS_w1=(const float*)d_in[15], *aS_b1=(const float*)d_in[16];
  const float *aS_w2=(const float*)d_in[17], *aS_b2=(const float*)d_in[18];
  const float *aS_w3=(const float*)d_in[19], *aS_b3=(const float*)d_in[20];
  const float *wS_w =(const float*)d_in[21], *wS_b =(const float*)d_in[22];
  const float *W2_w =(const float*)d_in[23], *W2_b =(const float*)d_in[24];
  const float *gu_w1=(const float*)d_in[25], *gu_b1=(const float*)d_in[26];
  const float *gu_w2=(const float*)d_in[27], *gu_b2=(const float*)d_in[28];
  const float *aU_w1=(const float*)d_in[29], *aU_b1=(const float*)d_in[30];
  const float *aU_w2=(const float*)d_in[31], *aU_b2=(const float*)d_in[32];
  const float *aU_w3=(const float*)d_in[33], *aU_b3=(const float*)d_in[34];
  const float *wU_w =(const float*)d_in[35], *wU_b =(const float*)d_in[36];
  const int* user_e    = (const int*)d_in[37];
  const int* item_e    = (const int*)d_in[38];
  const int* rating_e  = (const int*)d_in[39];
  const int* trust_e   = (const int*)d_in[40];
  const int* trustee_e = (const int*)d_in[41];
  float* dout = (float*)d_out;

  char* base = (char*)d_ws;
  size_t cur = 0;
  auto alloc = [&](size_t bytes)->char*{
    char* p = base + cur; cur += (bytes + 255) & ~(size_t)255; return p;
  };
  u16*   hI     = (u16*)  alloc((size_t)U_N * 64 * 2);   // 12.8 MB (bf16)
  float* esc    = (float*)alloc((size_t)EUI_E * 4);      // 4 MB (CSR-position indexed)
  float* sdst   = (float*)alloc((size_t)U_N * 4);
  int*   rowptr = (int*)  alloc((size_t)(U_N + 1) * 4);
  int*   part   = (int*)  alloc((size_t)U_N * 4);
  int*   deg    = (int*)  alloc((size_t)U_N * 4);
  int*   eids   = (int*)  alloc((size_t)EUI_E * 4);
  int*   blk    = (int*)  alloc(512 * 4);
  float* acc    = (float*)alloc((size_t)U_N * 64 * 4);   // 25.6 MB
  size_t fixed_end = cur;
  if (ws_size < fixed_end + 26500000) return;            // need D-region + X-overflow
  u16* tabD = (u16*)(base + fixed_end);                  // 12.8 MB: D tables / SS
  u16* tabX = (u16*)(base + fixed_end + 13000192);       // >=13 MB: X overflow / SD
  // X tables for key ranges live in d_out[0 .. U_N*64*4) (scratch until overwritten)
  u16* Xdout = (u16*)d_out;

  auto cdiv = [](int a, int b){ return (a + b - 1) / b; };
  auto buildCSR = [&](const int* dstIdx, int E, int N){
    hipMemsetAsync(deg, 0, (size_t)N * 4, stream);
    hist_k<<<cdiv(E,256), 256, 0, stream>>>(dstIdx, deg, E);
    int nb = cdiv(N, 256);
    scan1_k<<<nb, 256, 0, stream>>>(deg, part, blk, N);
    scan2_k<<<1, 512, 0, stream>>>(blk, nb);
    scan3_k<<<nb, 256, 0, stream>>>(part, blk, rowptr, N);
    hipMemsetAsync(deg, 0, (size_t)N * 4, stream);
    scatter_k<<<cdiv(E,256), 256, 0, stream>>>(dstIdx, rowptr, deg, eids, E);
  };
  auto gCap = [&](int groups){ int g = cdiv(groups, 4); return g > 1536 ? 1536 : g; };

  // ============ Phase 1: ItemAgg (dst = user) ============
  {
    buildCSR(user_e, EUI_E, U_N);
    mfma_lin_k<1><<<gCap(cdiv(U_N,16)), 256, 0, stream>>>(user_emb, aI_w1 + 64*64, aI_b1, 1, tabD, U_N);
    hipMemsetAsync(acc, 0, (size_t)U_N * 64 * 4, stream);
    hipMemsetAsync(sdst, 0, (size_t)U_N * 4, stream);
    const int NK = 250000, ND = NDOUT;                   // 200k rows in d_out + 50k in tabX
    mfma_pair_k<<<gCap(cdiv(NK,16)), 256, 0, stream>>>(item_emb, rating_emb,
        gv_w1, gv_b1, gv_w2, gv_b2, 0.01f, 0, NK, Xdout, tabX, ND);
    fscore_k<1><<<gCap(cdiv(EUI_E,16)), 256, 0, stream>>>(eids, item_e, rating_e, 5, user_e,
        Xdout, tabX, ND, 0, NK, tabD, aI_w1, aI_w2, aI_b2, aI_w3, aI_b3, esc, EUI_E);
    agg2_k<<<cdiv(U_N,256), 256, 0, stream>>>(rowptr, eids, item_e, rating_e, 5,
        esc, Xdout, tabX, ND, 0, NK, acc, sdst, U_N);
    fin_gemv_k<1><<<cdiv(U_N,256), 256, 0, stream>>>(acc, sdst, wI_w, wI_b, hI, U_N);
  }

  // ============ Phase 2: UserAgg (dst = item) ============
  {
    buildCSR(item_e, EUI_E, I_N);
    mfma_lin_k<1><<<gCap(cdiv(I_N,16)), 256, 0, stream>>>(item_emb, aU_w1 + 64*64, aU_b1, 1, tabD, I_N);
    hipMemsetAsync(acc, 0, (size_t)I_N * 64 * 4, stream);
    hipMemsetAsync(sdst, 0, (size_t)I_N * 4, stream);
    for (int klo = 0; klo < 500000; klo += 250000){
      const int NK = 250000, ND = NDOUT;
      mfma_pair_k<<<gCap(cdiv(NK,16)), 256, 0, stream>>>(user_emb, rating_emb,
          gu_w1, gu_b1, gu_w2, gu_b2, 0.0f, klo, klo + NK, Xdout, tabX, ND);
      fscore_k<1><<<gCap(cdiv(EUI_E,16)), 256, 0, stream>>>(eids, user_e, rating_e, 5, item_e,
          Xdout, tabX, ND, klo, NK, tabD, aU_w1, aU_w2, aU_b2, aU_w3, aU_b3, esc, EUI_E);
      agg2_k<<<cdiv(I_N,256), 256, 0, stream>>>(rowptr, eids, user_e, rating_e, 5,
          esc, Xdout, tabX, ND, klo, NK, acc, sdst, I_N);
    }
    fin_gemv_k<0><<<cdiv(I_N,256), 256, 0, stream>>>(acc, sdst, wU_w, wU_b,
        dout + (size_t)U_N * 64, I_N);
  }

  // ============ Phase 3: SocialAgg (dst = trustee) ============
  {
    buildCSR(trustee_e, EUU_E, U_N);
    mfma_lin_k<1><<<gCap(cdiv(U_N,16)), 256, 0, stream>>>(user_emb, aS_w1, aS_b1, 0, tabD, U_N); // SS
    mfma_lin_k<0><<<gCap(cdiv(U_N,16)), 256, 0, stream>>>(hI, aS_w1 + 64*64, aS_b1, 1, tabX, U_N); // SD
    hipMemsetAsync(acc, 0, (size_t)U_N * 64 * 4, stream);
    hipMemsetAsync(sdst, 0, (size_t)U_N * 4, stream);
    fscore_k<0><<<gCap(cdiv(EUU_E,16)), 256, 0, stream>>>(eids, trust_e, (const int*)nullptr, 1, trustee_e,
        tabD, tabD, U_N, 0, U_N, tabX, (const float*)nullptr, aS_w2, aS_b2, aS_w3, aS_b3, esc, EUU_E);
    agg2_k<<<cdiv(U_N,256), 256, 0, stream>>>(rowptr, eids, trust_e, (const int*)nullptr, 1,
        esc, hI, hI, U_N, 0, U_N, acc, sdst, U_N);
    fin_social_k<<<cdiv(U_N,256), 256, 0, stream>>>(acc, sdst, hI,
        wS_w, wS_b, W2_w, W2_b, dout, U_N);
  }
}

// Round 6
// 911.619 us; speedup vs baseline: 11.8095x; 1.1347x over previous
//
#include <hip/hip_runtime.h>

// GraphRec forward, MI355X. Round 6: MFMA finalize kernels (fin_social/fin_gemv
// -> matrix cores), agg2 zero-init (no acc/sdst memsets). Inputs f32, out f32.

typedef unsigned int   u32;
typedef unsigned short u16;
typedef short bf16x8 __attribute__((ext_vector_type(8)));
typedef float f32x4  __attribute__((ext_vector_type(4)));

#define U_N   100000
#define I_N   50000
#define EUI_E 1000000
#define EUU_E 500000
#define NDOUT 200000   // X rows that fit in d_out[0 .. U_N*64*4) used as scratch

// ---------- helpers ----------
__device__ __forceinline__ float bflo(u32 u){ return __uint_as_float(u << 16); }
__device__ __forceinline__ float bfhi(u32 u){ return __uint_as_float(u & 0xffff0000u); }
__device__ __forceinline__ u16 f2bf(float f){
  u32 x = __float_as_uint(f);
  x += 0x7fffu + ((x >> 16) & 1u);
  return (u16)(x >> 16);
}
__device__ __forceinline__ u32 pk2(float a, float b){
  return (u32)f2bf(a) | ((u32)f2bf(b) << 16);
}
__device__ __forceinline__ float actf(float x, float s){ return fmaxf(x, x * s); }
__device__ __forceinline__ void cvt8(uint4 q, float f[8]){
  f[0]=bflo(q.x); f[1]=bfhi(q.x); f[2]=bflo(q.y); f[3]=bfhi(q.y);
  f[4]=bflo(q.z); f[5]=bfhi(q.z); f[6]=bflo(q.w); f[7]=bfhi(q.w);
}

// ---------- MFMA fragment helpers (16x16x32 bf16) ----------
// A: lane l holds row (l&15), k = 8*(l>>4)+j. B: col (l&15), k = 8*(l>>4)+j.
// D: col (l&15), row = 4*(l>>4)+reg  [validated on HW rounds 4-5].
__device__ __forceinline__ bf16x8 bfrag(const float* __restrict__ W, int kt, int nt, int l){
  int c = l & 15, g = l >> 4;
  const float* p = W + (size_t)(kt*32 + g*8) * 64 + nt*16 + c;
  bf16x8 r;
  #pragma unroll
  for (int j = 0; j < 8; ++j) r[j] = (short)f2bf(p[(size_t)j * 64]);
  return r;
}
__device__ __forceinline__ bf16x8 afrag_f32(const float* p){
  float4 a = *(const float4*)p, b = *(const float4*)(p + 4);
  bf16x8 r;
  r[0]=(short)f2bf(a.x); r[1]=(short)f2bf(a.y); r[2]=(short)f2bf(a.z); r[3]=(short)f2bf(a.w);
  r[4]=(short)f2bf(b.x); r[5]=(short)f2bf(b.y); r[6]=(short)f2bf(b.z); r[7]=(short)f2bf(b.w);
  return r;
}
__device__ __forceinline__ bf16x8 afrag_f32s(const float* p, float s){
  float4 a = *(const float4*)p, b = *(const float4*)(p + 4);
  bf16x8 r;
  r[0]=(short)f2bf(a.x*s); r[1]=(short)f2bf(a.y*s); r[2]=(short)f2bf(a.z*s); r[3]=(short)f2bf(a.w*s);
  r[4]=(short)f2bf(b.x*s); r[5]=(short)f2bf(b.y*s); r[6]=(short)f2bf(b.z*s); r[7]=(short)f2bf(b.w*s);
  return r;
}
#define LDT 68   // LDS row stride (floats)
__device__ __forceinline__ void dwrite(float* lb, const f32x4* acc, float slope, int l){
  int c = l & 15, g = l >> 4;
  #pragma unroll
  for (int nt = 0; nt < 4; ++nt){
    #pragma unroll
    for (int rg = 0; rg < 4; ++rg)
      lb[(4*g + rg)*LDT + nt*16 + c] = actf(acc[nt][rg], slope);
  }
}
__device__ __forceinline__ bf16x8 afrag_lds(const float* lb, int kt, int l){
  int r = l & 15, g = l >> 4;
  return afrag_f32(lb + r*LDT + kt*32 + g*8);
}
// store 16 rows of 64 f32 from LDS to bf16 table split across two regions
__device__ __forceinline__ void store_rows2(const float* lb, u16* lo, u16* hi, int ndout,
                                            int base, int nrows, int l){
  int r = l >> 2, q = l & 3;
  if (r >= nrows) return;
  int row = base + r;
  u16* out = (row < ndout) ? lo + (size_t)row * 64 : hi + (size_t)(row - ndout) * 64;
  const float* src = lb + r*LDT + q*16;
  float4 a = *(const float4*)src, b = *(const float4*)(src+4);
  float4 c = *(const float4*)(src+8), d = *(const float4*)(src+12);
  uint4 w0, w1;
  w0.x = pk2(a.x,a.y); w0.y = pk2(a.z,a.w); w0.z = pk2(b.x,b.y); w0.w = pk2(b.z,b.w);
  w1.x = pk2(c.x,c.y); w1.y = pk2(c.z,c.w); w1.z = pk2(d.x,d.y); w1.w = pk2(d.z,d.w);
  u32* dst = (u32*)(out + (size_t)q*16);
  *(uint4*)dst = w0;
  *(uint4*)(dst + 4) = w1;
}
__device__ __forceinline__ void store_rows_f32(const float* lb, float* out,
                                               int base, int nrows, int l){
  int r = l >> 2, q = l & 3;
  if (r >= nrows) return;
  const float* src = lb + r*LDT + q*16;
  float* dst = out + (size_t)(base + r)*64 + q*16;
  *(float4*)(dst)    = *(const float4*)(src);
  *(float4*)(dst+4)  = *(const float4*)(src+4);
  *(float4*)(dst+8)  = *(const float4*)(src+8);
  *(float4*)(dst+12) = *(const float4*)(src+12);
}
#define MFMA(a,b,c) __builtin_amdgcn_mfma_f32_16x16x32_bf16((a),(b),(c),0,0,0)

// ---------- pair-table value MLP: X[p] = act2(act1(cat(embA[p/5],embR[p%5])@W1+b1)@W2+b2) ----------
__global__ void __launch_bounds__(256) mfma_pair_k(
    const float* __restrict__ embA, const float* __restrict__ embR,
    const float* __restrict__ W1, const float* __restrict__ b1,
    const float* __restrict__ W2, const float* __restrict__ b2,
    float slope, int plo, int phi, u16* __restrict__ Xlo, u16* __restrict__ Xhi, int ndout)
{
  __shared__ float lbuf[4][16*LDT];
  int l   = threadIdx.x & 63;
  int wid = threadIdx.x >> 6;
  float* lb = lbuf[wid];
  int c = l & 15;
  bf16x8 w1f[4][4], w2f[2][4];
  #pragma unroll
  for (int kt = 0; kt < 4; ++kt)
    #pragma unroll
    for (int nt = 0; nt < 4; ++nt) w1f[kt][nt] = bfrag(W1, kt, nt, l);
  #pragma unroll
  for (int kt = 0; kt < 2; ++kt)
    #pragma unroll
    for (int nt = 0; nt < 4; ++nt) w2f[kt][nt] = bfrag(W2, kt, nt, l);
  float bias1[4], bias2[4];
  #pragma unroll
  for (int nt = 0; nt < 4; ++nt){ bias1[nt] = b1[nt*16 + c]; bias2[nt] = b2[nt*16 + c]; }

  int n = phi - plo;
  int ngrp = (n + 15) >> 4;
  for (int grp = blockIdx.x*4 + wid; grp < ngrp; grp += gridDim.x*4){
    int base = grp * 16;
    int p = plo + base + (l & 15);
    if (p >= phi) p = phi - 1;
    int i = p / 5, r = p - 5*i;
    const float* ra = embA + (size_t)i * 64;
    const float* rr = embR + (size_t)r * 64;
    bf16x8 a0 = afrag_f32(ra + (l>>4)*8);
    bf16x8 a1 = afrag_f32(ra + 32 + (l>>4)*8);
    bf16x8 a2 = afrag_f32(rr + (l>>4)*8);
    bf16x8 a3 = afrag_f32(rr + 32 + (l>>4)*8);
    f32x4 acc[4];
    #pragma unroll
    for (int nt = 0; nt < 4; ++nt){
      f32x4 v; v[0]=bias1[nt]; v[1]=bias1[nt]; v[2]=bias1[nt]; v[3]=bias1[nt];
      v = MFMA(a0, w1f[0][nt], v);
      v = MFMA(a1, w1f[1][nt], v);
      v = MFMA(a2, w1f[2][nt], v);
      v = MFMA(a3, w1f[3][nt], v);
      acc[nt] = v;
    }
    dwrite(lb, acc, slope, l);
    bf16x8 x0 = afrag_lds(lb, 0, l);
    bf16x8 x1 = afrag_lds(lb, 1, l);
    #pragma unroll
    for (int nt = 0; nt < 4; ++nt){
      f32x4 v; v[0]=bias2[nt]; v[1]=bias2[nt]; v[2]=bias2[nt]; v[3]=bias2[nt];
      v = MFMA(x0, w2f[0][nt], v);
      v = MFMA(x1, w2f[1][nt], v);
      acc[nt] = v;
    }
    dwrite(lb, acc, slope, l);
    int nrows = n - base; if (nrows > 16) nrows = 16;
    store_rows2(lb, Xlo, Xhi, ndout, base, nrows, l);
  }
}

// ---------- single linear: out_bf16 = A[N x 64] @ W[64 x 64] (+ b) ----------
template<int AF32>
__global__ void __launch_bounds__(256) mfma_lin_k(
    const void* __restrict__ A, const float* __restrict__ W, const float* __restrict__ b,
    int has_bias, u16* __restrict__ out, int N)
{
  __shared__ float lbuf[4][16*LDT];
  int l   = threadIdx.x & 63;
  int wid = threadIdx.x >> 6;
  float* lb = lbuf[wid];
  int c = l & 15;
  bf16x8 wf[2][4];
  #pragma unroll
  for (int kt = 0; kt < 2; ++kt)
    #pragma unroll
    for (int nt = 0; nt < 4; ++nt) wf[kt][nt] = bfrag(W, kt, nt, l);
  float bias[4];
  #pragma unroll
  for (int nt = 0; nt < 4; ++nt) bias[nt] = has_bias ? b[nt*16 + c] : 0.0f;

  int ngrp = (N + 15) >> 4;
  for (int grp = blockIdx.x*4 + wid; grp < ngrp; grp += gridDim.x*4){
    int base = grp * 16;
    int ar = base + (l & 15);
    if (ar >= N) ar = N - 1;
    bf16x8 a0, a1;
    if (AF32){
      const float* row = (const float*)A + (size_t)ar * 64;
      a0 = afrag_f32(row + (l>>4)*8);
      a1 = afrag_f32(row + 32 + (l>>4)*8);
    } else {
      const u16* row = (const u16*)A + (size_t)ar * 64;
      a0 = *(const bf16x8*)(row + (l>>4)*8);
      a1 = *(const bf16x8*)(row + 32 + (l>>4)*8);
    }
    f32x4 acc[4];
    #pragma unroll
    for (int nt = 0; nt < 4; ++nt){
      f32x4 v; v[0]=bias[nt]; v[1]=bias[nt]; v[2]=bias[nt]; v[3]=bias[nt];
      v = MFMA(a0, wf[0][nt], v);
      v = MFMA(a1, wf[1][nt], v);
      acc[nt] = v;
    }
    dwrite(lb, acc, 1.0f, l);
    int nrows = N - base; if (nrows > 16) nrows = 16;
    store_rows2(lb, out, out, 1<<30, base, nrows, l);
  }
}

// ---------- MFMA finalize: out = leaky0.2((acc/s)@W + b); OUTBF -> bf16 else f32 ----------
template<int OUTBF>
__global__ void __launch_bounds__(256) mfma_fin_k(
    const float* __restrict__ acc, const float* __restrict__ sdst,
    const float* __restrict__ W, const float* __restrict__ b,
    void* __restrict__ out, int N)
{
  __shared__ float lbuf[4][16*LDT];
  int l   = threadIdx.x & 63;
  int wid = threadIdx.x >> 6;
  float* lb = lbuf[wid];
  int r16 = l & 15, g = l >> 4;
  bf16x8 wf[2][4];
  #pragma unroll
  for (int kt = 0; kt < 2; ++kt)
    #pragma unroll
    for (int nt = 0; nt < 4; ++nt) wf[kt][nt] = bfrag(W, kt, nt, l);
  float bias[4];
  #pragma unroll
  for (int nt = 0; nt < 4; ++nt) bias[nt] = b[nt*16 + r16];

  int ngrp = (N + 15) >> 4;
  for (int grp = blockIdx.x*4 + wid; grp < ngrp; grp += gridDim.x*4){
    int base = grp * 16;
    int ar = base + r16; if (ar >= N) ar = N - 1;
    float s = sdst[ar];
    float inv = (s > 0.f) ? 1.0f / s : 0.0f;
    const float* row = acc + (size_t)ar * 64;
    bf16x8 a0 = afrag_f32s(row + g*8, inv);
    bf16x8 a1 = afrag_f32s(row + 32 + g*8, inv);
    f32x4 o[4];
    #pragma unroll
    for (int nt = 0; nt < 4; ++nt){
      f32x4 v; v[0]=bias[nt]; v[1]=bias[nt]; v[2]=bias[nt]; v[3]=bias[nt];
      v = MFMA(a0, wf[0][nt], v);
      v = MFMA(a1, wf[1][nt], v);
      o[nt] = v;
    }
    dwrite(lb, o, 0.2f, l);
    int nrows = N - base; if (nrows > 16) nrows = 16;
    if (OUTBF) store_rows2(lb, (u16*)out, (u16*)out, 1<<30, base, nrows, l);
    else       store_rows_f32(lb, (float*)out, base, nrows, l);
  }
}

// ---------- MFMA social finalize: hS=leaky((accS/s)@wS+bS); out=leaky(hI@W2lo + hS@W2hi + b2) ----------
__global__ void __launch_bounds__(256) mfma_fin_social_k(
    const float* __restrict__ accS, const float* __restrict__ sdst,
    const u16* __restrict__ hI,
    const float* __restrict__ wS, const float* __restrict__ bS,
    const float* __restrict__ W2, const float* __restrict__ b2,
    float* __restrict__ out, int N)
{
  __shared__ float lbuf[4][16*LDT];
  int l   = threadIdx.x & 63;
  int wid = threadIdx.x >> 6;
  float* lb = lbuf[wid];
  int r16 = l & 15, g = l >> 4;
  bf16x8 wsf[2][4], w2f[4][4];
  #pragma unroll
  for (int kt = 0; kt < 2; ++kt)
    #pragma unroll
    for (int nt = 0; nt < 4; ++nt) wsf[kt][nt] = bfrag(wS, kt, nt, l);
  #pragma unroll
  for (int kt = 0; kt < 4; ++kt)
    #pragma unroll
    for (int nt = 0; nt < 4; ++nt) w2f[kt][nt] = bfrag(W2, kt, nt, l);
  float biasS[4], bias2[4];
  #pragma unroll
  for (int nt = 0; nt < 4; ++nt){ biasS[nt] = bS[nt*16 + r16]; bias2[nt] = b2[nt*16 + r16]; }

  int ngrp = (N + 15) >> 4;
  for (int grp = blockIdx.x*4 + wid; grp < ngrp; grp += gridDim.x*4){
    int base = grp * 16;
    int ar = base + r16; if (ar >= N) ar = N - 1;
    float s = sdst[ar];
    float inv = (s > 0.f) ? 1.0f / s : 0.0f;
    const float* row = accS + (size_t)ar * 64;
    bf16x8 a0 = afrag_f32s(row + g*8, inv);
    bf16x8 a1 = afrag_f32s(row + 32 + g*8, inv);
    f32x4 hs[4];
    #pragma unroll
    for (int nt = 0; nt < 4; ++nt){
      f32x4 v; v[0]=biasS[nt]; v[1]=biasS[nt]; v[2]=biasS[nt]; v[3]=biasS[nt];
      v = MFMA(a0, wsf[0][nt], v);
      v = MFMA(a1, wsf[1][nt], v);
      hs[nt] = v;
    }
    dwrite(lb, hs, 0.2f, l);                 // hS rows (leaky applied) in LDS
    bf16x8 h0 = afrag_lds(lb, 0, l);
    bf16x8 h1 = afrag_lds(lb, 1, l);
    const u16* hrow = hI + (size_t)ar * 64;
    bf16x8 i0 = *(const bf16x8*)(hrow + g*8);
    bf16x8 i1 = *(const bf16x8*)(hrow + 32 + g*8);
    f32x4 o[4];
    #pragma unroll
    for (int nt = 0; nt < 4; ++nt){
      f32x4 v; v[0]=bias2[nt]; v[1]=bias2[nt]; v[2]=bias2[nt]; v[3]=bias2[nt];
      v = MFMA(i0, w2f[0][nt], v);
      v = MFMA(i1, w2f[1][nt], v);
      v = MFMA(h0, w2f[2][nt], v);
      v = MFMA(h1, w2f[3][nt], v);
      o[nt] = v;
    }
    dwrite(lb, o, 0.2f, l);
    int nrows = N - base; if (nrows > 16) nrows = 16;
    store_rows_f32(lb, out, base, nrows, l);
  }
}

// ---------- CSR build ----------
__global__ void hist_k(const int* __restrict__ idx, int* __restrict__ deg, int E){
  int e = blockIdx.x*256 + threadIdx.x;
  if (e < E) atomicAdd(&deg[idx[e]], 1);
}
__global__ void scan1_k(const int* __restrict__ deg, int* __restrict__ part,
                        int* __restrict__ blk, int N){
  __shared__ int sh[256];
  int i = blockIdx.x*256 + threadIdx.x;
  sh[threadIdx.x] = (i < N) ? deg[i] : 0;
  __syncthreads();
  for (int o = 1; o < 256; o <<= 1){
    int t = (threadIdx.x >= o) ? sh[threadIdx.x - o] : 0;
    __syncthreads();
    sh[threadIdx.x] += t;
    __syncthreads();
  }
  if (i < N) part[i] = sh[threadIdx.x];
  if (threadIdx.x == 255) blk[blockIdx.x] = sh[255];
}
__global__ void scan2_k(int* __restrict__ blk, int nb){
  __shared__ int sh[512];
  sh[threadIdx.x] = (threadIdx.x < nb) ? blk[threadIdx.x] : 0;
  __syncthreads();
  for (int o = 1; o < 512; o <<= 1){
    int t = (threadIdx.x >= o) ? sh[threadIdx.x - o] : 0;
    __syncthreads();
    sh[threadIdx.x] += t;
    __syncthreads();
  }
  if (threadIdx.x < nb) blk[threadIdx.x] = sh[threadIdx.x];
}
__global__ void scan3_k(const int* __restrict__ part, const int* __restrict__ blk,
                        int* __restrict__ rowptr, int N){
  int i = blockIdx.x*256 + threadIdx.x;
  if (i >= N) return;
  int add = blockIdx.x ? blk[blockIdx.x - 1] : 0;
  rowptr[i + 1] = part[i] + add;
  if (i == 0) rowptr[0] = 0;
}
__global__ void scatter_k(const int* __restrict__ idx, const int* __restrict__ rowptr,
                          int* __restrict__ cur, int* __restrict__ eids, int E){
  int e = blockIdx.x*256 + threadIdx.x;
  if (e >= E) return;
  int d = idx[e];
  int pos = rowptr[d] + atomicAdd(&cur[d], 1);
  eids[pos] = e;
}

// ---------- fused MFMA score: esc[pos] = exp(w3 . relu(W2 . relu(Y + D[dst]) + b2) + b3) ----------
template<int CY>
__global__ void __launch_bounds__(256) fscore_k(
    const int* __restrict__ eids, const int* __restrict__ keyI,
    const int* __restrict__ ratI, int kmul, const int* __restrict__ dstI,
    const u16* __restrict__ Xlo, const u16* __restrict__ Xhi, int ndout,
    int klo, int nk,
    const u16* __restrict__ Dtab,
    const float* __restrict__ Wy,
    const float* __restrict__ W2, const float* __restrict__ b2,
    const float* __restrict__ w3, const float* __restrict__ b3,
    float* __restrict__ esc, int E)
{
  __shared__ float lbuf[4][16*LDT];
  int l   = threadIdx.x & 63;
  int wid = threadIdx.x >> 6;
  int r16 = l & 15, g = l >> 4;
  float* lb = lbuf[wid];
  bf16x8 wyf[2][4], w2f[2][4];
  if (CY){
    #pragma unroll
    for (int kt = 0; kt < 2; ++kt)
      #pragma unroll
      for (int nt = 0; nt < 4; ++nt) wyf[kt][nt] = bfrag(Wy, kt, nt, l);
  }
  #pragma unroll
  for (int kt = 0; kt < 2; ++kt)
    #pragma unroll
    for (int nt = 0; nt < 4; ++nt) w2f[kt][nt] = bfrag(W2, kt, nt, l);
  f32x4 b2v[4]; float w3v[4];
  #pragma unroll
  for (int nt = 0; nt < 4; ++nt){
    float bv = b2[nt*16 + r16];
    f32x4 t; t[0]=bv; t[1]=bv; t[2]=bv; t[3]=bv;
    b2v[nt] = t;
    w3v[nt] = w3[nt*16 + r16];
  }
  float b3v = b3[0];

  int ngrp = (E + 15) >> 4;
  for (int grp = blockIdx.x*4 + wid; grp < ngrp; grp += gridDim.x*4){
    int pos = grp*16 + r16;
    int pc  = pos < E ? pos : E - 1;
    int e   = eids[pc];
    int key = keyI[e]*kmul + (ratI ? ratI[e] : 0);
    int j   = key - klo;
    bool inr = (pos < E) && ((unsigned)j < (unsigned)nk);
    unsigned long long bal = __ballot(inr ? 1 : 0);
    uint4 xa = {0,0,0,0}, xb = xa, da = xa, db = xa;
    if (inr){
      const u16* xr = (j < ndout) ? Xlo + (size_t)j * 64 : Xhi + (size_t)(j - ndout) * 64;
      xa = *(const uint4*)(xr + g*8);
      xb = *(const uint4*)(xr + 32 + g*8);
      const u16* dr = Dtab + (size_t)dstI[e] * 64;
      da = *(const uint4*)(dr + g*8);
      db = *(const uint4*)(dr + 32 + g*8);
    }
    bf16x8 p0, p1;
    float dfa[8], dfb[8];
    cvt8(da, dfa); cvt8(db, dfb);
    if (CY){
      bf16x8 a0 = *reinterpret_cast<const bf16x8*>(&xa);
      bf16x8 a1 = *reinterpret_cast<const bf16x8*>(&xb);
      f32x4 y[4];
      #pragma unroll
      for (int nt = 0; nt < 4; ++nt){
        f32x4 z; z[0]=0.f; z[1]=0.f; z[2]=0.f; z[3]=0.f;
        z = MFMA(a0, wyf[0][nt], z);
        z = MFMA(a1, wyf[1][nt], z);
        y[nt] = z;
      }
      #pragma unroll
      for (int nt = 0; nt < 4; ++nt)
        #pragma unroll
        for (int rg = 0; rg < 4; ++rg)
          lb[(4*g + rg)*LDT + nt*16 + r16] = y[nt][rg];
      const float* pr = lb + r16*LDT;
      float4 f0 = *(const float4*)(pr + g*8);
      float4 f1 = *(const float4*)(pr + g*8 + 4);
      float4 f2 = *(const float4*)(pr + 32 + g*8);
      float4 f3 = *(const float4*)(pr + 36 + g*8);
      float q0[8] = {f0.x,f0.y,f0.z,f0.w,f1.x,f1.y,f1.z,f1.w};
      float q1[8] = {f2.x,f2.y,f2.z,f2.w,f3.x,f3.y,f3.z,f3.w};
      #pragma unroll
      for (int u = 0; u < 8; ++u){
        p0[u] = (short)f2bf(fmaxf(q0[u] + dfa[u], 0.0f));
        p1[u] = (short)f2bf(fmaxf(q1[u] + dfb[u], 0.0f));
      }
    } else {
      float xfa[8], xfb[8];
      cvt8(xa, xfa); cvt8(xb, xfb);
      #pragma unroll
      for (int u = 0; u < 8; ++u){
        p0[u] = (short)f2bf(fmaxf(xfa[u] + dfa[u], 0.0f));
        p1[u] = (short)f2bf(fmaxf(xfb[u] + dfb[u], 0.0f));
      }
    }
    f32x4 o[4];
    #pragma unroll
    for (int nt = 0; nt < 4; ++nt){
      f32x4 v = b2v[nt];
      v = MFMA(p0, w2f[0][nt], v);
      v = MFMA(p1, w2f[1][nt], v);
      o[nt] = v;
    }
    float part[4] = {0.f, 0.f, 0.f, 0.f};
    #pragma unroll
    for (int nt = 0; nt < 4; ++nt)
      #pragma unroll
      for (int rg = 0; rg < 4; ++rg)
        part[rg] += fmaxf(o[nt][rg], 0.0f) * w3v[nt];
    #pragma unroll
    for (int m = 1; m < 16; m <<= 1){
      #pragma unroll
      for (int rg = 0; rg < 4; ++rg) part[rg] += __shfl_xor(part[rg], m);
    }
    if (r16 < 4){
      int eidx = 4*g + r16;
      int p2 = grp*16 + eidx;
      if (p2 < E && ((bal >> eidx) & 1))
        esc[p2] = __expf(part[r16] + b3v);
    }
  }
}

// ---------- segmented accumulate + denominator; FIRST: zero-init (no memset) ----------
template<int FIRST>
__global__ void __launch_bounds__(256) agg2_k(
    const int* __restrict__ rowptr, const int* __restrict__ eids,
    const int* __restrict__ keyI, const int* __restrict__ ratI, int kmul,
    const float* __restrict__ esc,
    const u16* __restrict__ Xlo, const u16* __restrict__ Xhi, int ndout,
    int klo, int nk,
    float* __restrict__ acc, float* __restrict__ sdst, int N)
{
  int d = blockIdx.x*256 + threadIdx.x;
  if (d >= N) return;
  float a[64];
  float* ar = acc + (size_t)d * 64;
  float s;
  if (FIRST){
    #pragma unroll
    for (int t = 0; t < 64; ++t) a[t] = 0.0f;
    s = 0.0f;
  } else {
    #pragma unroll
    for (int t = 0; t < 64; t += 4){
      float4 q = *(const float4*)(ar + t);
      a[t]=q.x; a[t+1]=q.y; a[t+2]=q.z; a[t+3]=q.w;
    }
    s = sdst[d];
  }
  int k0 = rowptr[d], k1 = rowptr[d+1];
  for (int k = k0; k < k1; ++k){
    int e = eids[k];
    int j = keyI[e]*kmul + (ratI ? ratI[e] : 0) - klo;
    if ((unsigned)j >= (unsigned)nk) continue;
    float w = esc[k];
    s += w;
    const u16* xr = (j < ndout) ? Xlo + (size_t)j * 64 : Xhi + (size_t)(j - ndout) * 64;
    #pragma unroll
    for (int kk = 0; kk < 64; kk += 8){
      uint4 q = *(const uint4*)(xr + kk);
      float f[8]; cvt8(q, f);
      #pragma unroll
      for (int u = 0; u < 8; ++u) a[kk+u] = fmaf(w, f[u], a[kk+u]);
    }
  }
  #pragma unroll
  for (int t = 0; t < 64; t += 4)
    *(float4*)(ar + t) = make_float4(a[t], a[t+1], a[t+2], a[t+3]);
  sdst[d] = s;
}

extern "C" void kernel_launch(void* const* d_in, const int* in_sizes, int n_in,
                              void* d_out, int out_size, void* d_ws, size_t ws_size,
                              hipStream_t stream) {
  (void)in_sizes; (void)n_in; (void)out_size;
  const float* user_emb   = (const float*)d_in[0];
  const float* item_emb   = (const float*)d_in[1];
  const float* rating_emb = (const float*)d_in[2];
  const float *gv_w1=(const float*)d_in[3],  *gv_b1=(const float*)d_in[4];
  const float *gv_w2=(const float*)d_in[5],  *gv_b2=(const float*)d_in[6];
  const float *aI_w1=(const float*)d_in[7],  *aI_b1=(const float*)d_in[8];
  const float *aI_w2=(const float*)d_in[9],  *aI_b2=(const float*)d_in[10];
  const float *aI_w3=(const float*)d_in[11], *aI_b3=(const float*)d_in[12];
  const float *wI_w =(const float*)d_in[13], *wI_b =(const float*)d_in[14];
  const float *aS_w1=(const float*)d_in[15], *aS_b1=(const float*)d_in[16];
  const float *aS_w2=(const float*)d_in[17], *aS_b2=(const float*)d_in[18];
  const float *aS_w3=(const float*)d_in[19], *aS_b3=(const float*)d_in[20];
  const float *wS_w =(const float*)d_in[21], *wS_b =(const float*)d_in[22];
  const float *W2_w =(const float*)d_in[23], *W2_b =(const float*)d_in[24];
  const float *gu_w1=(const float*)d_in[25], *gu_b1=(const float*)d_in[26];
  const float *gu_w2=(const float*)d_in[27], *gu_b2=(const float*)d_in[28];
  const float *aU_w1=(const float*)d_in[29], *aU_b1=(const float*)d_in[30];
  const float *aU_w2=(const float*)d_in[31], *aU_b2=(const float*)d_in[32];
  const float *aU_w3=(const float*)d_in[33], *aU_b3=(const float*)d_in[34];
  const float *wU_w =(const float*)d_in[35], *wU_b =(const float*)d_in[36];
  const int* user_e    = (const int*)d_in[37];
  const int* item_e    = (const int*)d_in[38];
  const int* rating_e  = (const int*)d_in[39];
  const int* trust_e   = (const int*)d_in[40];
  const int* trustee_e = (const int*)d_in[41];
  float* dout = (float*)d_out;

  char* base = (char*)d_ws;
  size_t cur = 0;
  auto alloc = [&](size_t bytes)->char*{
    char* p = base + cur; cur += (bytes + 255) & ~(size_t)255; return p;
  };
  u16*   hI     = (u16*)  alloc((size_t)U_N * 64 * 2);   // 12.8 MB (bf16)
  float* esc    = (float*)alloc((size_t)EUI_E * 4);      // 4 MB (CSR-position indexed)
  float* sdst   = (float*)alloc((size_t)U_N * 4);
  int*   rowptr = (int*)  alloc((size_t)(U_N + 1) * 4);
  int*   part   = (int*)  alloc((size_t)U_N * 4);
  int*   deg    = (int*)  alloc((size_t)U_N * 4);
  int*   eids   = (int*)  alloc((size_t)EUI_E * 4);
  int*   blk    = (int*)  alloc(512 * 4);
  float* acc    = (float*)alloc((size_t)U_N * 64 * 4);   // 25.6 MB
  size_t fixed_end = cur;
  if (ws_size < fixed_end + 26500000) return;
  u16* tabD = (u16*)(base + fixed_end);                  // 12.8 MB: D tables / SS
  u16* tabX = (u16*)(base + fixed_end + 13000192);       // >=13 MB: X overflow / SD
  u16* Xdout = (u16*)d_out;                              // d_out scratch (overwritten later)

  auto cdiv = [](int a, int b){ return (a + b - 1) / b; };
  auto buildCSR = [&](const int* dstIdx, int E, int N){
    hipMemsetAsync(deg, 0, (size_t)N * 4, stream);
    hist_k<<<cdiv(E,256), 256, 0, stream>>>(dstIdx, deg, E);
    int nb = cdiv(N, 256);
    scan1_k<<<nb, 256, 0, stream>>>(deg, part, blk, N);
    scan2_k<<<1, 512, 0, stream>>>(blk, nb);
    scan3_k<<<nb, 256, 0, stream>>>(part, blk, rowptr, N);
    hipMemsetAsync(deg, 0, (size_t)N * 4, stream);
    scatter_k<<<cdiv(E,256), 256, 0, stream>>>(dstIdx, rowptr, deg, eids, E);
  };
  auto gCap = [&](int groups){ int g = cdiv(groups, 4); return g > 1536 ? 1536 : g; };

  // ============ Phase 1: ItemAgg (dst = user) ============
  {
    buildCSR(user_e, EUI_E, U_N);
    mfma_lin_k<1><<<gCap(cdiv(U_N,16)), 256, 0, stream>>>(user_emb, aI_w1 + 64*64, aI_b1, 1, tabD, U_N);
    const int NK = 250000, ND = NDOUT;
    mfma_pair_k<<<gCap(cdiv(NK,16)), 256, 0, stream>>>(item_emb, rating_emb,
        gv_w1, gv_b1, gv_w2, gv_b2, 0.01f, 0, NK, Xdout, tabX, ND);
    fscore_k<1><<<gCap(cdiv(EUI_E,16)), 256, 0, stream>>>(eids, item_e, rating_e, 5, user_e,
        Xdout, tabX, ND, 0, NK, tabD, aI_w1, aI_w2, aI_b2, aI_w3, aI_b3, esc, EUI_E);
    agg2_k<1><<<cdiv(U_N,256), 256, 0, stream>>>(rowptr, eids, item_e, rating_e, 5,
        esc, Xdout, tabX, ND, 0, NK, acc, sdst, U_N);
    mfma_fin_k<1><<<gCap(cdiv(U_N,16)), 256, 0, stream>>>(acc, sdst, wI_w, wI_b, hI, U_N);
  }

  // ============ Phase 2: UserAgg (dst = item) ============
  {
    buildCSR(item_e, EUI_E, I_N);
    mfma_lin_k<1><<<gCap(cdiv(I_N,16)), 256, 0, stream>>>(item_emb, aU_w1 + 64*64, aU_b1, 1, tabD, I_N);
    for (int klo = 0; klo < 500000; klo += 250000){
      const int NK = 250000, ND = NDOUT;
      mfma_pair_k<<<gCap(cdiv(NK,16)), 256, 0, stream>>>(user_emb, rating_emb,
          gu_w1, gu_b1, gu_w2, gu_b2, 0.0f, klo, klo + NK, Xdout, tabX, ND);
      fscore_k<1><<<gCap(cdiv(EUI_E,16)), 256, 0, stream>>>(eids, user_e, rating_e, 5, item_e,
          Xdout, tabX, ND, klo, NK, tabD, aU_w1, aU_w2, aU_b2, aU_w3, aU_b3, esc, EUI_E);
      if (klo == 0)
        agg2_k<1><<<cdiv(I_N,256), 256, 0, stream>>>(rowptr, eids, user_e, rating_e, 5,
            esc, Xdout, tabX, ND, klo, NK, acc, sdst, I_N);
      else
        agg2_k<0><<<cdiv(I_N,256), 256, 0, stream>>>(rowptr, eids, user_e, rating_e, 5,
            esc, Xdout, tabX, ND, klo, NK, acc, sdst, I_N);
    }
    mfma_fin_k<0><<<gCap(cdiv(I_N,16)), 256, 0, stream>>>(acc, sdst, wU_w, wU_b,
        dout + (size_t)U_N * 64, I_N);
  }

  // ============ Phase 3: SocialAgg (dst = trustee) ============
  {
    buildCSR(trustee_e, EUU_E, U_N);
    mfma_lin_k<1><<<gCap(cdiv(U_N,16)), 256, 0, stream>>>(user_emb, aS_w1, aS_b1, 0, tabD, U_N); // SS
    mfma_lin_k<0><<<gCap(cdiv(U_N,16)), 256, 0, stream>>>(hI, aS_w1 + 64*64, aS_b1, 1, tabX, U_N); // SD
    fscore_k<0><<<gCap(cdiv(EUU_E,16)), 256, 0, stream>>>(eids, trust_e, (const int*)nullptr, 1, trustee_e,
        tabD, tabD, U_N, 0, U_N, tabX, (const float*)nullptr, aS_w2, aS_b2, aS_w3, aS_b3, esc, EUU_E);
    agg2_k<1><<<cdiv(U_N,256), 256, 0, stream>>>(rowptr, eids, trust_e, (const int*)nullptr, 1,
        esc, hI, hI, U_N, 0, U_N, acc, sdst, U_N);
    mfma_fin_social_k<<<gCap(cdiv(U_N,16)), 256, 0, stream>>>(acc, sdst, hI,
        wS_w, wS_b, W2_w, W2_b, dout, U_N);
  }
}

// Round 7
// 698.346 us; speedup vs baseline: 15.4161x; 1.3054x over previous
//
#include <hip/hip_runtime.h>

// GraphRec forward, MI355X. Round 7: sorted edge payloads kd={key,dst} (seq
// reads in score/agg), 4-lane-per-dst aggregation, full-d_out X scratch.
// Inputs f32, output f32.

typedef unsigned int   u32;
typedef unsigned short u16;
typedef short bf16x8 __attribute__((ext_vector_type(8)));
typedef float f32x4  __attribute__((ext_vector_type(4)));

#define U_N   100000
#define I_N   50000
#define EUI_E 1000000
#define EUU_E 500000
#define DOUT_ROWS 300000   // bf16 X rows that fit in d_out (150k f32 rows)

// ---------- helpers ----------
__device__ __forceinline__ float bflo(u32 u){ return __uint_as_float(u << 16); }
__device__ __forceinline__ float bfhi(u32 u){ return __uint_as_float(u & 0xffff0000u); }
__device__ __forceinline__ u16 f2bf(float f){
  u32 x = __float_as_uint(f);
  x += 0x7fffu + ((x >> 16) & 1u);
  return (u16)(x >> 16);
}
__device__ __forceinline__ u32 pk2(float a, float b){
  return (u32)f2bf(a) | ((u32)f2bf(b) << 16);
}
__device__ __forceinline__ float actf(float x, float s){ return fmaxf(x, x * s); }
__device__ __forceinline__ void cvt8(uint4 q, float f[8]){
  f[0]=bflo(q.x); f[1]=bfhi(q.x); f[2]=bflo(q.y); f[3]=bfhi(q.y);
  f[4]=bflo(q.z); f[5]=bfhi(q.z); f[6]=bflo(q.w); f[7]=bfhi(q.w);
}

// ---------- MFMA fragment helpers (16x16x32 bf16) ----------
// A: lane l holds row (l&15), k = 8*(l>>4)+j. B: col (l&15), k = 8*(l>>4)+j.
// D: col (l&15), row = 4*(l>>4)+reg  [validated on HW rounds 4-6].
__device__ __forceinline__ bf16x8 bfrag(const float* __restrict__ W, int kt, int nt, int l){
  int c = l & 15, g = l >> 4;
  const float* p = W + (size_t)(kt*32 + g*8) * 64 + nt*16 + c;
  bf16x8 r;
  #pragma unroll
  for (int j = 0; j < 8; ++j) r[j] = (short)f2bf(p[(size_t)j * 64]);
  return r;
}
__device__ __forceinline__ bf16x8 afrag_f32(const float* p){
  float4 a = *(const float4*)p, b = *(const float4*)(p + 4);
  bf16x8 r;
  r[0]=(short)f2bf(a.x); r[1]=(short)f2bf(a.y); r[2]=(short)f2bf(a.z); r[3]=(short)f2bf(a.w);
  r[4]=(short)f2bf(b.x); r[5]=(short)f2bf(b.y); r[6]=(short)f2bf(b.z); r[7]=(short)f2bf(b.w);
  return r;
}
__device__ __forceinline__ bf16x8 afrag_f32s(const float* p, float s){
  float4 a = *(const float4*)p, b = *(const float4*)(p + 4);
  bf16x8 r;
  r[0]=(short)f2bf(a.x*s); r[1]=(short)f2bf(a.y*s); r[2]=(short)f2bf(a.z*s); r[3]=(short)f2bf(a.w*s);
  r[4]=(short)f2bf(b.x*s); r[5]=(short)f2bf(b.y*s); r[6]=(short)f2bf(b.z*s); r[7]=(short)f2bf(b.w*s);
  return r;
}
#define LDT 68   // LDS row stride (floats)
__device__ __forceinline__ void dwrite(float* lb, const f32x4* acc, float slope, int l){
  int c = l & 15, g = l >> 4;
  #pragma unroll
  for (int nt = 0; nt < 4; ++nt){
    #pragma unroll
    for (int rg = 0; rg < 4; ++rg)
      lb[(4*g + rg)*LDT + nt*16 + c] = actf(acc[nt][rg], slope);
  }
}
__device__ __forceinline__ bf16x8 afrag_lds(const float* lb, int kt, int l){
  int r = l & 15, g = l >> 4;
  return afrag_f32(lb + r*LDT + kt*32 + g*8);
}
// store 16 rows of 64 f32 from LDS to bf16 table split across two regions
__device__ __forceinline__ void store_rows2(const float* lb, u16* lo, u16* hi, int ndout,
                                            int base, int nrows, int l){
  int r = l >> 2, q = l & 3;
  if (r >= nrows) return;
  int row = base + r;
  u16* out = (row < ndout) ? lo + (size_t)row * 64 : hi + (size_t)(row - ndout) * 64;
  const float* src = lb + r*LDT + q*16;
  float4 a = *(const float4*)src, b = *(const float4*)(src+4);
  float4 c = *(const float4*)(src+8), d = *(const float4*)(src+12);
  uint4 w0, w1;
  w0.x = pk2(a.x,a.y); w0.y = pk2(a.z,a.w); w0.z = pk2(b.x,b.y); w0.w = pk2(b.z,b.w);
  w1.x = pk2(c.x,c.y); w1.y = pk2(c.z,c.w); w1.z = pk2(d.x,d.y); w1.w = pk2(d.z,d.w);
  u32* dst = (u32*)(out + (size_t)q*16);
  *(uint4*)dst = w0;
  *(uint4*)(dst + 4) = w1;
}
__device__ __forceinline__ void store_rows_f32(const float* lb, float* out,
                                               int base, int nrows, int l){
  int r = l >> 2, q = l & 3;
  if (r >= nrows) return;
  const float* src = lb + r*LDT + q*16;
  float* dst = out + (size_t)(base + r)*64 + q*16;
  *(float4*)(dst)    = *(const float4*)(src);
  *(float4*)(dst+4)  = *(const float4*)(src+4);
  *(float4*)(dst+8)  = *(const float4*)(src+8);
  *(float4*)(dst+12) = *(const float4*)(src+12);
}
#define MFMA(a,b,c) __builtin_amdgcn_mfma_f32_16x16x32_bf16((a),(b),(c),0,0,0)

// ---------- pair-table value MLP ----------
__global__ void __launch_bounds__(256) mfma_pair_k(
    const float* __restrict__ embA, const float* __restrict__ embR,
    const float* __restrict__ W1, const float* __restrict__ b1,
    const float* __restrict__ W2, const float* __restrict__ b2,
    float slope, int plo, int phi, u16* __restrict__ Xlo, u16* __restrict__ Xhi, int ndout)
{
  __shared__ float lbuf[4][16*LDT];
  int l   = threadIdx.x & 63;
  int wid = threadIdx.x >> 6;
  float* lb = lbuf[wid];
  int c = l & 15;
  bf16x8 w1f[4][4], w2f[2][4];
  #pragma unroll
  for (int kt = 0; kt < 4; ++kt)
    #pragma unroll
    for (int nt = 0; nt < 4; ++nt) w1f[kt][nt] = bfrag(W1, kt, nt, l);
  #pragma unroll
  for (int kt = 0; kt < 2; ++kt)
    #pragma unroll
    for (int nt = 0; nt < 4; ++nt) w2f[kt][nt] = bfrag(W2, kt, nt, l);
  float bias1[4], bias2[4];
  #pragma unroll
  for (int nt = 0; nt < 4; ++nt){ bias1[nt] = b1[nt*16 + c]; bias2[nt] = b2[nt*16 + c]; }

  int n = phi - plo;
  int ngrp = (n + 15) >> 4;
  for (int grp = blockIdx.x*4 + wid; grp < ngrp; grp += gridDim.x*4){
    int base = grp * 16;
    int p = plo + base + (l & 15);
    if (p >= phi) p = phi - 1;
    int i = p / 5, r = p - 5*i;
    const float* ra = embA + (size_t)i * 64;
    const float* rr = embR + (size_t)r * 64;
    bf16x8 a0 = afrag_f32(ra + (l>>4)*8);
    bf16x8 a1 = afrag_f32(ra + 32 + (l>>4)*8);
    bf16x8 a2 = afrag_f32(rr + (l>>4)*8);
    bf16x8 a3 = afrag_f32(rr + 32 + (l>>4)*8);
    f32x4 acc[4];
    #pragma unroll
    for (int nt = 0; nt < 4; ++nt){
      f32x4 v; v[0]=bias1[nt]; v[1]=bias1[nt]; v[2]=bias1[nt]; v[3]=bias1[nt];
      v = MFMA(a0, w1f[0][nt], v);
      v = MFMA(a1, w1f[1][nt], v);
      v = MFMA(a2, w1f[2][nt], v);
      v = MFMA(a3, w1f[3][nt], v);
      acc[nt] = v;
    }
    dwrite(lb, acc, slope, l);
    bf16x8 x0 = afrag_lds(lb, 0, l);
    bf16x8 x1 = afrag_lds(lb, 1, l);
    #pragma unroll
    for (int nt = 0; nt < 4; ++nt){
      f32x4 v; v[0]=bias2[nt]; v[1]=bias2[nt]; v[2]=bias2[nt]; v[3]=bias2[nt];
      v = MFMA(x0, w2f[0][nt], v);
      v = MFMA(x1, w2f[1][nt], v);
      acc[nt] = v;
    }
    dwrite(lb, acc, slope, l);
    int nrows = n - base; if (nrows > 16) nrows = 16;
    store_rows2(lb, Xlo, Xhi, ndout, base, nrows, l);
  }
}

// ---------- single linear: out_bf16 = A[N x 64] @ W[64 x 64] (+ b) ----------
template<int AF32>
__global__ void __launch_bounds__(256) mfma_lin_k(
    const void* __restrict__ A, const float* __restrict__ W, const float* __restrict__ b,
    int has_bias, u16* __restrict__ out, int N)
{
  __shared__ float lbuf[4][16*LDT];
  int l   = threadIdx.x & 63;
  int wid = threadIdx.x >> 6;
  float* lb = lbuf[wid];
  int c = l & 15;
  bf16x8 wf[2][4];
  #pragma unroll
  for (int kt = 0; kt < 2; ++kt)
    #pragma unroll
    for (int nt = 0; nt < 4; ++nt) wf[kt][nt] = bfrag(W, kt, nt, l);
  float bias[4];
  #pragma unroll
  for (int nt = 0; nt < 4; ++nt) bias[nt] = has_bias ? b[nt*16 + c] : 0.0f;

  int ngrp = (N + 15) >> 4;
  for (int grp = blockIdx.x*4 + wid; grp < ngrp; grp += gridDim.x*4){
    int base = grp * 16;
    int ar = base + (l & 15);
    if (ar >= N) ar = N - 1;
    bf16x8 a0, a1;
    if (AF32){
      const float* row = (const float*)A + (size_t)ar * 64;
      a0 = afrag_f32(row + (l>>4)*8);
      a1 = afrag_f32(row + 32 + (l>>4)*8);
    } else {
      const u16* row = (const u16*)A + (size_t)ar * 64;
      a0 = *(const bf16x8*)(row + (l>>4)*8);
      a1 = *(const bf16x8*)(row + 32 + (l>>4)*8);
    }
    f32x4 acc[4];
    #pragma unroll
    for (int nt = 0; nt < 4; ++nt){
      f32x4 v; v[0]=bias[nt]; v[1]=bias[nt]; v[2]=bias[nt]; v[3]=bias[nt];
      v = MFMA(a0, wf[0][nt], v);
      v = MFMA(a1, wf[1][nt], v);
      acc[nt] = v;
    }
    dwrite(lb, acc, 1.0f, l);
    int nrows = N - base; if (nrows > 16) nrows = 16;
    store_rows2(lb, out, out, 1<<30, base, nrows, l);
  }
}

// ---------- MFMA finalize: out = leaky0.2((acc/s)@W + b) ----------
template<int OUTBF>
__global__ void __launch_bounds__(256) mfma_fin_k(
    const float* __restrict__ acc, const float* __restrict__ sdst,
    const float* __restrict__ W, const float* __restrict__ b,
    void* __restrict__ out, int N)
{
  __shared__ float lbuf[4][16*LDT];
  int l   = threadIdx.x & 63;
  int wid = threadIdx.x >> 6;
  float* lb = lbuf[wid];
  int r16 = l & 15, g = l >> 4;
  bf16x8 wf[2][4];
  #pragma unroll
  for (int kt = 0; kt < 2; ++kt)
    #pragma unroll
    for (int nt = 0; nt < 4; ++nt) wf[kt][nt] = bfrag(W, kt, nt, l);
  float bias[4];
  #pragma unroll
  for (int nt = 0; nt < 4; ++nt) bias[nt] = b[nt*16 + r16];

  int ngrp = (N + 15) >> 4;
  for (int grp = blockIdx.x*4 + wid; grp < ngrp; grp += gridDim.x*4){
    int base = grp * 16;
    int ar = base + r16; if (ar >= N) ar = N - 1;
    float s = sdst[ar];
    float inv = (s > 0.f) ? 1.0f / s : 0.0f;
    const float* row = acc + (size_t)ar * 64;
    bf16x8 a0 = afrag_f32s(row + g*8, inv);
    bf16x8 a1 = afrag_f32s(row + 32 + g*8, inv);
    f32x4 o[4];
    #pragma unroll
    for (int nt = 0; nt < 4; ++nt){
      f32x4 v; v[0]=bias[nt]; v[1]=bias[nt]; v[2]=bias[nt]; v[3]=bias[nt];
      v = MFMA(a0, wf[0][nt], v);
      v = MFMA(a1, wf[1][nt], v);
      o[nt] = v;
    }
    dwrite(lb, o, 0.2f, l);
    int nrows = N - base; if (nrows > 16) nrows = 16;
    if (OUTBF) store_rows2(lb, (u16*)out, (u16*)out, 1<<30, base, nrows, l);
    else       store_rows_f32(lb, (float*)out, base, nrows, l);
  }
}

// ---------- MFMA social finalize ----------
__global__ void __launch_bounds__(256) mfma_fin_social_k(
    const float* __restrict__ accS, const float* __restrict__ sdst,
    const u16* __restrict__ hI,
    const float* __restrict__ wS, const float* __restrict__ bS,
    const float* __restrict__ W2, const float* __restrict__ b2,
    float* __restrict__ out, int N)
{
  __shared__ float lbuf[4][16*LDT];
  int l   = threadIdx.x & 63;
  int wid = threadIdx.x >> 6;
  float* lb = lbuf[wid];
  int r16 = l & 15, g = l >> 4;
  bf16x8 wsf[2][4], w2f[4][4];
  #pragma unroll
  for (int kt = 0; kt < 2; ++kt)
    #pragma unroll
    for (int nt = 0; nt < 4; ++nt) wsf[kt][nt] = bfrag(wS, kt, nt, l);
  #pragma unroll
  for (int kt = 0; kt < 4; ++kt)
    #pragma unroll
    for (int nt = 0; nt < 4; ++nt) w2f[kt][nt] = bfrag(W2, kt, nt, l);
  float biasS[4], bias2[4];
  #pragma unroll
  for (int nt = 0; nt < 4; ++nt){ biasS[nt] = bS[nt*16 + r16]; bias2[nt] = b2[nt*16 + r16]; }

  int ngrp = (N + 15) >> 4;
  for (int grp = blockIdx.x*4 + wid; grp < ngrp; grp += gridDim.x*4){
    int base = grp * 16;
    int ar = base + r16; if (ar >= N) ar = N - 1;
    float s = sdst[ar];
    float inv = (s > 0.f) ? 1.0f / s : 0.0f;
    const float* row = accS + (size_t)ar * 64;
    bf16x8 a0 = afrag_f32s(row + g*8, inv);
    bf16x8 a1 = afrag_f32s(row + 32 + g*8, inv);
    f32x4 hs[4];
    #pragma unroll
    for (int nt = 0; nt < 4; ++nt){
      f32x4 v; v[0]=biasS[nt]; v[1]=biasS[nt]; v[2]=biasS[nt]; v[3]=biasS[nt];
      v = MFMA(a0, wsf[0][nt], v);
      v = MFMA(a1, wsf[1][nt], v);
      hs[nt] = v;
    }
    dwrite(lb, hs, 0.2f, l);
    bf16x8 h0 = afrag_lds(lb, 0, l);
    bf16x8 h1 = afrag_lds(lb, 1, l);
    const u16* hrow = hI + (size_t)ar * 64;
    bf16x8 i0 = *(const bf16x8*)(hrow + g*8);
    bf16x8 i1 = *(const bf16x8*)(hrow + 32 + g*8);
    f32x4 o[4];
    #pragma unroll
    for (int nt = 0; nt < 4; ++nt){
      f32x4 v; v[0]=bias2[nt]; v[1]=bias2[nt]; v[2]=bias2[nt]; v[3]=bias2[nt];
      v = MFMA(i0, w2f[0][nt], v);
      v = MFMA(i1, w2f[1][nt], v);
      v = MFMA(h0, w2f[2][nt], v);
      v = MFMA(h1, w2f[3][nt], v);
      o[nt] = v;
    }
    dwrite(lb, o, 0.2f, l);
    int nrows = N - base; if (nrows > 16) nrows = 16;
    store_rows_f32(lb, out, base, nrows, l);
  }
}

// ---------- CSR build ----------
__global__ void hist_k(const int* __restrict__ idx, int* __restrict__ deg, int E){
  int e = blockIdx.x*256 + threadIdx.x;
  if (e < E) atomicAdd(&deg[idx[e]], 1);
}
__global__ void scan1_k(const int* __restrict__ deg, int* __restrict__ part,
                        int* __restrict__ blk, int N){
  __shared__ int sh[256];
  int i = blockIdx.x*256 + threadIdx.x;
  sh[threadIdx.x] = (i < N) ? deg[i] : 0;
  __syncthreads();
  for (int o = 1; o < 256; o <<= 1){
    int t = (threadIdx.x >= o) ? sh[threadIdx.x - o] : 0;
    __syncthreads();
    sh[threadIdx.x] += t;
    __syncthreads();
  }
  if (i < N) part[i] = sh[threadIdx.x];
  if (threadIdx.x == 255) blk[blockIdx.x] = sh[255];
}
__global__ void scan2_k(int* __restrict__ blk, int nb){
  __shared__ int sh[512];
  sh[threadIdx.x] = (threadIdx.x < nb) ? blk[threadIdx.x] : 0;
  __syncthreads();
  for (int o = 1; o < 512; o <<= 1){
    int t = (threadIdx.x >= o) ? sh[threadIdx.x - o] : 0;
    __syncthreads();
    sh[threadIdx.x] += t;
    __syncthreads();
  }
  if (threadIdx.x < nb) blk[threadIdx.x] = sh[threadIdx.x];
}
__global__ void scan3_k(const int* __restrict__ part, const int* __restrict__ blk,
                        int* __restrict__ rowptr, int N){
  int i = blockIdx.x*256 + threadIdx.x;
  if (i >= N) return;
  int add = blockIdx.x ? blk[blockIdx.x - 1] : 0;
  rowptr[i + 1] = part[i] + add;
  if (i == 0) rowptr[0] = 0;
}
// scatter sorted payload kd[pos] = {key, dst} (8B nontemporal store)
__global__ void scatter_k(const int* __restrict__ keyI, const int* __restrict__ ratI,
                          int kmul, const int* __restrict__ dstI,
                          const int* __restrict__ rowptr, int* __restrict__ cur,
                          int2* __restrict__ kd, int E){
  int e = blockIdx.x*256 + threadIdx.x;
  if (e >= E) return;
  int d = dstI[e];
  int key = keyI[e]*kmul + (ratI ? ratI[e] : 0);
  int pos = rowptr[d] + atomicAdd(&cur[d], 1);
  long long v = ((long long)d << 32) | (unsigned)key;   // int2{x=key, y=d}
  __builtin_nontemporal_store(v, (long long*)(kd + pos));
}

// ---------- fused MFMA score over sorted edges ----------
template<int CY>
__global__ void __launch_bounds__(256) fscore_k(
    const int2* __restrict__ kd,
    const u16* __restrict__ Xlo, const u16* __restrict__ Xhi, int ndout,
    int klo, int nk,
    const u16* __restrict__ Dtab,
    const float* __restrict__ Wy,
    const float* __restrict__ W2, const float* __restrict__ b2,
    const float* __restrict__ w3, const float* __restrict__ b3,
    float* __restrict__ esc, int E)
{
  __shared__ float lbuf[4][16*LDT];
  int l   = threadIdx.x & 63;
  int wid = threadIdx.x >> 6;
  int r16 = l & 15, g = l >> 4;
  float* lb = lbuf[wid];
  bf16x8 wyf[2][4], w2f[2][4];
  if (CY){
    #pragma unroll
    for (int kt = 0; kt < 2; ++kt)
      #pragma unroll
      for (int nt = 0; nt < 4; ++nt) wyf[kt][nt] = bfrag(Wy, kt, nt, l);
  }
  #pragma unroll
  for (int kt = 0; kt < 2; ++kt)
    #pragma unroll
    for (int nt = 0; nt < 4; ++nt) w2f[kt][nt] = bfrag(W2, kt, nt, l);
  f32x4 b2v[4]; float w3v[4];
  #pragma unroll
  for (int nt = 0; nt < 4; ++nt){
    float bv = b2[nt*16 + r16];
    f32x4 t; t[0]=bv; t[1]=bv; t[2]=bv; t[3]=bv;
    b2v[nt] = t;
    w3v[nt] = w3[nt*16 + r16];
  }
  float b3v = b3[0];

  int ngrp = (E + 15) >> 4;
  for (int grp = blockIdx.x*4 + wid; grp < ngrp; grp += gridDim.x*4){
    int pos = grp*16 + r16;
    int pc  = pos < E ? pos : E - 1;
    int2 kde = kd[pc];
    int j   = kde.x - klo;
    bool inr = (pos < E) && ((unsigned)j < (unsigned)nk);
    unsigned long long bal = __ballot(inr ? 1 : 0);
    uint4 xa = {0,0,0,0}, xb = xa, da = xa, db = xa;
    if (inr){
      const u16* xr = (j < ndout) ? Xlo + (size_t)j * 64 : Xhi + (size_t)(j - ndout) * 64;
      xa = *(const uint4*)(xr + g*8);
      xb = *(const uint4*)(xr + 32 + g*8);
      const u16* dr = Dtab + (size_t)kde.y * 64;
      da = *(const uint4*)(dr + g*8);
      db = *(const uint4*)(dr + 32 + g*8);
    }
    bf16x8 p0, p1;
    float dfa[8], dfb[8];
    cvt8(da, dfa); cvt8(db, dfb);
    if (CY){
      bf16x8 a0 = *reinterpret_cast<const bf16x8*>(&xa);
      bf16x8 a1 = *reinterpret_cast<const bf16x8*>(&xb);
      f32x4 y[4];
      #pragma unroll
      for (int nt = 0; nt < 4; ++nt){
        f32x4 z; z[0]=0.f; z[1]=0.f; z[2]=0.f; z[3]=0.f;
        z = MFMA(a0, wyf[0][nt], z);
        z = MFMA(a1, wyf[1][nt], z);
        y[nt] = z;
      }
      #pragma unroll
      for (int nt = 0; nt < 4; ++nt)
        #pragma unroll
        for (int rg = 0; rg < 4; ++rg)
          lb[(4*g + rg)*LDT + nt*16 + r16] = y[nt][rg];
      const float* pr = lb + r16*LDT;
      float4 f0 = *(const float4*)(pr + g*8);
      float4 f1 = *(const float4*)(pr + g*8 + 4);
      float4 f2 = *(const float4*)(pr + 32 + g*8);
      float4 f3 = *(const float4*)(pr + 36 + g*8);
      float q0[8] = {f0.x,f0.y,f0.z,f0.w,f1.x,f1.y,f1.z,f1.w};
      float q1[8] = {f2.x,f2.y,f2.z,f2.w,f3.x,f3.y,f3.z,f3.w};
      #pragma unroll
      for (int u = 0; u < 8; ++u){
        p0[u] = (short)f2bf(fmaxf(q0[u] + dfa[u], 0.0f));
        p1[u] = (short)f2bf(fmaxf(q1[u] + dfb[u], 0.0f));
      }
    } else {
      float xfa[8], xfb[8];
      cvt8(xa, xfa); cvt8(xb, xfb);
      #pragma unroll
      for (int u = 0; u < 8; ++u){
        p0[u] = (short)f2bf(fmaxf(xfa[u] + dfa[u], 0.0f));
        p1[u] = (short)f2bf(fmaxf(xfb[u] + dfb[u], 0.0f));
      }
    }
    f32x4 o[4];
    #pragma unroll
    for (int nt = 0; nt < 4; ++nt){
      f32x4 v = b2v[nt];
      v = MFMA(p0, w2f[0][nt], v);
      v = MFMA(p1, w2f[1][nt], v);
      o[nt] = v;
    }
    float part[4] = {0.f, 0.f, 0.f, 0.f};
    #pragma unroll
    for (int nt = 0; nt < 4; ++nt)
      #pragma unroll
      for (int rg = 0; rg < 4; ++rg)
        part[rg] += fmaxf(o[nt][rg], 0.0f) * w3v[nt];
    #pragma unroll
    for (int m = 1; m < 16; m <<= 1){
      #pragma unroll
      for (int rg = 0; rg < 4; ++rg) part[rg] += __shfl_xor(part[rg], m);
    }
    if (r16 < 4){
      int eidx = 4*g + r16;
      int p2 = grp*16 + eidx;
      if (p2 < E && ((bal >> eidx) & 1))
        esc[p2] = __expf(part[r16] + b3v);
    }
  }
}

// ---------- 4-lane-per-dst segmented accumulate + denominator ----------
template<int FIRST>
__global__ void __launch_bounds__(256) agg4_k(
    const int* __restrict__ rowptr, const int2* __restrict__ kd,
    const float* __restrict__ esc,
    const u16* __restrict__ Xlo, const u16* __restrict__ Xhi, int ndout,
    int klo, int nk,
    float* __restrict__ acc, float* __restrict__ sdst, int N)
{
  int t = blockIdx.x*256 + threadIdx.x;
  int d = t >> 2, q = t & 3;
  if (d >= N) return;
  float a[16];
  float* ar = acc + (size_t)d * 64 + q*16;
  float s;
  if (FIRST){
    #pragma unroll
    for (int u = 0; u < 16; ++u) a[u] = 0.0f;
    s = 0.0f;
  } else {
    #pragma unroll
    for (int u = 0; u < 16; u += 4){
      float4 v = *(const float4*)(ar + u);
      a[u]=v.x; a[u+1]=v.y; a[u+2]=v.z; a[u+3]=v.w;
    }
    s = sdst[d];
  }
  int k0 = rowptr[d], k1 = rowptr[d+1];
  for (int k = k0; k < k1; ++k){
    int key = kd[k].x - klo;
    if ((unsigned)key >= (unsigned)nk) continue;
    float w = esc[k];
    s += w;
    const u16* xr = ((key < ndout) ? Xlo + (size_t)key * 64
                                   : Xhi + (size_t)(key - ndout) * 64) + q*16;
    uint4 q0 = *(const uint4*)xr;
    uint4 q1 = *(const uint4*)(xr + 8);
    float f0[8], f1[8]; cvt8(q0, f0); cvt8(q1, f1);
    #pragma unroll
    for (int u = 0; u < 8; ++u){
      a[u]     = fmaf(w, f0[u], a[u]);
      a[u + 8] = fmaf(w, f1[u], a[u + 8]);
    }
  }
  #pragma unroll
  for (int u = 0; u < 16; u += 4)
    *(float4*)(ar + u) = make_float4(a[u], a[u+1], a[u+2], a[u+3]);
  if (q == 0) sdst[d] = s;
}

extern "C" void kernel_launch(void* const* d_in, const int* in_sizes, int n_in,
                              void* d_out, int out_size, void* d_ws, size_t ws_size,
                              hipStream_t stream) {
  (void)in_sizes; (void)n_in; (void)out_size;
  const float* user_emb   = (const float*)d_in[0];
  const float* item_emb   = (const float*)d_in[1];
  const float* rating_emb = (const float*)d_in[2];
  const float *gv_w1=(const float*)d_in[3],  *gv_b1=(const float*)d_in[4];
  const float *gv_w2=(const float*)d_in[5],  *gv_b2=(const float*)d_in[6];
  const float *aI_w1=(const float*)d_in[7],  *aI_b1=(const float*)d_in[8];
  const float *aI_w2=(const float*)d_in[9],  *aI_b2=(const float*)d_in[10];
  const float *aI_w3=(const float*)d_in[11], *aI_b3=(const float*)d_in[12];
  const float *wI_w =(const float*)d_in[13], *wI_b =(const float*)d_in[14];
  const float *aS_w1=(const float*)d_in[15], *aS_b1=(const float*)d_in[16];
  const float *aS_w2=(const float*)d_in[17], *aS_b2=(const float*)d_in[18];
  const float *aS_w3=(const float*)d_in[19], *aS_b3=(const float*)d_in[20];
  const float *wS_w =(const float*)d_in[21], *wS_b =(const float*)d_in[22];
  const float *W2_w =(const float*)d_in[23], *W2_b =(const float*)d_in[24];
  const float *gu_w1=(const float*)d_in[25], *gu_b1=(const float*)d_in[26];
  const float *gu_w2=(const float*)d_in[27], *gu_b2=(const float*)d_in[28];
  const float *aU_w1=(const float*)d_in[29], *aU_b1=(const float*)d_in[30];
  const float *aU_w2=(const float*)d_in[31], *aU_b2=(const float*)d_in[32];
  const float *aU_w3=(const float*)d_in[33], *aU_b3=(const float*)d_in[34];
  const float *wU_w =(const float*)d_in[35], *wU_b =(const float*)d_in[36];
  const int* user_e    = (const int*)d_in[37];
  const int* item_e    = (const int*)d_in[38];
  const int* rating_e  = (const int*)d_in[39];
  const int* trust_e   = (const int*)d_in[40];
  const int* trustee_e = (const int*)d_in[41];
  float* dout = (float*)d_out;

  char* base = (char*)d_ws;
  size_t cur = 0;
  auto alloc = [&](size_t bytes)->char*{
    char* p = base + cur; cur += (bytes + 255) & ~(size_t)255; return p;
  };
  u16*   hI     = (u16*)  alloc((size_t)U_N * 64 * 2);   // 12.8 MB (bf16)
  float* esc    = (float*)alloc((size_t)EUI_E * 4);      // 4 MB (CSR-position)
  float* sdst   = (float*)alloc((size_t)U_N * 4);
  int*   rowptr = (int*)  alloc((size_t)(U_N + 1) * 4);
  int*   part   = (int*)  alloc((size_t)U_N * 4);
  int*   deg    = (int*)  alloc((size_t)U_N * 4);
  int2*  kd     = (int2*) alloc((size_t)EUI_E * 8);      // 8 MB sorted {key,dst}
  int*   blk    = (int*)  alloc(512 * 4);
  float* acc    = (float*)alloc((size_t)U_N * 64 * 4);   // 25.6 MB
  size_t fixed_end = cur;
  if (ws_size < fixed_end + 13100000) return;            // arena >= 13.1 MB
  u16* tabD = (u16*)(base + fixed_end);                  // 12.8 MB D tables / SS
  u16* tabX = (u16*)(base + fixed_end + 6500352);        // X overflow (after 6.4MB item-D)
  size_t arena = ws_size - fixed_end;
  u16* Xdout = (u16*)d_out;                              // 300k bf16 rows scratch

  auto cdiv = [](int a, int b){ return (a + b - 1) / b; };
  auto buildCSR = [&](const int* keyI, const int* ratI, int kmul,
                      const int* dstIdx, int E, int N){
    hipMemsetAsync(deg, 0, (size_t)N * 4, stream);
    hist_k<<<cdiv(E,256), 256, 0, stream>>>(dstIdx, deg, E);
    int nb = cdiv(N, 256);
    scan1_k<<<nb, 256, 0, stream>>>(deg, part, blk, N);
    scan2_k<<<1, 512, 0, stream>>>(blk, nb);
    scan3_k<<<nb, 256, 0, stream>>>(part, blk, rowptr, N);
    hipMemsetAsync(deg, 0, (size_t)N * 4, stream);
    scatter_k<<<cdiv(E,256), 256, 0, stream>>>(keyI, ratI, kmul, dstIdx, rowptr, deg, kd, E);
  };
  auto gCap = [&](int groups){ int g = cdiv(groups, 4); return g > 1536 ? 1536 : g; };

  // ============ Phase 1: ItemAgg (dst = user) ============
  {
    buildCSR(item_e, rating_e, 5, user_e, EUI_E, U_N);
    mfma_lin_k<1><<<gCap(cdiv(U_N,16)), 256, 0, stream>>>(user_emb, aI_w1 + 64*64, aI_b1, 1, tabD, U_N);
    const int NK = 250000;                                // all in d_out (<=300k rows)
    mfma_pair_k<<<gCap(cdiv(NK,16)), 256, 0, stream>>>(item_emb, rating_emb,
        gv_w1, gv_b1, gv_w2, gv_b2, 0.01f, 0, NK, Xdout, Xdout, 1<<30);
    fscore_k<1><<<gCap(cdiv(EUI_E,16)), 256, 0, stream>>>(kd,
        Xdout, Xdout, 1<<30, 0, NK, tabD, aI_w1, aI_w2, aI_b2, aI_w3, aI_b3, esc, EUI_E);
    agg4_k<1><<<cdiv(U_N*4,256), 256, 0, stream>>>(rowptr, kd, esc,
        Xdout, Xdout, 1<<30, 0, NK, acc, sdst, U_N);
    mfma_fin_k<1><<<gCap(cdiv(U_N,16)), 256, 0, stream>>>(acc, sdst, wI_w, wI_b, hI, U_N);
  }

  // ============ Phase 2: UserAgg (dst = item) ============
  {
    buildCSR(user_e, rating_e, 5, item_e, EUI_E, I_N);
    mfma_lin_k<1><<<gCap(cdiv(I_N,16)), 256, 0, stream>>>(item_emb, aU_w1 + 64*64, aU_b1, 1, tabD, I_N);
    bool single = arena >= 33000000;                      // 6.4MB D + 25.6MB X overflow
    int CP = single ? 500000 : 250000;
    int ND = single ? DOUT_ROWS : (1<<30);
    for (int klo = 0; klo < 500000; klo += CP){
      mfma_pair_k<<<gCap(cdiv(CP,16)), 256, 0, stream>>>(user_emb, rating_emb,
          gu_w1, gu_b1, gu_w2, gu_b2, 0.0f, klo, klo + CP, Xdout, tabX, ND);
      fscore_k<1><<<gCap(cdiv(EUI_E,16)), 256, 0, stream>>>(kd,
          Xdout, tabX, ND, klo, CP, tabD, aU_w1, aU_w2, aU_b2, aU_w3, aU_b3, esc, EUI_E);
      if (klo == 0)
        agg4_k<1><<<cdiv(I_N*4,256), 256, 0, stream>>>(rowptr, kd, esc,
            Xdout, tabX, ND, klo, CP, acc, sdst, I_N);
      else
        agg4_k<0><<<cdiv(I_N*4,256), 256, 0, stream>>>(rowptr, kd, esc,
            Xdout, tabX, ND, klo, CP, acc, sdst, I_N);
    }
    mfma_fin_k<0><<<gCap(cdiv(I_N,16)), 256, 0, stream>>>(acc, sdst, wU_w, wU_b,
        dout + (size_t)U_N * 64, I_N);
  }

  // ============ Phase 3: SocialAgg (dst = trustee) ============
  {
    buildCSR(trust_e, (const int*)nullptr, 1, trustee_e, EUU_E, U_N);
    u16* SD = Xdout;                                      // d_out U-region scratch
    mfma_lin_k<1><<<gCap(cdiv(U_N,16)), 256, 0, stream>>>(user_emb, aS_w1, aS_b1, 0, tabD, U_N); // SS
    mfma_lin_k<0><<<gCap(cdiv(U_N,16)), 256, 0, stream>>>(hI, aS_w1 + 64*64, aS_b1, 1, SD, U_N); // SD
    fscore_k<0><<<gCap(cdiv(EUU_E,16)), 256, 0, stream>>>(kd,
        tabD, tabD, 1<<30, 0, U_N, SD, (const float*)nullptr,
        aS_w2, aS_b2, aS_w3, aS_b3, esc, EUU_E);
    agg4_k<1><<<cdiv(U_N*4,256), 256, 0, stream>>>(rowptr, kd, esc,
        hI, hI, 1<<30, 0, U_N, acc, sdst, U_N);
    mfma_fin_social_k<<<gCap(cdiv(U_N,16)), 256, 0, stream>>>(acc, sdst, hI,
        wS_w, wS_b, W2_w, W2_b, dout, U_N);
  }
}

// Round 8
// 629.461 us; speedup vs baseline: 17.1031x; 1.1094x over previous
//
#include <hip/hip_runtime.h>

// GraphRec forward, MI355X. Round 8: two-level partition scatter (XCD-local
// writes, kills 8x write amplification), else same as round 7.
// Inputs f32, output f32.

typedef unsigned int   u32;
typedef unsigned short u16;
typedef short bf16x8 __attribute__((ext_vector_type(8)));
typedef float f32x4  __attribute__((ext_vector_type(4)));

#define U_N   100000
#define I_N   50000
#define EUI_E 1000000
#define EUU_E 500000
#define DOUT_ROWS 300000
#define RANGE 256      // dsts per bucket
#define PB    256      // partition blocks

// ---------- helpers ----------
__device__ __forceinline__ float bflo(u32 u){ return __uint_as_float(u << 16); }
__device__ __forceinline__ float bfhi(u32 u){ return __uint_as_float(u & 0xffff0000u); }
__device__ __forceinline__ u16 f2bf(float f){
  u32 x = __float_as_uint(f);
  x += 0x7fffu + ((x >> 16) & 1u);
  return (u16)(x >> 16);
}
__device__ __forceinline__ u32 pk2(float a, float b){
  return (u32)f2bf(a) | ((u32)f2bf(b) << 16);
}
__device__ __forceinline__ float actf(float x, float s){ return fmaxf(x, x * s); }
__device__ __forceinline__ void cvt8(uint4 q, float f[8]){
  f[0]=bflo(q.x); f[1]=bfhi(q.x); f[2]=bflo(q.y); f[3]=bfhi(q.y);
  f[4]=bflo(q.z); f[5]=bfhi(q.z); f[6]=bflo(q.w); f[7]=bfhi(q.w);
}

// ---------- MFMA fragment helpers (16x16x32 bf16) ----------
// A: lane l holds row (l&15), k = 8*(l>>4)+j. B: col (l&15), k = 8*(l>>4)+j.
// D: col (l&15), row = 4*(l>>4)+reg  [validated on HW rounds 4-7].
__device__ __forceinline__ bf16x8 bfrag(const float* __restrict__ W, int kt, int nt, int l){
  int c = l & 15, g = l >> 4;
  const float* p = W + (size_t)(kt*32 + g*8) * 64 + nt*16 + c;
  bf16x8 r;
  #pragma unroll
  for (int j = 0; j < 8; ++j) r[j] = (short)f2bf(p[(size_t)j * 64]);
  return r;
}
__device__ __forceinline__ bf16x8 afrag_f32(const float* p){
  float4 a = *(const float4*)p, b = *(const float4*)(p + 4);
  bf16x8 r;
  r[0]=(short)f2bf(a.x); r[1]=(short)f2bf(a.y); r[2]=(short)f2bf(a.z); r[3]=(short)f2bf(a.w);
  r[4]=(short)f2bf(b.x); r[5]=(short)f2bf(b.y); r[6]=(short)f2bf(b.z); r[7]=(short)f2bf(b.w);
  return r;
}
__device__ __forceinline__ bf16x8 afrag_f32s(const float* p, float s){
  float4 a = *(const float4*)p, b = *(const float4*)(p + 4);
  bf16x8 r;
  r[0]=(short)f2bf(a.x*s); r[1]=(short)f2bf(a.y*s); r[2]=(short)f2bf(a.z*s); r[3]=(short)f2bf(a.w*s);
  r[4]=(short)f2bf(b.x*s); r[5]=(short)f2bf(b.y*s); r[6]=(short)f2bf(b.z*s); r[7]=(short)f2bf(b.w*s);
  return r;
}
#define LDT 68
__device__ __forceinline__ void dwrite(float* lb, const f32x4* acc, float slope, int l){
  int c = l & 15, g = l >> 4;
  #pragma unroll
  for (int nt = 0; nt < 4; ++nt){
    #pragma unroll
    for (int rg = 0; rg < 4; ++rg)
      lb[(4*g + rg)*LDT + nt*16 + c] = actf(acc[nt][rg], slope);
  }
}
__device__ __forceinline__ bf16x8 afrag_lds(const float* lb, int kt, int l){
  int r = l & 15, g = l >> 4;
  return afrag_f32(lb + r*LDT + kt*32 + g*8);
}
__device__ __forceinline__ void store_rows2(const float* lb, u16* lo, u16* hi, int ndout,
                                            int base, int nrows, int l){
  int r = l >> 2, q = l & 3;
  if (r >= nrows) return;
  int row = base + r;
  u16* out = (row < ndout) ? lo + (size_t)row * 64 : hi + (size_t)(row - ndout) * 64;
  const float* src = lb + r*LDT + q*16;
  float4 a = *(const float4*)src, b = *(const float4*)(src+4);
  float4 c = *(const float4*)(src+8), d = *(const float4*)(src+12);
  uint4 w0, w1;
  w0.x = pk2(a.x,a.y); w0.y = pk2(a.z,a.w); w0.z = pk2(b.x,b.y); w0.w = pk2(b.z,b.w);
  w1.x = pk2(c.x,c.y); w1.y = pk2(c.z,c.w); w1.z = pk2(d.x,d.y); w1.w = pk2(d.z,d.w);
  u32* dst = (u32*)(out + (size_t)q*16);
  *(uint4*)dst = w0;
  *(uint4*)(dst + 4) = w1;
}
__device__ __forceinline__ void store_rows_f32(const float* lb, float* out,
                                               int base, int nrows, int l){
  int r = l >> 2, q = l & 3;
  if (r >= nrows) return;
  const float* src = lb + r*LDT + q*16;
  float* dst = out + (size_t)(base + r)*64 + q*16;
  *(float4*)(dst)    = *(const float4*)(src);
  *(float4*)(dst+4)  = *(const float4*)(src+4);
  *(float4*)(dst+8)  = *(const float4*)(src+8);
  *(float4*)(dst+12) = *(const float4*)(src+12);
}
#define MFMA(a,b,c) __builtin_amdgcn_mfma_f32_16x16x32_bf16((a),(b),(c),0,0,0)

// ---------- pair-table value MLP ----------
__global__ void __launch_bounds__(256) mfma_pair_k(
    const float* __restrict__ embA, const float* __restrict__ embR,
    const float* __restrict__ W1, const float* __restrict__ b1,
    const float* __restrict__ W2, const float* __restrict__ b2,
    float slope, int plo, int phi, u16* __restrict__ Xlo, u16* __restrict__ Xhi, int ndout)
{
  __shared__ float lbuf[4][16*LDT];
  int l   = threadIdx.x & 63;
  int wid = threadIdx.x >> 6;
  float* lb = lbuf[wid];
  int c = l & 15;
  bf16x8 w1f[4][4], w2f[2][4];
  #pragma unroll
  for (int kt = 0; kt < 4; ++kt)
    #pragma unroll
    for (int nt = 0; nt < 4; ++nt) w1f[kt][nt] = bfrag(W1, kt, nt, l);
  #pragma unroll
  for (int kt = 0; kt < 2; ++kt)
    #pragma unroll
    for (int nt = 0; nt < 4; ++nt) w2f[kt][nt] = bfrag(W2, kt, nt, l);
  float bias1[4], bias2[4];
  #pragma unroll
  for (int nt = 0; nt < 4; ++nt){ bias1[nt] = b1[nt*16 + c]; bias2[nt] = b2[nt*16 + c]; }

  int n = phi - plo;
  int ngrp = (n + 15) >> 4;
  for (int grp = blockIdx.x*4 + wid; grp < ngrp; grp += gridDim.x*4){
    int base = grp * 16;
    int p = plo + base + (l & 15);
    if (p >= phi) p = phi - 1;
    int i = p / 5, r = p - 5*i;
    const float* ra = embA + (size_t)i * 64;
    const float* rr = embR + (size_t)r * 64;
    bf16x8 a0 = afrag_f32(ra + (l>>4)*8);
    bf16x8 a1 = afrag_f32(ra + 32 + (l>>4)*8);
    bf16x8 a2 = afrag_f32(rr + (l>>4)*8);
    bf16x8 a3 = afrag_f32(rr + 32 + (l>>4)*8);
    f32x4 acc[4];
    #pragma unroll
    for (int nt = 0; nt < 4; ++nt){
      f32x4 v; v[0]=bias1[nt]; v[1]=bias1[nt]; v[2]=bias1[nt]; v[3]=bias1[nt];
      v = MFMA(a0, w1f[0][nt], v);
      v = MFMA(a1, w1f[1][nt], v);
      v = MFMA(a2, w1f[2][nt], v);
      v = MFMA(a3, w1f[3][nt], v);
      acc[nt] = v;
    }
    dwrite(lb, acc, slope, l);
    bf16x8 x0 = afrag_lds(lb, 0, l);
    bf16x8 x1 = afrag_lds(lb, 1, l);
    #pragma unroll
    for (int nt = 0; nt < 4; ++nt){
      f32x4 v; v[0]=bias2[nt]; v[1]=bias2[nt]; v[2]=bias2[nt]; v[3]=bias2[nt];
      v = MFMA(x0, w2f[0][nt], v);
      v = MFMA(x1, w2f[1][nt], v);
      acc[nt] = v;
    }
    dwrite(lb, acc, slope, l);
    int nrows = n - base; if (nrows > 16) nrows = 16;
    store_rows2(lb, Xlo, Xhi, ndout, base, nrows, l);
  }
}

// ---------- single linear ----------
template<int AF32>
__global__ void __launch_bounds__(256) mfma_lin_k(
    const void* __restrict__ A, const float* __restrict__ W, const float* __restrict__ b,
    int has_bias, u16* __restrict__ out, int N)
{
  __shared__ float lbuf[4][16*LDT];
  int l   = threadIdx.x & 63;
  int wid = threadIdx.x >> 6;
  float* lb = lbuf[wid];
  int c = l & 15;
  bf16x8 wf[2][4];
  #pragma unroll
  for (int kt = 0; kt < 2; ++kt)
    #pragma unroll
    for (int nt = 0; nt < 4; ++nt) wf[kt][nt] = bfrag(W, kt, nt, l);
  float bias[4];
  #pragma unroll
  for (int nt = 0; nt < 4; ++nt) bias[nt] = has_bias ? b[nt*16 + c] : 0.0f;

  int ngrp = (N + 15) >> 4;
  for (int grp = blockIdx.x*4 + wid; grp < ngrp; grp += gridDim.x*4){
    int base = grp * 16;
    int ar = base + (l & 15);
    if (ar >= N) ar = N - 1;
    bf16x8 a0, a1;
    if (AF32){
      const float* row = (const float*)A + (size_t)ar * 64;
      a0 = afrag_f32(row + (l>>4)*8);
      a1 = afrag_f32(row + 32 + (l>>4)*8);
    } else {
      const u16* row = (const u16*)A + (size_t)ar * 64;
      a0 = *(const bf16x8*)(row + (l>>4)*8);
      a1 = *(const bf16x8*)(row + 32 + (l>>4)*8);
    }
    f32x4 acc[4];
    #pragma unroll
    for (int nt = 0; nt < 4; ++nt){
      f32x4 v; v[0]=bias[nt]; v[1]=bias[nt]; v[2]=bias[nt]; v[3]=bias[nt];
      v = MFMA(a0, wf[0][nt], v);
      v = MFMA(a1, wf[1][nt], v);
      acc[nt] = v;
    }
    dwrite(lb, acc, 1.0f, l);
    int nrows = N - base; if (nrows > 16) nrows = 16;
    store_rows2(lb, out, out, 1<<30, base, nrows, l);
  }
}

// ---------- MFMA finalize ----------
template<int OUTBF>
__global__ void __launch_bounds__(256) mfma_fin_k(
    const float* __restrict__ acc, const float* __restrict__ sdst,
    const float* __restrict__ W, const float* __restrict__ b,
    void* __restrict__ out, int N)
{
  __shared__ float lbuf[4][16*LDT];
  int l   = threadIdx.x & 63;
  int wid = threadIdx.x >> 6;
  float* lb = lbuf[wid];
  int r16 = l & 15, g = l >> 4;
  bf16x8 wf[2][4];
  #pragma unroll
  for (int kt = 0; kt < 2; ++kt)
    #pragma unroll
    for (int nt = 0; nt < 4; ++nt) wf[kt][nt] = bfrag(W, kt, nt, l);
  float bias[4];
  #pragma unroll
  for (int nt = 0; nt < 4; ++nt) bias[nt] = b[nt*16 + r16];

  int ngrp = (N + 15) >> 4;
  for (int grp = blockIdx.x*4 + wid; grp < ngrp; grp += gridDim.x*4){
    int base = grp * 16;
    int ar = base + r16; if (ar >= N) ar = N - 1;
    float s = sdst[ar];
    float inv = (s > 0.f) ? 1.0f / s : 0.0f;
    const float* row = acc + (size_t)ar * 64;
    bf16x8 a0 = afrag_f32s(row + g*8, inv);
    bf16x8 a1 = afrag_f32s(row + 32 + g*8, inv);
    f32x4 o[4];
    #pragma unroll
    for (int nt = 0; nt < 4; ++nt){
      f32x4 v; v[0]=bias[nt]; v[1]=bias[nt]; v[2]=bias[nt]; v[3]=bias[nt];
      v = MFMA(a0, wf[0][nt], v);
      v = MFMA(a1, wf[1][nt], v);
      o[nt] = v;
    }
    dwrite(lb, o, 0.2f, l);
    int nrows = N - base; if (nrows > 16) nrows = 16;
    if (OUTBF) store_rows2(lb, (u16*)out, (u16*)out, 1<<30, base, nrows, l);
    else       store_rows_f32(lb, (float*)out, base, nrows, l);
  }
}

// ---------- MFMA social finalize ----------
__global__ void __launch_bounds__(256) mfma_fin_social_k(
    const float* __restrict__ accS, const float* __restrict__ sdst,
    const u16* __restrict__ hI,
    const float* __restrict__ wS, const float* __restrict__ bS,
    const float* __restrict__ W2, const float* __restrict__ b2,
    float* __restrict__ out, int N)
{
  __shared__ float lbuf[4][16*LDT];
  int l   = threadIdx.x & 63;
  int wid = threadIdx.x >> 6;
  float* lb = lbuf[wid];
  int r16 = l & 15, g = l >> 4;
  bf16x8 wsf[2][4], w2f[4][4];
  #pragma unroll
  for (int kt = 0; kt < 2; ++kt)
    #pragma unroll
    for (int nt = 0; nt < 4; ++nt) wsf[kt][nt] = bfrag(wS, kt, nt, l);
  #pragma unroll
  for (int kt = 0; kt < 4; ++kt)
    #pragma unroll
    for (int nt = 0; nt < 4; ++nt) w2f[kt][nt] = bfrag(W2, kt, nt, l);
  float biasS[4], bias2[4];
  #pragma unroll
  for (int nt = 0; nt < 4; ++nt){ biasS[nt] = bS[nt*16 + r16]; bias2[nt] = b2[nt*16 + r16]; }

  int ngrp = (N + 15) >> 4;
  for (int grp = blockIdx.x*4 + wid; grp < ngrp; grp += gridDim.x*4){
    int base = grp * 16;
    int ar = base + r16; if (ar >= N) ar = N - 1;
    float s = sdst[ar];
    float inv = (s > 0.f) ? 1.0f / s : 0.0f;
    const float* row = accS + (size_t)ar * 64;
    bf16x8 a0 = afrag_f32s(row + g*8, inv);
    bf16x8 a1 = afrag_f32s(row + 32 + g*8, inv);
    f32x4 hs[4];
    #pragma unroll
    for (int nt = 0; nt < 4; ++nt){
      f32x4 v; v[0]=biasS[nt]; v[1]=biasS[nt]; v[2]=biasS[nt]; v[3]=biasS[nt];
      v = MFMA(a0, wsf[0][nt], v);
      v = MFMA(a1, wsf[1][nt], v);
      hs[nt] = v;
    }
    dwrite(lb, hs, 0.2f, l);
    bf16x8 h0 = afrag_lds(lb, 0, l);
    bf16x8 h1 = afrag_lds(lb, 1, l);
    const u16* hrow = hI + (size_t)ar * 64;
    bf16x8 i0 = *(const bf16x8*)(hrow + g*8);
    bf16x8 i1 = *(const bf16x8*)(hrow + 32 + g*8);
    f32x4 o[4];
    #pragma unroll
    for (int nt = 0; nt < 4; ++nt){
      f32x4 v; v[0]=bias2[nt]; v[1]=bias2[nt]; v[2]=bias2[nt]; v[3]=bias2[nt];
      v = MFMA(i0, w2f[0][nt], v);
      v = MFMA(i1, w2f[1][nt], v);
      v = MFMA(h0, w2f[2][nt], v);
      v = MFMA(h1, w2f[3][nt], v);
      o[nt] = v;
    }
    dwrite(lb, o, 0.2f, l);
    int nrows = N - base; if (nrows > 16) nrows = 16;
    store_rows_f32(lb, out, base, nrows, l);
  }
}

// ---------- CSR rowptr build ----------
__global__ void hist_k(const int* __restrict__ idx, int* __restrict__ deg, int E){
  int e = blockIdx.x*256 + threadIdx.x;
  if (e < E) atomicAdd(&deg[idx[e]], 1);
}
__global__ void scan1_k(const int* __restrict__ deg, int* __restrict__ part,
                        int* __restrict__ blk, int N){
  __shared__ int sh[256];
  int i = blockIdx.x*256 + threadIdx.x;
  sh[threadIdx.x] = (i < N) ? deg[i] : 0;
  __syncthreads();
  for (int o = 1; o < 256; o <<= 1){
    int t = (threadIdx.x >= o) ? sh[threadIdx.x - o] : 0;
    __syncthreads();
    sh[threadIdx.x] += t;
    __syncthreads();
  }
  if (i < N) part[i] = sh[threadIdx.x];
  if (threadIdx.x == 255) blk[blockIdx.x] = sh[255];
}
__global__ void scan2_k(int* __restrict__ blk, int nb){
  __shared__ int sh[512];
  sh[threadIdx.x] = (threadIdx.x < nb) ? blk[threadIdx.x] : 0;
  __syncthreads();
  for (int o = 1; o < 512; o <<= 1){
    int t = (threadIdx.x >= o) ? sh[threadIdx.x - o] : 0;
    __syncthreads();
    sh[threadIdx.x] += t;
    __syncthreads();
  }
  if (threadIdx.x < nb) blk[threadIdx.x] = sh[threadIdx.x];
}
__global__ void scan3_k(const int* __restrict__ part, const int* __restrict__ blk,
                        int* __restrict__ rowptr, int N){
  int i = blockIdx.x*256 + threadIdx.x;
  if (i >= N) return;
  int add = blockIdx.x ? blk[blockIdx.x - 1] : 0;
  rowptr[i + 1] = part[i] + add;
  if (i == 0) rowptr[0] = 0;
}

// ---------- two-level partition scatter ----------
// pass A0: per-block bucket histograms (bucket = dst >> 8)
__global__ void __launch_bounds__(256) hist2_k(const int* __restrict__ dstI, int E,
                                               int* __restrict__ H, int nb){
  __shared__ int h[512];
  for (int t = threadIdx.x; t < nb; t += 256) h[t] = 0;
  __syncthreads();
  int chunk = (E + PB - 1) / PB;
  int s = blockIdx.x * chunk;
  int e_end = s + chunk; if (e_end > E) e_end = E;
  for (int e = s + threadIdx.x; e < e_end; e += 256)
    atomicAdd(&h[dstI[e] >> 8], 1);
  __syncthreads();
  for (int t = threadIdx.x; t < nb; t += 256) H[t*PB + blockIdx.x] = h[t];
}
// pass A1: per-bucket exclusive scan across blocks + CSR base
__global__ void __launch_bounds__(PB) bscan_k(int* __restrict__ H,
                                              const int* __restrict__ rowptr, int N){
  __shared__ int sh[PB];
  int b = blockIdx.x;
  int v = H[b*PB + threadIdx.x];
  sh[threadIdx.x] = v;
  __syncthreads();
  for (int o = 1; o < PB; o <<= 1){
    int t = (threadIdx.x >= o) ? sh[threadIdx.x - o] : 0;
    __syncthreads();
    sh[threadIdx.x] += t;
    __syncthreads();
  }
  int dst0 = b * RANGE; if (dst0 > N) dst0 = N;
  int base = rowptr[dst0];
  H[b*PB + threadIdx.x] = base + sh[threadIdx.x] - v;
}
// pass A2: partition edges into bucket-contiguous kd2 (per-block runs coalesced)
__global__ void __launch_bounds__(256) part_k(
    const int* __restrict__ keyI, const int* __restrict__ ratI, int kmul,
    const int* __restrict__ dstI, const int* __restrict__ H, int nb,
    long long* __restrict__ kd2, int E){
  __shared__ int cur[512];
  for (int t = threadIdx.x; t < nb; t += 256) cur[t] = H[t*PB + blockIdx.x];
  __syncthreads();
  int chunk = (E + PB - 1) / PB;
  int s = blockIdx.x * chunk;
  int e_end = s + chunk; if (e_end > E) e_end = E;
  for (int e = s + threadIdx.x; e < e_end; e += 256){
    int d = dstI[e];
    int key = keyI[e]*kmul + (ratI ? ratI[e] : 0);
    int pos = atomicAdd(&cur[d >> 8], 1);
    long long v = ((long long)d << 32) | (unsigned)key;
    __builtin_nontemporal_store(v, kd2 + pos);
  }
}
// pass B: bucket-local final scatter (single block per bucket -> single-XCD writes)
__global__ void __launch_bounds__(256) bscatter_k(
    const long long* __restrict__ kd2, const int* __restrict__ rowptr,
    int N, long long* __restrict__ kd){
  __shared__ int cur[RANGE];
  int b = blockIdx.x;
  int dst0 = b * RANGE;
  int di = dst0 + threadIdx.x; if (di > N) di = N;
  cur[threadIdx.x] = rowptr[di];
  __syncthreads();
  int lo = rowptr[dst0 > N ? N : dst0];
  int d1 = dst0 + RANGE; if (d1 > N) d1 = N;
  int hi = rowptr[d1];
  for (int k = lo + (int)threadIdx.x; k < hi; k += 256){
    long long v = kd2[k];
    int d = (int)(v >> 32);
    int pos = atomicAdd(&cur[d - dst0], 1);
    kd[pos] = v;
  }
}

// ---------- fused MFMA score over sorted edges ----------
template<int CY>
__global__ void __launch_bounds__(256) fscore_k(
    const int2* __restrict__ kd,
    const u16* __restrict__ Xlo, const u16* __restrict__ Xhi, int ndout,
    int klo, int nk,
    const u16* __restrict__ Dtab,
    const float* __restrict__ Wy,
    const float* __restrict__ W2, const float* __restrict__ b2,
    const float* __restrict__ w3, const float* __restrict__ b3,
    float* __restrict__ esc, int E)
{
  __shared__ float lbuf[4][16*LDT];
  int l   = threadIdx.x & 63;
  int wid = threadIdx.x >> 6;
  int r16 = l & 15, g = l >> 4;
  float* lb = lbuf[wid];
  bf16x8 wyf[2][4], w2f[2][4];
  if (CY){
    #pragma unroll
    for (int kt = 0; kt < 2; ++kt)
      #pragma unroll
      for (int nt = 0; nt < 4; ++nt) wyf[kt][nt] = bfrag(Wy, kt, nt, l);
  }
  #pragma unroll
  for (int kt = 0; kt < 2; ++kt)
    #pragma unroll
    for (int nt = 0; nt < 4; ++nt) w2f[kt][nt] = bfrag(W2, kt, nt, l);
  f32x4 b2v[4]; float w3v[4];
  #pragma unroll
  for (int nt = 0; nt < 4; ++nt){
    float bv = b2[nt*16 + r16];
    f32x4 t; t[0]=bv; t[1]=bv; t[2]=bv; t[3]=bv;
    b2v[nt] = t;
    w3v[nt] = w3[nt*16 + r16];
  }
  float b3v = b3[0];

  int ngrp = (E + 15) >> 4;
  for (int grp = blockIdx.x*4 + wid; grp < ngrp; grp += gridDim.x*4){
    int pos = grp*16 + r16;
    int pc  = pos < E ? pos : E - 1;
    int2 kde = kd[pc];
    int j   = kde.x - klo;
    bool inr = (pos < E) && ((unsigned)j < (unsigned)nk);
    unsigned long long bal = __ballot(inr ? 1 : 0);
    uint4 xa = {0,0,0,0}, xb = xa, da = xa, db = xa;
    if (inr){
      const u16* xr = (j < ndout) ? Xlo + (size_t)j * 64 : Xhi + (size_t)(j - ndout) * 64;
      xa = *(const uint4*)(xr + g*8);
      xb = *(const uint4*)(xr + 32 + g*8);
      const u16* dr = Dtab + (size_t)kde.y * 64;
      da = *(const uint4*)(dr + g*8);
      db = *(const uint4*)(dr + 32 + g*8);
    }
    bf16x8 p0, p1;
    float dfa[8], dfb[8];
    cvt8(da, dfa); cvt8(db, dfb);
    if (CY){
      bf16x8 a0 = *reinterpret_cast<const bf16x8*>(&xa);
      bf16x8 a1 = *reinterpret_cast<const bf16x8*>(&xb);
      f32x4 y[4];
      #pragma unroll
      for (int nt = 0; nt < 4; ++nt){
        f32x4 z; z[0]=0.f; z[1]=0.f; z[2]=0.f; z[3]=0.f;
        z = MFMA(a0, wyf[0][nt], z);
        z = MFMA(a1, wyf[1][nt], z);
        y[nt] = z;
      }
      #pragma unroll
      for (int nt = 0; nt < 4; ++nt)
        #pragma unroll
        for (int rg = 0; rg < 4; ++rg)
          lb[(4*g + rg)*LDT + nt*16 + r16] = y[nt][rg];
      const float* pr = lb + r16*LDT;
      float4 f0 = *(const float4*)(pr + g*8);
      float4 f1 = *(const float4*)(pr + g*8 + 4);
      float4 f2 = *(const float4*)(pr + 32 + g*8);
      float4 f3 = *(const float4*)(pr + 36 + g*8);
      float q0[8] = {f0.x,f0.y,f0.z,f0.w,f1.x,f1.y,f1.z,f1.w};
      float q1[8] = {f2.x,f2.y,f2.z,f2.w,f3.x,f3.y,f3.z,f3.w};
      #pragma unroll
      for (int u = 0; u < 8; ++u){
        p0[u] = (short)f2bf(fmaxf(q0[u] + dfa[u], 0.0f));
        p1[u] = (short)f2bf(fmaxf(q1[u] + dfb[u], 0.0f));
      }
    } else {
      float xfa[8], xfb[8];
      cvt8(xa, xfa); cvt8(xb, xfb);
      #pragma unroll
      for (int u = 0; u < 8; ++u){
        p0[u] = (short)f2bf(fmaxf(xfa[u] + dfa[u], 0.0f));
        p1[u] = (short)f2bf(fmaxf(xfb[u] + dfb[u], 0.0f));
      }
    }
    f32x4 o[4];
    #pragma unroll
    for (int nt = 0; nt < 4; ++nt){
      f32x4 v = b2v[nt];
      v = MFMA(p0, w2f[0][nt], v);
      v = MFMA(p1, w2f[1][nt], v);
      o[nt] = v;
    }
    float part[4] = {0.f, 0.f, 0.f, 0.f};
    #pragma unroll
    for (int nt = 0; nt < 4; ++nt)
      #pragma unroll
      for (int rg = 0; rg < 4; ++rg)
        part[rg] += fmaxf(o[nt][rg], 0.0f) * w3v[nt];
    #pragma unroll
    for (int m = 1; m < 16; m <<= 1){
      #pragma unroll
      for (int rg = 0; rg < 4; ++rg) part[rg] += __shfl_xor(part[rg], m);
    }
    if (r16 < 4){
      int eidx = 4*g + r16;
      int p2 = grp*16 + eidx;
      if (p2 < E && ((bal >> eidx) & 1))
        esc[p2] = __expf(part[r16] + b3v);
    }
  }
}

// ---------- 4-lane-per-dst segmented accumulate + denominator ----------
template<int FIRST>
__global__ void __launch_bounds__(256) agg4_k(
    const int* __restrict__ rowptr, const int2* __restrict__ kd,
    const float* __restrict__ esc,
    const u16* __restrict__ Xlo, const u16* __restrict__ Xhi, int ndout,
    int klo, int nk,
    float* __restrict__ acc, float* __restrict__ sdst, int N)
{
  int t = blockIdx.x*256 + threadIdx.x;
  int d = t >> 2, q = t & 3;
  if (d >= N) return;
  float a[16];
  float* ar = acc + (size_t)d * 64 + q*16;
  float s;
  if (FIRST){
    #pragma unroll
    for (int u = 0; u < 16; ++u) a[u] = 0.0f;
    s = 0.0f;
  } else {
    #pragma unroll
    for (int u = 0; u < 16; u += 4){
      float4 v = *(const float4*)(ar + u);
      a[u]=v.x; a[u+1]=v.y; a[u+2]=v.z; a[u+3]=v.w;
    }
    s = sdst[d];
  }
  int k0 = rowptr[d], k1 = rowptr[d+1];
  for (int k = k0; k < k1; ++k){
    int key = kd[k].x - klo;
    if ((unsigned)key >= (unsigned)nk) continue;
    float w = esc[k];
    s += w;
    const u16* xr = ((key < ndout) ? Xlo + (size_t)key * 64
                                   : Xhi + (size_t)(key - ndout) * 64) + q*16;
    uint4 q0 = *(const uint4*)xr;
    uint4 q1 = *(const uint4*)(xr + 8);
    float f0[8], f1[8]; cvt8(q0, f0); cvt8(q1, f1);
    #pragma unroll
    for (int u = 0; u < 8; ++u){
      a[u]     = fmaf(w, f0[u], a[u]);
      a[u + 8] = fmaf(w, f1[u], a[u + 8]);
    }
  }
  #pragma unroll
  for (int u = 0; u < 16; u += 4)
    *(float4*)(ar + u) = make_float4(a[u], a[u+1], a[u+2], a[u+3]);
  if (q == 0) sdst[d] = s;
}

extern "C" void kernel_launch(void* const* d_in, const int* in_sizes, int n_in,
                              void* d_out, int out_size, void* d_ws, size_t ws_size,
                              hipStream_t stream) {
  (void)in_sizes; (void)n_in; (void)out_size;
  const float* user_emb   = (const float*)d_in[0];
  const float* item_emb   = (const float*)d_in[1];
  const float* rating_emb = (const float*)d_in[2];
  const float *gv_w1=(const float*)d_in[3],  *gv_b1=(const float*)d_in[4];
  const float *gv_w2=(const float*)d_in[5],  *gv_b2=(const float*)d_in[6];
  const float *aI_w1=(const float*)d_in[7],  *aI_b1=(const float*)d_in[8];
  const float *aI_w2=(const float*)d_in[9],  *aI_b2=(const float*)d_in[10];
  const float *aI_w3=(const float*)d_in[11], *aI_b3=(const float*)d_in[12];
  const float *wI_w =(const float*)d_in[13], *wI_b =(const float*)d_in[14];
  const float *aS_w1=(const float*)d_in[15], *aS_b1=(const float*)d_in[16];
  const float *aS_w2=(const float*)d_in[17], *aS_b2=(const float*)d_in[18];
  const float *aS_w3=(const float*)d_in[19], *aS_b3=(const float*)d_in[20];
  const float *wS_w =(const float*)d_in[21], *wS_b =(const float*)d_in[22];
  const float *W2_w =(const float*)d_in[23], *W2_b =(const float*)d_in[24];
  const float *gu_w1=(const float*)d_in[25], *gu_b1=(const float*)d_in[26];
  const float *gu_w2=(const float*)d_in[27], *gu_b2=(const float*)d_in[28];
  const float *aU_w1=(const float*)d_in[29], *aU_b1=(const float*)d_in[30];
  const float *aU_w2=(const float*)d_in[31], *aU_b2=(const float*)d_in[32];
  const float *aU_w3=(const float*)d_in[33], *aU_b3=(const float*)d_in[34];
  const float *wU_w =(const float*)d_in[35], *wU_b =(const float*)d_in[36];
  const int* user_e    = (const int*)d_in[37];
  const int* item_e    = (const int*)d_in[38];
  const int* rating_e  = (const int*)d_in[39];
  const int* trust_e   = (const int*)d_in[40];
  const int* trustee_e = (const int*)d_in[41];
  float* dout = (float*)d_out;

  char* base = (char*)d_ws;
  size_t cur = 0;
  auto alloc = [&](size_t bytes)->char*{
    char* p = base + cur; cur += (bytes + 255) & ~(size_t)255; return p;
  };
  u16*   hI     = (u16*)  alloc((size_t)U_N * 64 * 2);
  float* esc    = (float*)alloc((size_t)EUI_E * 4);
  float* sdst   = (float*)alloc((size_t)U_N * 4);
  int*   rowptr = (int*)  alloc((size_t)(U_N + 1) * 4);
  int*   part   = (int*)  alloc((size_t)U_N * 4);
  int*   deg    = (int*)  alloc((size_t)U_N * 4);
  int2*  kd     = (int2*) alloc((size_t)EUI_E * 8);
  int*   blk    = (int*)  alloc(512 * 4);
  int*   H      = (int*)  alloc((size_t)512 * PB * 4);   // 512 KB partition offsets
  float* acc    = (float*)alloc((size_t)U_N * 64 * 4);   // 25.6 MB
  long long* kd2 = (long long*)acc;                      // alias: dead when agg runs
  size_t fixed_end = cur;
  if (ws_size < fixed_end + 13100000) return;
  u16* tabD = (u16*)(base + fixed_end);
  u16* tabX = (u16*)(base + fixed_end + 6500352);
  size_t arena = ws_size - fixed_end;
  u16* Xdout = (u16*)d_out;

  auto cdiv = [](int a, int b){ return (a + b - 1) / b; };
  auto buildCSR = [&](const int* keyI, const int* ratI, int kmul,
                      const int* dstIdx, int E, int N){
    hipMemsetAsync(deg, 0, (size_t)N * 4, stream);
    hist_k<<<cdiv(E,256), 256, 0, stream>>>(dstIdx, deg, E);
    int nb = cdiv(N, 256);
    scan1_k<<<nb, 256, 0, stream>>>(deg, part, blk, N);
    scan2_k<<<1, 512, 0, stream>>>(blk, nb);
    scan3_k<<<nb, 256, 0, stream>>>(part, blk, rowptr, N);
    hist2_k<<<PB, 256, 0, stream>>>(dstIdx, E, H, nb);
    bscan_k<<<nb, PB, 0, stream>>>(H, rowptr, N);
    part_k<<<PB, 256, 0, stream>>>(keyI, ratI, kmul, dstIdx, H, nb, kd2, E);
    bscatter_k<<<nb, 256, 0, stream>>>(kd2, rowptr, N, (long long*)kd);
  };
  auto gCap = [&](int groups){ int g = cdiv(groups, 4); return g > 1536 ? 1536 : g; };

  // ============ Phase 1: ItemAgg (dst = user) ============
  {
    buildCSR(item_e, rating_e, 5, user_e, EUI_E, U_N);
    mfma_lin_k<1><<<gCap(cdiv(U_N,16)), 256, 0, stream>>>(user_emb, aI_w1 + 64*64, aI_b1, 1, tabD, U_N);
    const int NK = 250000;
    mfma_pair_k<<<gCap(cdiv(NK,16)), 256, 0, stream>>>(item_emb, rating_emb,
        gv_w1, gv_b1, gv_w2, gv_b2, 0.01f, 0, NK, Xdout, Xdout, 1<<30);
    fscore_k<1><<<gCap(cdiv(EUI_E,16)), 256, 0, stream>>>(kd,
        Xdout, Xdout, 1<<30, 0, NK, tabD, aI_w1, aI_w2, aI_b2, aI_w3, aI_b3, esc, EUI_E);
    agg4_k<1><<<cdiv(U_N*4,256), 256, 0, stream>>>(rowptr, kd, esc,
        Xdout, Xdout, 1<<30, 0, NK, acc, sdst, U_N);
    mfma_fin_k<1><<<gCap(cdiv(U_N,16)), 256, 0, stream>>>(acc, sdst, wI_w, wI_b, hI, U_N);
  }

  // ============ Phase 2: UserAgg (dst = item) ============
  {
    buildCSR(user_e, rating_e, 5, item_e, EUI_E, I_N);
    mfma_lin_k<1><<<gCap(cdiv(I_N,16)), 256, 0, stream>>>(item_emb, aU_w1 + 64*64, aU_b1, 1, tabD, I_N);
    bool single = arena >= 33000000;
    int CP = single ? 500000 : 250000;
    int ND = single ? DOUT_ROWS : (1<<30);
    for (int klo = 0; klo < 500000; klo += CP){
      mfma_pair_k<<<gCap(cdiv(CP,16)), 256, 0, stream>>>(user_emb, rating_emb,
          gu_w1, gu_b1, gu_w2, gu_b2, 0.0f, klo, klo + CP, Xdout, tabX, ND);
      fscore_k<1><<<gCap(cdiv(EUI_E,16)), 256, 0, stream>>>(kd,
          Xdout, tabX, ND, klo, CP, tabD, aU_w1, aU_w2, aU_b2, aU_w3, aU_b3, esc, EUI_E);
      if (klo == 0)
        agg4_k<1><<<cdiv(I_N*4,256), 256, 0, stream>>>(rowptr, kd, esc,
            Xdout, tabX, ND, klo, CP, acc, sdst, I_N);
      else
        agg4_k<0><<<cdiv(I_N*4,256), 256, 0, stream>>>(rowptr, kd, esc,
            Xdout, tabX, ND, klo, CP, acc, sdst, I_N);
    }
    mfma_fin_k<0><<<gCap(cdiv(I_N,16)), 256, 0, stream>>>(acc, sdst, wU_w, wU_b,
        dout + (size_t)U_N * 64, I_N);
  }

  // ============ Phase 3: SocialAgg (dst = trustee) ============
  {
    buildCSR(trust_e, (const int*)nullptr, 1, trustee_e, EUU_E, U_N);
    u16* SD = Xdout;
    mfma_lin_k<1><<<gCap(cdiv(U_N,16)), 256, 0, stream>>>(user_emb, aS_w1, aS_b1, 0, tabD, U_N); // SS
    mfma_lin_k<0><<<gCap(cdiv(U_N,16)), 256, 0, stream>>>(hI, aS_w1 + 64*64, aS_b1, 1, SD, U_N); // SD
    fscore_k<0><<<gCap(cdiv(EUU_E,16)), 256, 0, stream>>>(kd,
        tabD, tabD, 1<<30, 0, U_N, SD, (const float*)nullptr,
        aS_w2, aS_b2, aS_w3, aS_b3, esc, EUU_E);
    agg4_k<1><<<cdiv(U_N*4,256), 256, 0, stream>>>(rowptr, kd, esc,
        hI, hI, 1<<30, 0, U_N, acc, sdst, U_N);
    mfma_fin_social_k<<<gCap(cdiv(U_N,16)), 256, 0, stream>>>(acc, sdst, hI,
        wS_w, wS_b, W2_w, W2_b, dout, U_N);
  }
}